// Round 2
// baseline (773.929 us; speedup 1.0000x reference)
//
#include <hip/hip_runtime.h>
#include <stdint.h>

// Problem constants (match reference)
#define NN   100000   // nodes
#define FIN  500      // input features
#define HID  128      // hidden
#define KP1  512      // FIN padded to mult of 32 for MFMA K-loop
#define K2   256      // 2*HID (GEMM2 K)
#define CO   40       // classes
#define NPQ  80       // folded tail GEMM N (P|Q)
#define NBUCK 391     // ceil(NN/256) coarse buckets (target>>8)
#define CAPB_S 9216   // structural bucket capacity (mean 8184, +11 sigma)
#define CAPB_K 1536   // knn bucket capacity (mean 1279, +7 sigma)

typedef __attribute__((ext_vector_type(8))) short short8;
typedef __attribute__((ext_vector_type(4))) float float4v;
typedef __attribute__((address_space(3))) unsigned int as3_u32;
typedef __attribute__((address_space(1))) unsigned int as1_u32;

__device__ __forceinline__ unsigned short f2bf(float f) {
  unsigned u = __float_as_uint(f);
  u = u + 0x7fffu + ((u >> 16) & 1u);   // RNE
  return (unsigned short)(u >> 16);
}
__device__ __forceinline__ float bf2f(unsigned short s) {
  return __uint_as_float(((unsigned)s) << 16);
}
__device__ __forceinline__ void gl_lds16(const void* g, void* l) {
  __builtin_amdgcn_global_load_lds((const as1_u32*)g, (as3_u32*)l, 16, 0, 0);
}

// ---------------- phase 1: bin edges by target>>8 (both graphs fused) ----------------
__global__ __launch_bounds__(256) void k_bin(
    const int* __restrict__ ei, int nS, int nb1S, int* __restrict__ gcur_s, int* __restrict__ gbin_s,
    const int* __restrict__ eik, int nK, int* __restrict__ gcur_k, int* __restrict__ gbin_k) {
  __shared__ int cnt[NBUCK];
  __shared__ int base[NBUCK];
  const int b = blockIdx.x;
  const bool knn = (b >= nb1S);
  const int* src = knn ? eik      : ei;
  const int* tgt = knn ? eik + nK : ei + nS;
  const int n    = knn ? nK : nS;
  int* gcur      = knn ? gcur_k : gcur_s;
  int* gbin      = knn ? gbin_k : gbin_s;
  const int capb = knn ? CAPB_K : CAPB_S;
  const int ebase = (knn ? b - nb1S : b) * 4096;
  const int t = threadIdx.x;

  for (int i = t; i < NBUCK; i += 256) cnt[i] = 0;
  __syncthreads();
  int s[16], g[16];
#pragma unroll
  for (int i = 0; i < 16; ++i) {
    const int e = ebase + i * 256 + t;
    const bool v = e < n;
    s[i] = v ? src[e] : 0;
    g[i] = v ? tgt[e] : -1;
    if (v) atomicAdd(&cnt[g[i] >> 8], 1);
  }
  __syncthreads();
  for (int i = t; i < NBUCK; i += 256) {       // reserve global space, reset local cursor
    const int c = cnt[i];
    base[i] = c ? atomicAdd(&gcur[i], c) : 0;
    cnt[i] = 0;
  }
  __syncthreads();
#pragma unroll
  for (int i = 0; i < 16; ++i) {
    if (g[i] >= 0) {
      const int bkt = g[i] >> 8;
      const int pos = base[bkt] + atomicAdd(&cnt[bkt], 1);
      if (pos < capb) gbin[bkt * capb + pos] = (s[i] << 8) | (g[i] & 255);
    }
  }
}

// ---------------- exclusive scan of bucket totals (2 blocks: structural, knn) ----------------
__global__ __launch_bounds__(512) void k_bscan(const int* __restrict__ gcur_s, int* __restrict__ bscan_s,
                                               const int* __restrict__ gcur_k, int* __restrict__ bscan_k) {
  __shared__ int sd[512];
  const int* gcur = blockIdx.x ? gcur_k : gcur_s;
  int* bscan      = blockIdx.x ? bscan_k : bscan_s;
  const int t = threadIdx.x;
  const int v = (t < NBUCK) ? gcur[t] : 0;
  sd[t] = v;
  __syncthreads();
  for (int off = 1; off < 512; off <<= 1) {
    const int x = (t >= off) ? sd[t - off] : 0;
    __syncthreads(); sd[t] += x; __syncthreads();
  }
  if (t < NBUCK) bscan[t] = sd[t] - v;   // exclusive
}

// ---------------- phase 2: per-bucket exact CSR + dinv (both graphs fused) ----------------
// colw entries: {src, w} — w filled later by k_fuse
__global__ __launch_bounds__(256) void k_csr(
    const int* __restrict__ gcur_s, const int* __restrict__ gbin_s, const int* __restrict__ bscan_s,
    int* __restrict__ rp_s, int2* __restrict__ colw_s, float* __restrict__ dinv_s,
    const int* __restrict__ gcur_k, const int* __restrict__ gbin_k, const int* __restrict__ bscan_k,
    int* __restrict__ rp_k, int2* __restrict__ colw_k, float* __restrict__ dinv_k) {
  __shared__ int cnt[256];
  __shared__ int base[256];
  const int b0 = blockIdx.x;
  const bool knn = (b0 >= NBUCK);
  const int b = knn ? b0 - NBUCK : b0;
  const int* gcur  = knn ? gcur_k  : gcur_s;
  const int* gbin  = knn ? gbin_k  : gbin_s;
  const int* bscan = knn ? bscan_k : bscan_s;
  int* rp     = knn ? rp_k   : rp_s;
  int2* colw  = knn ? colw_k : colw_s;
  float* dinv = knn ? dinv_k : dinv_s;
  const int capb = knn ? CAPB_K : CAPB_S;
  const int t = threadIdx.x;
  int nB = gcur[b]; if (nB > capb) nB = capb;
  const int gb0 = b * capb;
  const int gbase = bscan[b];

  cnt[t] = 0;
  __syncthreads();
  for (int i = t; i < nB; i += 256) atomicAdd(&cnt[gbin[gb0 + i] & 255], 1);
  __syncthreads();
  const int myc = cnt[t];
  base[t] = myc;
  __syncthreads();
  for (int off = 1; off < 256; off <<= 1) {   // inclusive Hillis-Steele
    const int x = (t >= off) ? base[t - off] : 0;
    __syncthreads(); base[t] += x; __syncthreads();
  }
  const int excl = base[t] - myc;
  const int tg = b * 256 + t;
  if (tg < NN) { rp[tg] = gbase + excl; dinv[tg] = rsqrtf((float)(myc + 1)); }
  if (tg == NN) rp[NN] = gbase + excl;        // only in last bucket (t=160)
  __syncthreads();
  base[t] = excl; cnt[t] = 0;
  __syncthreads();
  for (int i = t; i < nB; i += 256) {
    const int e = gbin[gb0 + i];
    const int tl = e & 255;
    const int pos = atomicAdd(&cnt[tl], 1);
    colw[gbase + base[tl] + pos] = make_int2(e >> 8, 0);
  }
}

// ---------------- fill w = dinv[src] into colw (both graphs) ----------------
__global__ __launch_bounds__(256) void k_fuse(
    int2* __restrict__ colw_s, const float* __restrict__ dinv_s, int nS, int nbF,
    int2* __restrict__ colw_k, const float* __restrict__ dinv_k, int nK) {
  const int b = blockIdx.x;
  if (b < nbF) {
    const int i = b * 256 + threadIdx.x;
    if (i < nS) {
      const int s = colw_s[i].x;
      colw_s[i].y = __float_as_int(dinv_s[s]);
    }
  } else {
    const int i = (b - nbF) * 256 + threadIdx.x;
    if (i < nK) {
      const int s = colw_k[i].x;
      colw_k[i].y = __float_as_int(dinv_k[s]);
    }
  }
}

// ---------------- weight prep ----------------
__global__ void k_w1t(const float* __restrict__ W1, unsigned short* __restrict__ W1T) {
  int idx = blockIdx.x * 256 + threadIdx.x;      // 128*512
  int n = idx >> 9, k = idx & 511;
  float v = (k < FIN) ? W1[k * HID + n] : 0.f;
  W1T[idx] = f2bf(v);
}
// WpqT[n][k], n<80, k<256: n<40 -> P col o=n (Wlin left), n>=40 -> Q col o=n-40 (Wlin right)
// cb[o] = blin[o] + sum_j b2[j]*(Wl[o][j] + Wl[o][40+j])
__global__ void k_wpq(const float* __restrict__ W2, const float* __restrict__ Wl,
                      const float* __restrict__ b2, const float* __restrict__ bl,
                      unsigned short* __restrict__ WpqT, float* __restrict__ cb) {
  const int idx = blockIdx.x * 256 + threadIdx.x;   // 80*256 = 20480
  const int n = idx >> 8, k = idx & 255;
  const int o = (n < CO) ? n : n - CO;
  const int joff = (n < CO) ? 0 : CO;
  float s = 0.f;
#pragma unroll 8
  for (int j = 0; j < CO; ++j) s += W2[k * CO + j] * Wl[o * NPQ + joff + j];
  WpqT[n * K2 + k] = f2bf(s);
  if (blockIdx.x == 0 && threadIdx.x < CO) {
    const int oo = threadIdx.x;
    float c = bl[oo];
    for (int j = 0; j < CO; ++j) c += b2[j] * (Wl[oo * NPQ + j] + Wl[oo * NPQ + CO + j]);
    cb[oo] = c;
  }
}

// ---------------- GEMM1: H1b = bf16(x @ W1)  [NN x 128] ----------------
__global__ __launch_bounds__(256) void k_gemm1(const float* __restrict__ x,
    const unsigned short* __restrict__ W1T, const float* __restrict__ zbuf,
    unsigned short* __restrict__ H1b) {
  __shared__ float Als[1024 * 4];          // chunk = kg4*128+m, 4 floats each (16B)
  __shared__ unsigned short Bls[512 * 8];  // chunk = kg8*128+n, 8 bf16 each (16B)
  const int t = threadIdx.x;
  const int wv = t >> 6, lane = t & 63;
  const int qd = lane >> 4, mr = lane & 15;
  const int m0 = blockIdx.x * 128;

  float4v acc[2][8];
  const float4v zf4 = {0.f, 0.f, 0.f, 0.f};
#pragma unroll
  for (int a = 0; a < 2; ++a)
#pragma unroll
    for (int b = 0; b < 8; ++b) acc[a][b] = zf4;

  for (int kk = 0; kk < 16; ++kk) {
    const int k0 = kk * 32;
    __syncthreads();
#pragma unroll
    for (int i = 0; i < 4; ++i) {
      const int cb = (wv * 4 + i) * 64;
      const int q = cb + lane;
      const int kg = q >> 7, m = q & 127;
      const int gm = m0 + m, kb = k0 + kg * 4;   // 500 % 4 == 0 -> never straddles
      const float* gp = (gm < NN && kb < FIN) ? (x + (size_t)gm * FIN + kb) : zbuf;
      gl_lds16(gp, &Als[cb * 4]);
    }
#pragma unroll
    for (int i = 0; i < 2; ++i) {
      const int cb = (wv * 2 + i) * 64;
      const int q = cb + lane;
      const int kg = q >> 7, n = q & 127;
      const unsigned short* gp = W1T + n * KP1 + k0 + kg * 8;
      gl_lds16(gp, &Bls[cb * 8]);
    }
    __syncthreads();
    short8 af[2];
#pragma unroll
    for (int rt = 0; rt < 2; ++rt) {   // A frag: A[m=lane&15][k=qd*8+j]
      const int m = wv * 32 + rt * 16 + mr;
      const float4v a0 = *(const float4v*)&Als[((2 * qd) * 128 + m) * 4];
      const float4v a1 = *(const float4v*)&Als[((2 * qd + 1) * 128 + m) * 4];
      short8 f;
      f[0] = (short)f2bf(a0[0]); f[1] = (short)f2bf(a0[1]);
      f[2] = (short)f2bf(a0[2]); f[3] = (short)f2bf(a0[3]);
      f[4] = (short)f2bf(a1[0]); f[5] = (short)f2bf(a1[1]);
      f[6] = (short)f2bf(a1[2]); f[7] = (short)f2bf(a1[3]);
      af[rt] = f;
    }
#pragma unroll
    for (int ct = 0; ct < 8; ++ct) {   // B frag: B[k=qd*8+j][n=lane&15]
      const short8 bf = *(const short8*)&Bls[(qd * 128 + ct * 16 + mr) * 8];
      acc[0][ct] = __builtin_amdgcn_mfma_f32_16x16x32_bf16(af[0], bf, acc[0][ct], 0, 0, 0);
      acc[1][ct] = __builtin_amdgcn_mfma_f32_16x16x32_bf16(af[1], bf, acc[1][ct], 0, 0, 0);
    }
  }
  // C/D layout: col = lane&15, row = (lane>>4)*4 + j
#pragma unroll
  for (int rt = 0; rt < 2; ++rt) {
    const int rb = m0 + wv * 32 + rt * 16 + qd * 4;
#pragma unroll
    for (int ct = 0; ct < 8; ++ct) {
      const int col = ct * 16 + mr;
#pragma unroll
      for (int j = 0; j < 4; ++j) {
        const int r = rb + j;
        if (r < NN) H1b[(size_t)r * HID + col] = f2bf(acc[rt][ct][j]);
      }
    }
  }
}

// ---------------- GEMM2: PQ = bf16(R1b @ Wpq)  [NN x 80] ----------------
__global__ __launch_bounds__(256) void k_gemm2(const unsigned short* __restrict__ R1b,
    const unsigned short* __restrict__ WpqT, const unsigned short* __restrict__ zbuf,
    unsigned short* __restrict__ PQ) {
  __shared__ unsigned short Als[512 * 8];  // chunk = kg8*128+m
  __shared__ unsigned short Bls[320 * 8];  // chunk = kg8*80+n
  const int t = threadIdx.x;
  const int wv = t >> 6, lane = t & 63;
  const int qd = lane >> 4, mr = lane & 15;
  const int m0 = blockIdx.x * 128;

  float4v acc[2][5];
  const float4v zf4 = {0.f, 0.f, 0.f, 0.f};
#pragma unroll
  for (int a = 0; a < 2; ++a)
#pragma unroll
    for (int b = 0; b < 5; ++b) acc[a][b] = zf4;

  for (int kk = 0; kk < 8; ++kk) {
    const int k0 = kk * 32;
    __syncthreads();
#pragma unroll
    for (int i = 0; i < 2; ++i) {
      const int cb = (wv * 2 + i) * 64;
      const int q = cb + lane;
      const int kg = q >> 7, m = q & 127;
      const int gm = m0 + m;
      const unsigned short* gp = (gm < NN) ? (R1b + (size_t)gm * K2 + k0 + kg * 8) : zbuf;
      gl_lds16(gp, &Als[cb * 8]);
    }
    // B: 320 chunks = 5 wave-instrs (wv 0..3 do inst wv; wv 0 also inst 4)
    {
      const int cb = wv * 64;
      const int q = cb + lane;
      const int kg = q / 80, n = q % 80;
      gl_lds16(WpqT + n * K2 + k0 + kg * 8, &Bls[cb * 8]);
      if (wv == 0) {
        const int cb2 = 4 * 64;
        const int q2 = cb2 + lane;
        const int kg2 = q2 / 80, n2 = q2 % 80;
        gl_lds16(WpqT + n2 * K2 + k0 + kg2 * 8, &Bls[cb2 * 8]);
      }
    }
    __syncthreads();
    short8 af[2];
#pragma unroll
    for (int rt = 0; rt < 2; ++rt)
      af[rt] = *(const short8*)&Als[(qd * 128 + wv * 32 + rt * 16 + mr) * 8];
#pragma unroll
    for (int ct = 0; ct < 5; ++ct) {
      const short8 bf = *(const short8*)&Bls[(qd * 80 + ct * 16 + mr) * 8];
      acc[0][ct] = __builtin_amdgcn_mfma_f32_16x16x32_bf16(af[0], bf, acc[0][ct], 0, 0, 0);
      acc[1][ct] = __builtin_amdgcn_mfma_f32_16x16x32_bf16(af[1], bf, acc[1][ct], 0, 0, 0);
    }
  }
#pragma unroll
  for (int rt = 0; rt < 2; ++rt) {
    const int rb = m0 + wv * 32 + rt * 16 + qd * 4;
#pragma unroll
    for (int ct = 0; ct < 5; ++ct) {
      const int col = ct * 16 + mr;
#pragma unroll
      for (int j = 0; j < 4; ++j) {
        const int r = rb + j;
        if (r < NN) PQ[(size_t)r * NPQ + col] = f2bf(acc[rt][ct][j]);
      }
    }
  }
}

// ---------------- gather helper v2: half-wave per edge, dwordx2, padded batches ----------------
// lanes 0-31 (h=0) take even edges, lanes 32-63 (h=1) odd edges; each lane covers
// bf16 cols 4*cl..4*cl+3 of the 128-col row via one dwordx2 load. 16 edges per batch,
// indices double-buffered; OOB edges clamp the index (valid row) and zero the weight.
__device__ __forceinline__ void agg_pairs(const int2* __restrict__ cw, const int e0, const int e1,
    const uint2* __restrict__ H2, const int cl, const int h, float* __restrict__ a) {
  const int deg = e1 - e0;
  if (deg <= 0) return;
  const int e1c = e1 - 1;
  const int nbat = (deg + 15) >> 4;
  int2 q[8];
#pragma unroll
  for (int j = 0; j < 8; ++j) {               // batch 0 indices (issued together)
    const int ee = e0 + 2 * j + h;
    const int ec = (ee < e1c) ? ee : e1c;
    int2 t = cw[ec];
    t.y = (ee < e1) ? t.y : 0;                // w = 0 kills padded edges
    q[j] = t;
  }
  for (int b = 0; b < nbat; ++b) {
    int2 qn[8];
    const bool more = (b + 1 < nbat);
    if (more) {                               // prefetch next batch indices
      const int eb = e0 + (b + 1) * 16;
#pragma unroll
      for (int j = 0; j < 8; ++j) {
        const int ee = eb + 2 * j + h;
        const int ec = (ee < e1c) ? ee : e1c;
        int2 t = cw[ec];
        t.y = (ee < e1) ? t.y : 0;
        qn[j] = t;
      }
    }
#pragma unroll
    for (int j = 0; j < 8; ++j) {
      const uint2 d = H2[((size_t)q[j].x << 5) + cl]; // row = 32 uint2
      const float w = __int_as_float(q[j].y);
      a[0] += w * __uint_as_float(d.x << 16);
      a[1] += w * __uint_as_float(d.x & 0xffff0000u);
      a[2] += w * __uint_as_float(d.y << 16);
      a[3] += w * __uint_as_float(d.y & 0xffff0000u);
    }
    if (more) {
#pragma unroll
      for (int j = 0; j < 8; ++j) q[j] = qn[j];
    }
  }
}

// ---------------- layer-1 aggregation: one wave per node, BOTH graphs ----------------
__global__ __launch_bounds__(256) void k_agg1(
    const int* __restrict__ rp_s, const int2* __restrict__ colw_s, const float* __restrict__ dinv_s,
    const int* __restrict__ rp_k, const int2* __restrict__ colw_k, const float* __restrict__ dinv_k,
    const unsigned short* __restrict__ H, const float* __restrict__ bias,
    unsigned short* __restrict__ out) {
  const int wv = threadIdx.x >> 6, lane = threadIdx.x & 63;
  const int c = blockIdx.x * 4 + wv;
  if (c >= NN) return;
  const uint2* H2 = (const uint2*)H;
  const int cl = lane & 31, h = lane >> 5;
  float a[4] = {0.f, 0.f, 0.f, 0.f};          // structural partials (this half's edges)
  float b[4] = {0.f, 0.f, 0.f, 0.f};          // knn partials
  agg_pairs(colw_s, rp_s[c], rp_s[c + 1], H2, cl, h, a);
  agg_pairs(colw_k, rp_k[c], rp_k[c + 1], H2, cl, h, b);
#pragma unroll
  for (int j = 0; j < 4; ++j) {               // combine even/odd-edge halves
    a[j] += __shfl_xor(a[j], 32);
    b[j] += __shfl_xor(b[j], 32);
  }
  const float dcs = dinv_s[c], dck = dinv_k[c];
  const uint2 pc = H2[((size_t)c << 5) + cl]; // self row, cols 4cl..4cl+3
  float self[4];
  self[0] = __uint_as_float(pc.x << 16);
  self[1] = __uint_as_float(pc.x & 0xffff0000u);
  self[2] = __uint_as_float(pc.y << 16);
  self[3] = __uint_as_float(pc.y & 0xffff0000u);
  const float4v bb = ((const float4v*)bias)[cl];
  unsigned short os[4], ok[4];
#pragma unroll
  for (int j = 0; j < 4; ++j) {
    const float vs = fmaxf(dcs * (a[j] + dcs * self[j]) + bb[j], 0.f);
    const float vk = fmaxf(dck * (b[j] + dck * self[j]) + bb[j], 0.f);
    os[j] = f2bf(vs);
    ok[j] = f2bf(vk);
  }
  uint2 ps, pk;
  ps.x = (unsigned)os[0] | ((unsigned)os[1] << 16);
  ps.y = (unsigned)os[2] | ((unsigned)os[3] << 16);
  pk.x = (unsigned)ok[0] | ((unsigned)ok[1] << 16);
  pk.y = (unsigned)ok[2] | ((unsigned)ok[3] << 16);
  uint2* orow = (uint2*)(out + (size_t)c * K2);
  if (h == 0) orow[cl] = ps;                  // structural cols 0..127
  else        orow[32 + cl] = pk;             // knn cols 128..255
}

// ---------------- tail: logits = agg_s(P) + agg_k(Q) + cb; log_softmax ----------------
// wave per node; 3 groups of 20 lanes gather edges in parallel (strided), combine via shfl
__global__ __launch_bounds__(256) void k_aggf(
    const int* __restrict__ rp_s, const int2* __restrict__ colw_s, const float* __restrict__ dinv_s,
    const int* __restrict__ rp_k, const int2* __restrict__ colw_k, const float* __restrict__ dinv_k,
    const unsigned short* __restrict__ PQ, const float* __restrict__ cb,
    float* __restrict__ out) {
  const int wv = threadIdx.x >> 6, lane = threadIdx.x & 63;
  const int c = blockIdx.x * 4 + wv;
  if (c >= NN) return;
  const unsigned* PQ32 = (const unsigned*)PQ;
  const int g = lane / 20;        // 0..2 active groups (lanes 60-63 idle)
  const int l = lane % 20;        // dword index: P dwords 0-19, Q dwords 20-39
  float sx = 0.f, sy = 0.f, kx = 0.f, ky = 0.f;
  if (g < 3) {
    // structural edges -> P
    {
      const int e1 = rp_s[c + 1];
      int e = rp_s[c] + g;
      for (; e + 9 < e1; e += 12) {
        const int2 q0 = colw_s[e], q1 = colw_s[e + 3], q2 = colw_s[e + 6], q3 = colw_s[e + 9];
        const unsigned d0 = PQ32[(size_t)q0.x * 40 + l];
        const unsigned d1 = PQ32[(size_t)q1.x * 40 + l];
        const unsigned d2 = PQ32[(size_t)q2.x * 40 + l];
        const unsigned d3 = PQ32[(size_t)q3.x * 40 + l];
        const float w0 = __int_as_float(q0.y), w1 = __int_as_float(q1.y);
        const float w2 = __int_as_float(q2.y), w3 = __int_as_float(q3.y);
        sx += w0 * __uint_as_float(d0 << 16) + w1 * __uint_as_float(d1 << 16)
            + w2 * __uint_as_float(d2 << 16) + w3 * __uint_as_float(d3 << 16);
        sy += w0 * __uint_as_float(d0 & 0xffff0000u) + w1 * __uint_as_float(d1 & 0xffff0000u)
            + w2 * __uint_as_float(d2 & 0xffff0000u) + w3 * __uint_as_float(d3 & 0xffff0000u);
      }
      for (; e < e1; e += 3) {
        const int2 q = colw_s[e];
        const unsigned d = PQ32[(size_t)q.x * 40 + l];
        const float w = __int_as_float(q.y);
        sx += w * __uint_as_float(d << 16);
        sy += w * __uint_as_float(d & 0xffff0000u);
      }
    }
    // knn edges -> Q
    {
      const int e1 = rp_k[c + 1];
      int e = rp_k[c] + g;
      for (; e < e1; e += 3) {
        const int2 q = colw_k[e];
        const unsigned d = PQ32[(size_t)q.x * 40 + 20 + l];
        const float w = __int_as_float(q.y);
        kx += w * __uint_as_float(d << 16);
        ky += w * __uint_as_float(d & 0xffff0000u);
      }
    }
  }
  // combine 3 group partials into lanes 0-19
  sx += __shfl(sx, lane + 20) + __shfl(sx, lane + 40);
  sy += __shfl(sy, lane + 20) + __shfl(sy, lane + 40);
  kx += __shfl(kx, lane + 20) + __shfl(kx, lane + 40);
  ky += __shfl(ky, lane + 20) + __shfl(ky, lane + 40);

  float lo = 0.f, hi = 0.f;
  if (lane < 20) {
    const float dcs = dinv_s[c], dck = dinv_k[c];
    const unsigned dP = PQ32[(size_t)c * 40 + lane];
    const unsigned dQ = PQ32[(size_t)c * 40 + 20 + lane];
    const float2 cbb = ((const float2*)cb)[lane];
    lo = dcs * (sx + dcs * __uint_as_float(dP << 16))
       + dck * (kx + dck * __uint_as_float(dQ << 16)) + cbb.x;
    hi = dcs * (sy + dcs * __uint_as_float(dP & 0xffff0000u))
       + dck * (ky + dck * __uint_as_float(dQ & 0xffff0000u)) + cbb.y;
  }
  // log_softmax over 40 (lanes 0-19 hold pairs)
  float m = (lane < 20) ? fmaxf(lo, hi) : -3.4e38f;
#pragma unroll
  for (int off = 1; off < 64; off <<= 1) m = fmaxf(m, __shfl_xor(m, off));
  float s = (lane < 20) ? (expf(lo - m) + expf(hi - m)) : 0.f;
#pragma unroll
  for (int off = 1; off < 64; off <<= 1) s += __shfl_xor(s, off);
  const float lse = m + logf(s);
  if (lane < 20) {
    float2 o; o.x = lo - lse; o.y = hi - lse;
    ((float2*)(out + (size_t)c * CO))[lane] = o;
  }
}

extern "C" void kernel_launch(void* const* d_in, const int* in_sizes, int n_in,
                              void* d_out, int out_size, void* d_ws, size_t ws_size,
                              hipStream_t stream) {
  const float* x  = (const float*)d_in[0];
  const int* ei   = (const int*)d_in[1];   // [2][E]: row0 = src, row1 = tgt
  const int* eik  = (const int*)d_in[2];
  const float* W1 = (const float*)d_in[3];
  const float* b1 = (const float*)d_in[4];
  const float* W2 = (const float*)d_in[5];
  const float* b2 = (const float*)d_in[6];
  const float* Wl = (const float*)d_in[7];
  const float* bl = (const float*)d_in[8];
  float* out = (float*)d_out;
  const int E  = in_sizes[1] / 2;
  const int EK = in_sizes[2] / 2;

  // workspace layout (~125 MB), 256B-aligned slots
  char* p = (char*)d_ws;
  size_t off = 0;
  auto alloc = [&](size_t bytes) -> void* {
    void* r = (void*)(p + off);
    off += (bytes + 255) & ~(size_t)255;
    return r;
  };
  int* gcur_s = (int*)alloc((size_t)NBUCK * 4);
  int* gcur_k = (int*)alloc((size_t)NBUCK * 4);
  void* zbuf = alloc(256);                 // zero redirect target for OOB tiles
  const size_t zero_span = off;            // memset covers gcur_s, gcur_k, zbuf
  int* bscan_s = (int*)alloc((size_t)NBUCK * 4);
  int* bscan_k = (int*)alloc((size_t)NBUCK * 4);
  float* dinv_s = (float*)alloc((size_t)NN * 4);
  float* dinv_k = (float*)alloc((size_t)NN * 4);
  int* rp_s = (int*)alloc((size_t)(NN + 1) * 4);
  int* rp_k = (int*)alloc((size_t)(NN + 1) * 4);
  unsigned short* W1T = (unsigned short*)alloc((size_t)HID * KP1 * 2);
  unsigned short* WpqT = (unsigned short*)alloc((size_t)NPQ * K2 * 2);
  float* cbv = (float*)alloc((size_t)CO * 4);
  int* gbin_s = (int*)alloc((size_t)NBUCK * CAPB_S * 4);    // 14.4 MB
  int* gbin_k = (int*)alloc((size_t)NBUCK * CAPB_K * 4);    // 2.4 MB
  int2* colw_s = (int2*)alloc((size_t)E * 8);               // 25.6 MB
  int2* colw_k = (int2*)alloc((size_t)EK * 8);              // 4 MB
  unsigned short* H1b = (unsigned short*)alloc((size_t)NN * HID * 2);   // 25.6 MB
  unsigned short* R1b = (unsigned short*)alloc((size_t)NN * K2 * 2);    // 51.2 MB
  unsigned short* PQ = H1b;   // alias: H1b dead after agg1; PQ = [NN x 80] bf16 (16 MB)

  hipMemsetAsync(d_ws, 0, zero_span, stream);

  // CSR build: bin -> scan -> per-bucket exact CSR (+dinv) -> fuse dinv[src] into edges
  const int nb1S = (E + 4095) / 4096;
  const int nb1K = (EK + 4095) / 4096;
  k_bin<<<nb1S + nb1K, 256, 0, stream>>>(ei, E, nb1S, gcur_s, gbin_s, eik, EK, gcur_k, gbin_k);
  k_bscan<<<2, 512, 0, stream>>>(gcur_s, bscan_s, gcur_k, bscan_k);
  k_csr<<<2 * NBUCK, 256, 0, stream>>>(gcur_s, gbin_s, bscan_s, rp_s, colw_s, dinv_s,
                                       gcur_k, gbin_k, bscan_k, rp_k, colw_k, dinv_k);
  const int nbF = (E + 255) / 256;
  const int nbFk = (EK + 255) / 256;
  k_fuse<<<nbF + nbFk, 256, 0, stream>>>(colw_s, dinv_s, E, nbF, colw_k, dinv_k, EK);

  // weight prep
  k_w1t<<<(HID * KP1) / 256, 256, 0, stream>>>(W1, W1T);
  k_wpq<<<NPQ, 256, 0, stream>>>(W2, Wl, b2, bl, WpqT, cbv);

  // layer 1: shared GEMM, fused dual aggregation (one wave per node)
  k_gemm1<<<(NN + 127) / 128, 256, 0, stream>>>(x, W1T, (const float*)zbuf, H1b);
  const int nbAgg = (NN + 3) / 4;
  k_agg1<<<nbAgg, 256, 0, stream>>>(rp_s, colw_s, dinv_s, rp_k, colw_k, dinv_k, H1b, b1, R1b);

  // folded tail: PQ GEMM + fused aggregation/log_softmax
  k_gemm2<<<(NN + 127) / 128, 256, 0, stream>>>(R1b, WpqT, (const unsigned short*)zbuf, PQ);
  k_aggf<<<nbAgg, 256, 0, stream>>>(rp_s, colw_s, dinv_s, rp_k, colw_k, dinv_k, PQ, cbv, out);
}

// Round 3
// 729.228 us; speedup vs baseline: 1.0613x; 1.0613x over previous
//
#include <hip/hip_runtime.h>
#include <stdint.h>

// Problem constants (match reference)
#define NN   100000   // nodes
#define FIN  500      // input features
#define HID  128      // hidden
#define KP1  512      // FIN padded to mult of 32 for MFMA K-loop
#define K2   256      // 2*HID (GEMM2 K)
#define CO   40       // classes
#define NPQ  80       // folded tail GEMM N (P|Q)
#define NBUCK 391     // ceil(NN/256) coarse buckets (target>>8)
#define CAPB_S 9216   // structural bucket capacity (mean 8184, +11 sigma)
#define CAPB_K 1536   // knn bucket capacity (mean 1279, +7 sigma)

typedef __attribute__((ext_vector_type(8))) short short8;
typedef __attribute__((ext_vector_type(4))) float float4v;
typedef __attribute__((address_space(3))) unsigned int as3_u32;
typedef __attribute__((address_space(1))) unsigned int as1_u32;

__device__ __forceinline__ unsigned short f2bf(float f) {
  unsigned u = __float_as_uint(f);
  u = u + 0x7fffu + ((u >> 16) & 1u);   // RNE
  return (unsigned short)(u >> 16);
}
__device__ __forceinline__ float bf2f(unsigned short s) {
  return __uint_as_float(((unsigned)s) << 16);
}
__device__ __forceinline__ void gl_lds16(const void* g, void* l) {
  __builtin_amdgcn_global_load_lds((const as1_u32*)g, (as3_u32*)l, 16, 0, 0);
}

// ---------------- phase 1: bin edges by target>>8 (both graphs fused) ----------------
__global__ __launch_bounds__(256) void k_bin(
    const int* __restrict__ ei, int nS, int nb1S, int* __restrict__ gcur_s, int* __restrict__ gbin_s,
    const int* __restrict__ eik, int nK, int* __restrict__ gcur_k, int* __restrict__ gbin_k) {
  __shared__ int cnt[NBUCK];
  __shared__ int base[NBUCK];
  const int b = blockIdx.x;
  const bool knn = (b >= nb1S);
  const int* src = knn ? eik      : ei;
  const int* tgt = knn ? eik + nK : ei + nS;
  const int n    = knn ? nK : nS;
  int* gcur      = knn ? gcur_k : gcur_s;
  int* gbin      = knn ? gbin_k : gbin_s;
  const int capb = knn ? CAPB_K : CAPB_S;
  const int ebase = (knn ? b - nb1S : b) * 4096;
  const int t = threadIdx.x;

  for (int i = t; i < NBUCK; i += 256) cnt[i] = 0;
  __syncthreads();
  int s[16], g[16];
#pragma unroll
  for (int i = 0; i < 16; ++i) {
    const int e = ebase + i * 256 + t;
    const bool v = e < n;
    s[i] = v ? src[e] : 0;
    g[i] = v ? tgt[e] : -1;
    if (v) atomicAdd(&cnt[g[i] >> 8], 1);
  }
  __syncthreads();
  for (int i = t; i < NBUCK; i += 256) {       // reserve global space, reset local cursor
    const int c = cnt[i];
    base[i] = c ? atomicAdd(&gcur[i], c) : 0;
    cnt[i] = 0;
  }
  __syncthreads();
#pragma unroll
  for (int i = 0; i < 16; ++i) {
    if (g[i] >= 0) {
      const int bkt = g[i] >> 8;
      const int pos = base[bkt] + atomicAdd(&cnt[bkt], 1);
      if (pos < capb) gbin[bkt * capb + pos] = (s[i] << 8) | (g[i] & 255);
    }
  }
}

// ---------------- exclusive scan of bucket totals (2 blocks: structural, knn) ----------------
__global__ __launch_bounds__(512) void k_bscan(const int* __restrict__ gcur_s, int* __restrict__ bscan_s,
                                               const int* __restrict__ gcur_k, int* __restrict__ bscan_k) {
  __shared__ int sd[512];
  const int* gcur = blockIdx.x ? gcur_k : gcur_s;
  int* bscan      = blockIdx.x ? bscan_k : bscan_s;
  const int t = threadIdx.x;
  const int v = (t < NBUCK) ? gcur[t] : 0;
  sd[t] = v;
  __syncthreads();
  for (int off = 1; off < 512; off <<= 1) {
    const int x = (t >= off) ? sd[t - off] : 0;
    __syncthreads(); sd[t] += x; __syncthreads();
  }
  if (t < NBUCK) bscan[t] = sd[t] - v;   // exclusive
}

// ---------------- phase 2: per-bucket exact CSR + dinv (both graphs fused) ----------------
// colw entries: {src, w} — w filled later by k_fuse
__global__ __launch_bounds__(256) void k_csr(
    const int* __restrict__ gcur_s, const int* __restrict__ gbin_s, const int* __restrict__ bscan_s,
    int* __restrict__ rp_s, int2* __restrict__ colw_s, float* __restrict__ dinv_s,
    const int* __restrict__ gcur_k, const int* __restrict__ gbin_k, const int* __restrict__ bscan_k,
    int* __restrict__ rp_k, int2* __restrict__ colw_k, float* __restrict__ dinv_k) {
  __shared__ int cnt[256];
  __shared__ int base[256];
  const int b0 = blockIdx.x;
  const bool knn = (b0 >= NBUCK);
  const int b = knn ? b0 - NBUCK : b0;
  const int* gcur  = knn ? gcur_k  : gcur_s;
  const int* gbin  = knn ? gbin_k  : gbin_s;
  const int* bscan = knn ? bscan_k : bscan_s;
  int* rp     = knn ? rp_k   : rp_s;
  int2* colw  = knn ? colw_k : colw_s;
  float* dinv = knn ? dinv_k : dinv_s;
  const int capb = knn ? CAPB_K : CAPB_S;
  const int t = threadIdx.x;
  int nB = gcur[b]; if (nB > capb) nB = capb;
  const int gb0 = b * capb;
  const int gbase = bscan[b];

  cnt[t] = 0;
  __syncthreads();
  for (int i = t; i < nB; i += 256) atomicAdd(&cnt[gbin[gb0 + i] & 255], 1);
  __syncthreads();
  const int myc = cnt[t];
  base[t] = myc;
  __syncthreads();
  for (int off = 1; off < 256; off <<= 1) {   // inclusive Hillis-Steele
    const int x = (t >= off) ? base[t - off] : 0;
    __syncthreads(); base[t] += x; __syncthreads();
  }
  const int excl = base[t] - myc;
  const int tg = b * 256 + t;
  if (tg < NN) { rp[tg] = gbase + excl; dinv[tg] = rsqrtf((float)(myc + 1)); }
  if (tg == NN) rp[NN] = gbase + excl;        // only in last bucket (t=160)
  __syncthreads();
  base[t] = excl; cnt[t] = 0;
  __syncthreads();
  for (int i = t; i < nB; i += 256) {
    const int e = gbin[gb0 + i];
    const int tl = e & 255;
    const int pos = atomicAdd(&cnt[tl], 1);
    colw[gbase + base[tl] + pos] = make_int2(e >> 8, 0);
  }
}

// ---------------- fill w = dinv[src] into colw (both graphs) ----------------
__global__ __launch_bounds__(256) void k_fuse(
    int2* __restrict__ colw_s, const float* __restrict__ dinv_s, int nS, int nbF,
    int2* __restrict__ colw_k, const float* __restrict__ dinv_k, int nK) {
  const int b = blockIdx.x;
  if (b < nbF) {
    const int i = b * 256 + threadIdx.x;
    if (i < nS) {
      const int s = colw_s[i].x;
      colw_s[i].y = __float_as_int(dinv_s[s]);
    }
  } else {
    const int i = (b - nbF) * 256 + threadIdx.x;
    if (i < nK) {
      const int s = colw_k[i].x;
      colw_k[i].y = __float_as_int(dinv_k[s]);
    }
  }
}

// ---------------- weight prep ----------------
__global__ void k_w1t(const float* __restrict__ W1, unsigned short* __restrict__ W1T) {
  int idx = blockIdx.x * 256 + threadIdx.x;      // 128*512
  int n = idx >> 9, k = idx & 511;
  float v = (k < FIN) ? W1[k * HID + n] : 0.f;
  W1T[idx] = f2bf(v);
}
// WpqT[n][k], n<80, k<256: n<40 -> P col o=n (Wlin left), n>=40 -> Q col o=n-40 (Wlin right)
// cb[o] = blin[o] + sum_j b2[j]*(Wl[o][j] + Wl[o][40+j])
__global__ void k_wpq(const float* __restrict__ W2, const float* __restrict__ Wl,
                      const float* __restrict__ b2, const float* __restrict__ bl,
                      unsigned short* __restrict__ WpqT, float* __restrict__ cb) {
  const int idx = blockIdx.x * 256 + threadIdx.x;   // 80*256 = 20480
  const int n = idx >> 8, k = idx & 255;
  const int o = (n < CO) ? n : n - CO;
  const int joff = (n < CO) ? 0 : CO;
  float s = 0.f;
#pragma unroll 8
  for (int j = 0; j < CO; ++j) s += W2[k * CO + j] * Wl[o * NPQ + joff + j];
  WpqT[n * K2 + k] = f2bf(s);
  if (blockIdx.x == 0 && threadIdx.x < CO) {
    const int oo = threadIdx.x;
    float c = bl[oo];
    for (int j = 0; j < CO; ++j) c += b2[j] * (Wl[oo * NPQ + j] + Wl[oo * NPQ + CO + j]);
    cb[oo] = c;
  }
}

// ---------------- GEMM1: H1b = bf16(x @ W1)  [NN x 128] ----------------
__global__ __launch_bounds__(256) void k_gemm1(const float* __restrict__ x,
    const unsigned short* __restrict__ W1T, const float* __restrict__ zbuf,
    unsigned short* __restrict__ H1b) {
  __shared__ float Als[1024 * 4];          // chunk = kg4*128+m, 4 floats each (16B)
  __shared__ unsigned short Bls[512 * 8];  // chunk = kg8*128+n, 8 bf16 each (16B)
  const int t = threadIdx.x;
  const int wv = t >> 6, lane = t & 63;
  const int qd = lane >> 4, mr = lane & 15;
  const int m0 = blockIdx.x * 128;

  float4v acc[2][8];
  const float4v zf4 = {0.f, 0.f, 0.f, 0.f};
#pragma unroll
  for (int a = 0; a < 2; ++a)
#pragma unroll
    for (int b = 0; b < 8; ++b) acc[a][b] = zf4;

  for (int kk = 0; kk < 16; ++kk) {
    const int k0 = kk * 32;
    __syncthreads();
#pragma unroll
    for (int i = 0; i < 4; ++i) {
      const int cb = (wv * 4 + i) * 64;
      const int q = cb + lane;
      const int kg = q >> 7, m = q & 127;
      const int gm = m0 + m, kb = k0 + kg * 4;   // 500 % 4 == 0 -> never straddles
      const float* gp = (gm < NN && kb < FIN) ? (x + (size_t)gm * FIN + kb) : zbuf;
      gl_lds16(gp, &Als[cb * 4]);
    }
#pragma unroll
    for (int i = 0; i < 2; ++i) {
      const int cb = (wv * 2 + i) * 64;
      const int q = cb + lane;
      const int kg = q >> 7, n = q & 127;
      const unsigned short* gp = W1T + n * KP1 + k0 + kg * 8;
      gl_lds16(gp, &Bls[cb * 8]);
    }
    __syncthreads();
    short8 af[2];
#pragma unroll
    for (int rt = 0; rt < 2; ++rt) {   // A frag: A[m=lane&15][k=qd*8+j]
      const int m = wv * 32 + rt * 16 + mr;
      const float4v a0 = *(const float4v*)&Als[((2 * qd) * 128 + m) * 4];
      const float4v a1 = *(const float4v*)&Als[((2 * qd + 1) * 128 + m) * 4];
      short8 f;
      f[0] = (short)f2bf(a0[0]); f[1] = (short)f2bf(a0[1]);
      f[2] = (short)f2bf(a0[2]); f[3] = (short)f2bf(a0[3]);
      f[4] = (short)f2bf(a1[0]); f[5] = (short)f2bf(a1[1]);
      f[6] = (short)f2bf(a1[2]); f[7] = (short)f2bf(a1[3]);
      af[rt] = f;
    }
#pragma unroll
    for (int ct = 0; ct < 8; ++ct) {   // B frag: B[k=qd*8+j][n=lane&15]
      const short8 bf = *(const short8*)&Bls[(qd * 128 + ct * 16 + mr) * 8];
      acc[0][ct] = __builtin_amdgcn_mfma_f32_16x16x32_bf16(af[0], bf, acc[0][ct], 0, 0, 0);
      acc[1][ct] = __builtin_amdgcn_mfma_f32_16x16x32_bf16(af[1], bf, acc[1][ct], 0, 0, 0);
    }
  }
  // C/D layout: col = lane&15, row = (lane>>4)*4 + j
#pragma unroll
  for (int rt = 0; rt < 2; ++rt) {
    const int rb = m0 + wv * 32 + rt * 16 + qd * 4;
#pragma unroll
    for (int ct = 0; ct < 8; ++ct) {
      const int col = ct * 16 + mr;
#pragma unroll
      for (int j = 0; j < 4; ++j) {
        const int r = rb + j;
        if (r < NN) H1b[(size_t)r * HID + col] = f2bf(acc[rt][ct][j]);
      }
    }
  }
}

// ---------------- GEMM2: PQ = bf16(R1b @ Wpq)  [NN x 80] ----------------
__global__ __launch_bounds__(256) void k_gemm2(const unsigned short* __restrict__ R1b,
    const unsigned short* __restrict__ WpqT, const unsigned short* __restrict__ zbuf,
    unsigned short* __restrict__ PQ) {
  __shared__ unsigned short Als[512 * 8];  // chunk = kg8*128+m
  __shared__ unsigned short Bls[320 * 8];  // chunk = kg8*80+n
  const int t = threadIdx.x;
  const int wv = t >> 6, lane = t & 63;
  const int qd = lane >> 4, mr = lane & 15;
  const int m0 = blockIdx.x * 128;

  float4v acc[2][5];
  const float4v zf4 = {0.f, 0.f, 0.f, 0.f};
#pragma unroll
  for (int a = 0; a < 2; ++a)
#pragma unroll
    for (int b = 0; b < 5; ++b) acc[a][b] = zf4;

  for (int kk = 0; kk < 8; ++kk) {
    const int k0 = kk * 32;
    __syncthreads();
#pragma unroll
    for (int i = 0; i < 2; ++i) {
      const int cb = (wv * 2 + i) * 64;
      const int q = cb + lane;
      const int kg = q >> 7, m = q & 127;
      const int gm = m0 + m;
      const unsigned short* gp = (gm < NN) ? (R1b + (size_t)gm * K2 + k0 + kg * 8) : zbuf;
      gl_lds16(gp, &Als[cb * 8]);
    }
    // B: 320 chunks = 5 wave-instrs (wv 0..3 do inst wv; wv 0 also inst 4)
    {
      const int cb = wv * 64;
      const int q = cb + lane;
      const int kg = q / 80, n = q % 80;
      gl_lds16(WpqT + n * K2 + k0 + kg * 8, &Bls[cb * 8]);
      if (wv == 0) {
        const int cb2 = 4 * 64;
        const int q2 = cb2 + lane;
        const int kg2 = q2 / 80, n2 = q2 % 80;
        gl_lds16(WpqT + n2 * K2 + k0 + kg2 * 8, &Bls[cb2 * 8]);
      }
    }
    __syncthreads();
    short8 af[2];
#pragma unroll
    for (int rt = 0; rt < 2; ++rt)
      af[rt] = *(const short8*)&Als[(qd * 128 + wv * 32 + rt * 16 + mr) * 8];
#pragma unroll
    for (int ct = 0; ct < 5; ++ct) {
      const short8 bf = *(const short8*)&Bls[(qd * 80 + ct * 16 + mr) * 8];
      acc[0][ct] = __builtin_amdgcn_mfma_f32_16x16x32_bf16(af[0], bf, acc[0][ct], 0, 0, 0);
      acc[1][ct] = __builtin_amdgcn_mfma_f32_16x16x32_bf16(af[1], bf, acc[1][ct], 0, 0, 0);
    }
  }
#pragma unroll
  for (int rt = 0; rt < 2; ++rt) {
    const int rb = m0 + wv * 32 + rt * 16 + qd * 4;
#pragma unroll
    for (int ct = 0; ct < 5; ++ct) {
      const int col = ct * 16 + mr;
#pragma unroll
      for (int j = 0; j < 4; ++j) {
        const int r = rb + j;
        if (r < NN) PQ[(size_t)r * NPQ + col] = f2bf(acc[rt][ct][j]);
      }
    }
  }
}

// ---------------- gather helper v3: scalarized edge stream, padded tail batch ----------------
// e0/e1 readfirstlane'd -> edge-index loads are uniform (scalar s_load path) and the
// gather base H32 + q.x*64 is SGPR-computed; per-edge VALU = 2 unpack + 2 fmac.
// Full batches of 8 load contiguous (mergeable); the remainder is ONE clamped batch
// (index clamped to e1-1 = valid row, weight zeroed) -> no serial dependent tail.
__device__ __forceinline__ void fma8(const int2* __restrict__ q,
    const unsigned* __restrict__ H32, int lane, float& ax, float& ay) {
#pragma unroll
  for (int j = 0; j < 8; ++j) {
    const unsigned d = H32[(size_t)q[j].x * 64 + lane];
    const float w = __int_as_float(q[j].y);
    ax += w * __uint_as_float(d << 16);
    ay += w * __uint_as_float(d & 0xffff0000u);
  }
}

__device__ __forceinline__ void ldc8(const int2* __restrict__ cw, int eb, int e1,
                                     int2* __restrict__ q) {
  const int e1c = e1 - 1;
#pragma unroll
  for (int j = 0; j < 8; ++j) {
    const int ee = eb + j;
    int2 t = cw[(ee < e1) ? ee : e1c];   // clamped: always a real edge of some node
    t.y = (ee < e1) ? t.y : 0;           // zero weight kills padded edges
    q[j] = t;
  }
}

__device__ __forceinline__ void agg_row128(const int2* __restrict__ cw, int e0u, int e1u,
    const unsigned* __restrict__ H32, int lane, float& ax, float& ay) {
  const int e0 = __builtin_amdgcn_readfirstlane(e0u);
  const int e1 = __builtin_amdgcn_readfirstlane(e1u);
  const int deg = e1 - e0;
  if (deg <= 0) return;
  const int nfull = deg >> 3;
  const int rem = deg & 7;
  int2 q[8], qn[8];
  if (nfull == 0) {                      // small row (knn typical): one clamped batch
    ldc8(cw, e0, e1, q);
    fma8(q, H32, lane, ax, ay);
    return;
  }
#pragma unroll
  for (int j = 0; j < 8; ++j) q[j] = cw[e0 + j];
  for (int b = 0; b < nfull; ++b) {
    const int nb0 = e0 + (b + 1) * 8;
    if (b + 1 < nfull) {                 // prefetch next full batch (contiguous)
#pragma unroll
      for (int j = 0; j < 8; ++j) qn[j] = cw[nb0 + j];
    } else if (rem) {                    // prefetch clamped remainder batch
      ldc8(cw, nb0, e1, qn);
    }
    fma8(q, H32, lane, ax, ay);
    if (b + 1 < nfull || rem) {
#pragma unroll
      for (int j = 0; j < 8; ++j) q[j] = qn[j];
    }
  }
  if (rem) fma8(q, H32, lane, ax, ay);
}

// ---------------- layer-1 aggregation: one wave per node, BOTH graphs ----------------
__global__ __launch_bounds__(256) void k_agg1(
    const int* __restrict__ rp_s, const int2* __restrict__ colw_s, const float* __restrict__ dinv_s,
    const int* __restrict__ rp_k, const int2* __restrict__ colw_k, const float* __restrict__ dinv_k,
    const unsigned short* __restrict__ H, const float* __restrict__ bias,
    unsigned short* __restrict__ out) {
  const int wv = threadIdx.x >> 6, lane = threadIdx.x & 63;
  const int c = blockIdx.x * 4 + wv;
  if (c >= NN) return;
  const unsigned* H32 = (const unsigned*)H;
  const float dcs = dinv_s[c];
  const float dck = dinv_k[c];
  const unsigned pc = H32[(size_t)c * 64 + lane];
  const float slo = __uint_as_float(pc << 16);
  const float shi = __uint_as_float(pc & 0xffff0000u);
  float ax = dcs * slo, ay = dcs * shi;   // structural self
  float bx = dck * slo, by = dck * shi;   // knn self
  agg_row128(colw_s, rp_s[c], rp_s[c + 1], H32, lane, ax, ay);
  agg_row128(colw_k, rp_k[c], rp_k[c + 1], H32, lane, bx, by);
  const float2 bb = ((const float2*)bias)[lane];
  const float o0 = fmaxf(dcs * ax + bb.x, 0.f);
  const float o1 = fmaxf(dcs * ay + bb.y, 0.f);
  const float o2 = fmaxf(dck * bx + bb.x, 0.f);
  const float o3 = fmaxf(dck * by + bb.y, 0.f);
  unsigned* orow = (unsigned*)(out + (size_t)c * K2);
  orow[lane]      = (unsigned)f2bf(o0) | ((unsigned)f2bf(o1) << 16);
  orow[64 + lane] = (unsigned)f2bf(o2) | ((unsigned)f2bf(o3) << 16);
}

// ---------------- tail: logits = agg_s(P) + agg_k(Q) + cb; log_softmax ----------------
// wave per node; 3 groups of 20 lanes gather edges in parallel (strided), combine via shfl
__global__ __launch_bounds__(256) void k_aggf(
    const int* __restrict__ rp_s, const int2* __restrict__ colw_s, const float* __restrict__ dinv_s,
    const int* __restrict__ rp_k, const int2* __restrict__ colw_k, const float* __restrict__ dinv_k,
    const unsigned short* __restrict__ PQ, const float* __restrict__ cb,
    float* __restrict__ out) {
  const int wv = threadIdx.x >> 6, lane = threadIdx.x & 63;
  const int c = blockIdx.x * 4 + wv;
  if (c >= NN) return;
  const unsigned* PQ32 = (const unsigned*)PQ;
  const int g = lane / 20;        // 0..2 active groups (lanes 60-63 idle)
  const int l = lane % 20;        // dword index: P dwords 0-19, Q dwords 20-39
  float sx = 0.f, sy = 0.f, kx = 0.f, ky = 0.f;
  if (g < 3) {
    // structural edges -> P
    {
      const int e1 = rp_s[c + 1];
      int e = rp_s[c] + g;
      for (; e + 9 < e1; e += 12) {
        const int2 q0 = colw_s[e], q1 = colw_s[e + 3], q2 = colw_s[e + 6], q3 = colw_s[e + 9];
        const unsigned d0 = PQ32[(size_t)q0.x * 40 + l];
        const unsigned d1 = PQ32[(size_t)q1.x * 40 + l];
        const unsigned d2 = PQ32[(size_t)q2.x * 40 + l];
        const unsigned d3 = PQ32[(size_t)q3.x * 40 + l];
        const float w0 = __int_as_float(q0.y), w1 = __int_as_float(q1.y);
        const float w2 = __int_as_float(q2.y), w3 = __int_as_float(q3.y);
        sx += w0 * __uint_as_float(d0 << 16) + w1 * __uint_as_float(d1 << 16)
            + w2 * __uint_as_float(d2 << 16) + w3 * __uint_as_float(d3 << 16);
        sy += w0 * __uint_as_float(d0 & 0xffff0000u) + w1 * __uint_as_float(d1 & 0xffff0000u)
            + w2 * __uint_as_float(d2 & 0xffff0000u) + w3 * __uint_as_float(d3 & 0xffff0000u);
      }
      for (; e < e1; e += 3) {
        const int2 q = colw_s[e];
        const unsigned d = PQ32[(size_t)q.x * 40 + l];
        const float w = __int_as_float(q.y);
        sx += w * __uint_as_float(d << 16);
        sy += w * __uint_as_float(d & 0xffff0000u);
      }
    }
    // knn edges -> Q
    {
      const int e1 = rp_k[c + 1];
      int e = rp_k[c] + g;
      for (; e < e1; e += 3) {
        const int2 q = colw_k[e];
        const unsigned d = PQ32[(size_t)q.x * 40 + 20 + l];
        const float w = __int_as_float(q.y);
        kx += w * __uint_as_float(d << 16);
        ky += w * __uint_as_float(d & 0xffff0000u);
      }
    }
  }
  // combine 3 group partials into lanes 0-19
  sx += __shfl(sx, lane + 20) + __shfl(sx, lane + 40);
  sy += __shfl(sy, lane + 20) + __shfl(sy, lane + 40);
  kx += __shfl(kx, lane + 20) + __shfl(kx, lane + 40);
  ky += __shfl(ky, lane + 20) + __shfl(ky, lane + 40);

  float lo = 0.f, hi = 0.f;
  if (lane < 20) {
    const float dcs = dinv_s[c], dck = dinv_k[c];
    const unsigned dP = PQ32[(size_t)c * 40 + lane];
    const unsigned dQ = PQ32[(size_t)c * 40 + 20 + lane];
    const float2 cbb = ((const float2*)cb)[lane];
    lo = dcs * (sx + dcs * __uint_as_float(dP << 16))
       + dck * (kx + dck * __uint_as_float(dQ << 16)) + cbb.x;
    hi = dcs * (sy + dcs * __uint_as_float(dP & 0xffff0000u))
       + dck * (ky + dck * __uint_as_float(dQ & 0xffff0000u)) + cbb.y;
  }
  // log_softmax over 40 (lanes 0-19 hold pairs)
  float m = (lane < 20) ? fmaxf(lo, hi) : -3.4e38f;
#pragma unroll
  for (int off = 1; off < 64; off <<= 1) m = fmaxf(m, __shfl_xor(m, off));
  float s = (lane < 20) ? (expf(lo - m) + expf(hi - m)) : 0.f;
#pragma unroll
  for (int off = 1; off < 64; off <<= 1) s += __shfl_xor(s, off);
  const float lse = m + logf(s);
  if (lane < 20) {
    float2 o; o.x = lo - lse; o.y = hi - lse;
    ((float2*)(out + (size_t)c * CO))[lane] = o;
  }
}

extern "C" void kernel_launch(void* const* d_in, const int* in_sizes, int n_in,
                              void* d_out, int out_size, void* d_ws, size_t ws_size,
                              hipStream_t stream) {
  const float* x  = (const float*)d_in[0];
  const int* ei   = (const int*)d_in[1];   // [2][E]: row0 = src, row1 = tgt
  const int* eik  = (const int*)d_in[2];
  const float* W1 = (const float*)d_in[3];
  const float* b1 = (const float*)d_in[4];
  const float* W2 = (const float*)d_in[5];
  const float* b2 = (const float*)d_in[6];
  const float* Wl = (const float*)d_in[7];
  const float* bl = (const float*)d_in[8];
  float* out = (float*)d_out;
  const int E  = in_sizes[1] / 2;
  const int EK = in_sizes[2] / 2;

  // workspace layout (~125 MB), 256B-aligned slots
  char* p = (char*)d_ws;
  size_t off = 0;
  auto alloc = [&](size_t bytes) -> void* {
    void* r = (void*)(p + off);
    off += (bytes + 255) & ~(size_t)255;
    return r;
  };
  int* gcur_s = (int*)alloc((size_t)NBUCK * 4);
  int* gcur_k = (int*)alloc((size_t)NBUCK * 4);
  void* zbuf = alloc(256);                 // zero redirect target for OOB tiles
  const size_t zero_span = off;            // memset covers gcur_s, gcur_k, zbuf
  int* bscan_s = (int*)alloc((size_t)NBUCK * 4);
  int* bscan_k = (int*)alloc((size_t)NBUCK * 4);
  float* dinv_s = (float*)alloc((size_t)NN * 4);
  float* dinv_k = (float*)alloc((size_t)NN * 4);
  int* rp_s = (int*)alloc((size_t)(NN + 1) * 4);
  int* rp_k = (int*)alloc((size_t)(NN + 1) * 4);
  unsigned short* W1T = (unsigned short*)alloc((size_t)HID * KP1 * 2);
  unsigned short* WpqT = (unsigned short*)alloc((size_t)NPQ * K2 * 2);
  float* cbv = (float*)alloc((size_t)CO * 4);
  int* gbin_s = (int*)alloc((size_t)NBUCK * CAPB_S * 4);    // 14.4 MB
  int* gbin_k = (int*)alloc((size_t)NBUCK * CAPB_K * 4);    // 2.4 MB
  int2* colw_s = (int2*)alloc((size_t)E * 8);               // 25.6 MB
  int2* colw_k = (int2*)alloc((size_t)EK * 8);              // 4 MB
  unsigned short* H1b = (unsigned short*)alloc((size_t)NN * HID * 2);   // 25.6 MB
  unsigned short* R1b = (unsigned short*)alloc((size_t)NN * K2 * 2);    // 51.2 MB
  unsigned short* PQ = H1b;   // alias: H1b dead after agg1; PQ = [NN x 80] bf16 (16 MB)

  hipMemsetAsync(d_ws, 0, zero_span, stream);

  // CSR build: bin -> scan -> per-bucket exact CSR (+dinv) -> fuse dinv[src] into edges
  const int nb1S = (E + 4095) / 4096;
  const int nb1K = (EK + 4095) / 4096;
  k_bin<<<nb1S + nb1K, 256, 0, stream>>>(ei, E, nb1S, gcur_s, gbin_s, eik, EK, gcur_k, gbin_k);
  k_bscan<<<2, 512, 0, stream>>>(gcur_s, bscan_s, gcur_k, bscan_k);
  k_csr<<<2 * NBUCK, 256, 0, stream>>>(gcur_s, gbin_s, bscan_s, rp_s, colw_s, dinv_s,
                                       gcur_k, gbin_k, bscan_k, rp_k, colw_k, dinv_k);
  const int nbF = (E + 255) / 256;
  const int nbFk = (EK + 255) / 256;
  k_fuse<<<nbF + nbFk, 256, 0, stream>>>(colw_s, dinv_s, E, nbF, colw_k, dinv_k, EK);

  // weight prep
  k_w1t<<<(HID * KP1) / 256, 256, 0, stream>>>(W1, W1T);
  k_wpq<<<NPQ, 256, 0, stream>>>(W2, Wl, b2, bl, WpqT, cbv);

  // layer 1: shared GEMM, fused dual aggregation (one wave per node)
  k_gemm1<<<(NN + 127) / 128, 256, 0, stream>>>(x, W1T, (const float*)zbuf, H1b);
  const int nbAgg = (NN + 3) / 4;
  k_agg1<<<nbAgg, 256, 0, stream>>>(rp_s, colw_s, dinv_s, rp_k, colw_k, dinv_k, H1b, b1, R1b);

  // folded tail: PQ GEMM + fused aggregation/log_softmax
  k_gemm2<<<(NN + 127) / 128, 256, 0, stream>>>(R1b, WpqT, (const unsigned short*)zbuf, PQ);
  k_aggf<<<nbAgg, 256, 0, stream>>>(rp_s, colw_s, dinv_s, rp_k, colw_k, dinv_k, PQ, cbv, out);
}

// Round 4
// 722.759 us; speedup vs baseline: 1.0708x; 1.0090x over previous
//
#include <hip/hip_runtime.h>
#include <stdint.h>

// Problem constants (match reference)
#define NN   100000   // nodes
#define FIN  500      // input features
#define HID  128      // hidden
#define KP1  512      // FIN padded to mult of 32 for MFMA K-loop
#define K2   256      // 2*HID (GEMM2 K)
#define CO   40       // classes
#define NPQ  80       // folded tail GEMM N (P|Q)
#define NBUCK 391     // ceil(NN/256) coarse buckets (target>>8)
#define CAPB_S 9216   // structural bucket capacity (mean 8184, +11 sigma)
#define CAPB_K 1536   // knn bucket capacity (mean 1279, +7 sigma)

typedef __attribute__((ext_vector_type(8))) short short8;
typedef __attribute__((ext_vector_type(4))) float float4v;
typedef __attribute__((address_space(3))) unsigned int as3_u32;
typedef __attribute__((address_space(1))) unsigned int as1_u32;

__device__ __forceinline__ unsigned short f2bf(float f) {
  unsigned u = __float_as_uint(f);
  u = u + 0x7fffu + ((u >> 16) & 1u);   // RNE
  return (unsigned short)(u >> 16);
}
__device__ __forceinline__ float bf2f(unsigned short s) {
  return __uint_as_float(((unsigned)s) << 16);
}
__device__ __forceinline__ void gl_lds16(const void* g, void* l) {
  __builtin_amdgcn_global_load_lds((const as1_u32*)g, (as3_u32*)l, 16, 0, 0);
}

// ---------------- phase 1: bin edges by target>>8 (both graphs fused) ----------------
__global__ __launch_bounds__(256) void k_bin(
    const int* __restrict__ ei, int nS, int nb1S, int* __restrict__ gcur_s, int* __restrict__ gbin_s,
    const int* __restrict__ eik, int nK, int* __restrict__ gcur_k, int* __restrict__ gbin_k) {
  __shared__ int cnt[NBUCK];
  __shared__ int base[NBUCK];
  const int b = blockIdx.x;
  const bool knn = (b >= nb1S);
  const int* src = knn ? eik      : ei;
  const int* tgt = knn ? eik + nK : ei + nS;
  const int n    = knn ? nK : nS;
  int* gcur      = knn ? gcur_k : gcur_s;
  int* gbin      = knn ? gbin_k : gbin_s;
  const int capb = knn ? CAPB_K : CAPB_S;
  const int ebase = (knn ? b - nb1S : b) * 4096;
  const int t = threadIdx.x;

  for (int i = t; i < NBUCK; i += 256) cnt[i] = 0;
  __syncthreads();
  int s[16], g[16];
#pragma unroll
  for (int i = 0; i < 16; ++i) {
    const int e = ebase + i * 256 + t;
    const bool v = e < n;
    s[i] = v ? src[e] : 0;
    g[i] = v ? tgt[e] : -1;
    if (v) atomicAdd(&cnt[g[i] >> 8], 1);
  }
  __syncthreads();
  for (int i = t; i < NBUCK; i += 256) {       // reserve global space, reset local cursor
    const int c = cnt[i];
    base[i] = c ? atomicAdd(&gcur[i], c) : 0;
    cnt[i] = 0;
  }
  __syncthreads();
#pragma unroll
  for (int i = 0; i < 16; ++i) {
    if (g[i] >= 0) {
      const int bkt = g[i] >> 8;
      const int pos = base[bkt] + atomicAdd(&cnt[bkt], 1);
      if (pos < capb) gbin[bkt * capb + pos] = (s[i] << 8) | (g[i] & 255);
    }
  }
}

// ---------------- exclusive scan of bucket totals (2 blocks: structural, knn) ----------------
__global__ __launch_bounds__(512) void k_bscan(const int* __restrict__ gcur_s, int* __restrict__ bscan_s,
                                               const int* __restrict__ gcur_k, int* __restrict__ bscan_k) {
  __shared__ int sd[512];
  const int* gcur = blockIdx.x ? gcur_k : gcur_s;
  int* bscan      = blockIdx.x ? bscan_k : bscan_s;
  const int t = threadIdx.x;
  const int v = (t < NBUCK) ? gcur[t] : 0;
  sd[t] = v;
  __syncthreads();
  for (int off = 1; off < 512; off <<= 1) {
    const int x = (t >= off) ? sd[t - off] : 0;
    __syncthreads(); sd[t] += x; __syncthreads();
  }
  if (t < NBUCK) bscan[t] = sd[t] - v;   // exclusive
}

// ---------------- phase 2: per-bucket exact CSR + dinv (both graphs fused) ----------------
// colw entries: {src, w} — w filled later by k_fuse
__global__ __launch_bounds__(256) void k_csr(
    const int* __restrict__ gcur_s, const int* __restrict__ gbin_s, const int* __restrict__ bscan_s,
    int* __restrict__ rp_s, int2* __restrict__ colw_s, float* __restrict__ dinv_s,
    const int* __restrict__ gcur_k, const int* __restrict__ gbin_k, const int* __restrict__ bscan_k,
    int* __restrict__ rp_k, int2* __restrict__ colw_k, float* __restrict__ dinv_k) {
  __shared__ int cnt[256];
  __shared__ int base[256];
  const int b0 = blockIdx.x;
  const bool knn = (b0 >= NBUCK);
  const int b = knn ? b0 - NBUCK : b0;
  const int* gcur  = knn ? gcur_k  : gcur_s;
  const int* gbin  = knn ? gbin_k  : gbin_s;
  const int* bscan = knn ? bscan_k : bscan_s;
  int* rp     = knn ? rp_k   : rp_s;
  int2* colw  = knn ? colw_k : colw_s;
  float* dinv = knn ? dinv_k : dinv_s;
  const int capb = knn ? CAPB_K : CAPB_S;
  const int t = threadIdx.x;
  int nB = gcur[b]; if (nB > capb) nB = capb;
  const int gb0 = b * capb;
  const int gbase = bscan[b];

  cnt[t] = 0;
  __syncthreads();
  for (int i = t; i < nB; i += 256) atomicAdd(&cnt[gbin[gb0 + i] & 255], 1);
  __syncthreads();
  const int myc = cnt[t];
  base[t] = myc;
  __syncthreads();
  for (int off = 1; off < 256; off <<= 1) {   // inclusive Hillis-Steele
    const int x = (t >= off) ? base[t - off] : 0;
    __syncthreads(); base[t] += x; __syncthreads();
  }
  const int excl = base[t] - myc;
  const int tg = b * 256 + t;
  if (tg < NN) { rp[tg] = gbase + excl; dinv[tg] = rsqrtf((float)(myc + 1)); }
  if (tg == NN) rp[NN] = gbase + excl;        // only in last bucket (t=160)
  __syncthreads();
  base[t] = excl; cnt[t] = 0;
  __syncthreads();
  for (int i = t; i < nB; i += 256) {
    const int e = gbin[gb0 + i];
    const int tl = e & 255;
    const int pos = atomicAdd(&cnt[tl], 1);
    colw[gbase + base[tl] + pos] = make_int2(e >> 8, 0);
  }
}

// ---------------- fill w = dinv[src] into colw (both graphs) ----------------
__global__ __launch_bounds__(256) void k_fuse(
    int2* __restrict__ colw_s, const float* __restrict__ dinv_s, int nS, int nbF,
    int2* __restrict__ colw_k, const float* __restrict__ dinv_k, int nK) {
  const int b = blockIdx.x;
  if (b < nbF) {
    const int i = b * 256 + threadIdx.x;
    if (i < nS) {
      const int s = colw_s[i].x;
      colw_s[i].y = __float_as_int(dinv_s[s]);
    }
  } else {
    const int i = (b - nbF) * 256 + threadIdx.x;
    if (i < nK) {
      const int s = colw_k[i].x;
      colw_k[i].y = __float_as_int(dinv_k[s]);
    }
  }
}

// ---------------- weight prep ----------------
__global__ void k_w1t(const float* __restrict__ W1, unsigned short* __restrict__ W1T) {
  int idx = blockIdx.x * 256 + threadIdx.x;      // 128*512
  int n = idx >> 9, k = idx & 511;
  float v = (k < FIN) ? W1[k * HID + n] : 0.f;
  W1T[idx] = f2bf(v);
}
// WpqT[n][k], n<80, k<256: n<40 -> P col o=n (Wlin left), n>=40 -> Q col o=n-40 (Wlin right)
// cb[o] = blin[o] + sum_j b2[j]*(Wl[o][j] + Wl[o][40+j])
__global__ void k_wpq(const float* __restrict__ W2, const float* __restrict__ Wl,
                      const float* __restrict__ b2, const float* __restrict__ bl,
                      unsigned short* __restrict__ WpqT, float* __restrict__ cb) {
  const int idx = blockIdx.x * 256 + threadIdx.x;   // 80*256 = 20480
  const int n = idx >> 8, k = idx & 255;
  const int o = (n < CO) ? n : n - CO;
  const int joff = (n < CO) ? 0 : CO;
  float s = 0.f;
#pragma unroll 8
  for (int j = 0; j < CO; ++j) s += W2[k * CO + j] * Wl[o * NPQ + joff + j];
  WpqT[n * K2 + k] = f2bf(s);
  if (blockIdx.x == 0 && threadIdx.x < CO) {
    const int oo = threadIdx.x;
    float c = bl[oo];
    for (int j = 0; j < CO; ++j) c += b2[j] * (Wl[oo * NPQ + j] + Wl[oo * NPQ + CO + j]);
    cb[oo] = c;
  }
}

// ---------------- GEMM1: H1b = bf16(x @ W1)  [NN x 128] ----------------
__global__ __launch_bounds__(256) void k_gemm1(const float* __restrict__ x,
    const unsigned short* __restrict__ W1T, const float* __restrict__ zbuf,
    unsigned short* __restrict__ H1b) {
  __shared__ float Als[1024 * 4];          // chunk = kg4*128+m, 4 floats each (16B)
  __shared__ unsigned short Bls[512 * 8];  // chunk = kg8*128+n, 8 bf16 each (16B)
  const int t = threadIdx.x;
  const int wv = t >> 6, lane = t & 63;
  const int qd = lane >> 4, mr = lane & 15;
  const int m0 = blockIdx.x * 128;

  float4v acc[2][8];
  const float4v zf4 = {0.f, 0.f, 0.f, 0.f};
#pragma unroll
  for (int a = 0; a < 2; ++a)
#pragma unroll
    for (int b = 0; b < 8; ++b) acc[a][b] = zf4;

  for (int kk = 0; kk < 16; ++kk) {
    const int k0 = kk * 32;
    __syncthreads();
#pragma unroll
    for (int i = 0; i < 4; ++i) {
      const int cb = (wv * 4 + i) * 64;
      const int q = cb + lane;
      const int kg = q >> 7, m = q & 127;
      const int gm = m0 + m, kb = k0 + kg * 4;   // 500 % 4 == 0 -> never straddles
      const float* gp = (gm < NN && kb < FIN) ? (x + (size_t)gm * FIN + kb) : zbuf;
      gl_lds16(gp, &Als[cb * 4]);
    }
#pragma unroll
    for (int i = 0; i < 2; ++i) {
      const int cb = (wv * 2 + i) * 64;
      const int q = cb + lane;
      const int kg = q >> 7, n = q & 127;
      const unsigned short* gp = W1T + n * KP1 + k0 + kg * 8;
      gl_lds16(gp, &Bls[cb * 8]);
    }
    __syncthreads();
    short8 af[2];
#pragma unroll
    for (int rt = 0; rt < 2; ++rt) {   // A frag: A[m=lane&15][k=qd*8+j]
      const int m = wv * 32 + rt * 16 + mr;
      const float4v a0 = *(const float4v*)&Als[((2 * qd) * 128 + m) * 4];
      const float4v a1 = *(const float4v*)&Als[((2 * qd + 1) * 128 + m) * 4];
      short8 f;
      f[0] = (short)f2bf(a0[0]); f[1] = (short)f2bf(a0[1]);
      f[2] = (short)f2bf(a0[2]); f[3] = (short)f2bf(a0[3]);
      f[4] = (short)f2bf(a1[0]); f[5] = (short)f2bf(a1[1]);
      f[6] = (short)f2bf(a1[2]); f[7] = (short)f2bf(a1[3]);
      af[rt] = f;
    }
#pragma unroll
    for (int ct = 0; ct < 8; ++ct) {   // B frag: B[k=qd*8+j][n=lane&15]
      const short8 bf = *(const short8*)&Bls[(qd * 128 + ct * 16 + mr) * 8];
      acc[0][ct] = __builtin_amdgcn_mfma_f32_16x16x32_bf16(af[0], bf, acc[0][ct], 0, 0, 0);
      acc[1][ct] = __builtin_amdgcn_mfma_f32_16x16x32_bf16(af[1], bf, acc[1][ct], 0, 0, 0);
    }
  }
  // C/D layout: col = lane&15, row = (lane>>4)*4 + j
#pragma unroll
  for (int rt = 0; rt < 2; ++rt) {
    const int rb = m0 + wv * 32 + rt * 16 + qd * 4;
#pragma unroll
    for (int ct = 0; ct < 8; ++ct) {
      const int col = ct * 16 + mr;
#pragma unroll
      for (int j = 0; j < 4; ++j) {
        const int r = rb + j;
        if (r < NN) H1b[(size_t)r * HID + col] = f2bf(acc[rt][ct][j]);
      }
    }
  }
}

// ---------------- GEMM2: PQ = bf16(R1b @ Wpq)  [NN x 80] ----------------
__global__ __launch_bounds__(256) void k_gemm2(const unsigned short* __restrict__ R1b,
    const unsigned short* __restrict__ WpqT, const unsigned short* __restrict__ zbuf,
    unsigned short* __restrict__ PQ) {
  __shared__ unsigned short Als[512 * 8];  // chunk = kg8*128+m
  __shared__ unsigned short Bls[320 * 8];  // chunk = kg8*80+n
  const int t = threadIdx.x;
  const int wv = t >> 6, lane = t & 63;
  const int qd = lane >> 4, mr = lane & 15;
  const int m0 = blockIdx.x * 128;

  float4v acc[2][5];
  const float4v zf4 = {0.f, 0.f, 0.f, 0.f};
#pragma unroll
  for (int a = 0; a < 2; ++a)
#pragma unroll
    for (int b = 0; b < 5; ++b) acc[a][b] = zf4;

  for (int kk = 0; kk < 8; ++kk) {
    const int k0 = kk * 32;
    __syncthreads();
#pragma unroll
    for (int i = 0; i < 2; ++i) {
      const int cb = (wv * 2 + i) * 64;
      const int q = cb + lane;
      const int kg = q >> 7, m = q & 127;
      const int gm = m0 + m;
      const unsigned short* gp = (gm < NN) ? (R1b + (size_t)gm * K2 + k0 + kg * 8) : zbuf;
      gl_lds16(gp, &Als[cb * 8]);
    }
    // B: 320 chunks = 5 wave-instrs (wv 0..3 do inst wv; wv 0 also inst 4)
    {
      const int cb = wv * 64;
      const int q = cb + lane;
      const int kg = q / 80, n = q % 80;
      gl_lds16(WpqT + n * K2 + k0 + kg * 8, &Bls[cb * 8]);
      if (wv == 0) {
        const int cb2 = 4 * 64;
        const int q2 = cb2 + lane;
        const int kg2 = q2 / 80, n2 = q2 % 80;
        gl_lds16(WpqT + n2 * K2 + k0 + kg2 * 8, &Bls[cb2 * 8]);
      }
    }
    __syncthreads();
    short8 af[2];
#pragma unroll
    for (int rt = 0; rt < 2; ++rt)
      af[rt] = *(const short8*)&Als[(qd * 128 + wv * 32 + rt * 16 + mr) * 8];
#pragma unroll
    for (int ct = 0; ct < 5; ++ct) {
      const short8 bf = *(const short8*)&Bls[(qd * 80 + ct * 16 + mr) * 8];
      acc[0][ct] = __builtin_amdgcn_mfma_f32_16x16x32_bf16(af[0], bf, acc[0][ct], 0, 0, 0);
      acc[1][ct] = __builtin_amdgcn_mfma_f32_16x16x32_bf16(af[1], bf, acc[1][ct], 0, 0, 0);
    }
  }
#pragma unroll
  for (int rt = 0; rt < 2; ++rt) {
    const int rb = m0 + wv * 32 + rt * 16 + qd * 4;
#pragma unroll
    for (int ct = 0; ct < 5; ++ct) {
      const int col = ct * 16 + mr;
#pragma unroll
      for (int j = 0; j < 4; ++j) {
        const int r = rb + j;
        if (r < NN) PQ[(size_t)r * NPQ + col] = f2bf(acc[rt][ct][j]);
      }
    }
  }
}

// ---------------- gather helpers v4: scalar index batches + pipelined gathers ----------------
// ld8: load 8 edge (src,w) pairs. Full batches are contiguous (mergeable s_load);
// tail batches clamp the index to e1-1 (valid row) and zero the weight.
__device__ __forceinline__ void ld8(const int2* __restrict__ cw, int base, int e1, bool full,
                                    int2* __restrict__ q) {
  if (full) {
#pragma unroll
    for (int j = 0; j < 8; ++j) q[j] = cw[base + j];
  } else {
    const int e1c = e1 - 1;
#pragma unroll
    for (int j = 0; j < 8; ++j) {
      const int ee = base + j;
      int2 t = cw[(ee < e1) ? ee : e1c];
      t.y = (ee < e1) ? t.y : 0;
      q[j] = t;
    }
  }
}
// g8: issue the 8 row gathers (SGPR base + lane offset) into VGPR buffer d
__device__ __forceinline__ void g8(const int2* __restrict__ q,
    const unsigned* __restrict__ H32, int lane, unsigned* __restrict__ d) {
#pragma unroll
  for (int j = 0; j < 8; ++j) d[j] = H32[(size_t)q[j].x * 64 + lane];
}
// f8: consume a gathered batch
__device__ __forceinline__ void f8(const int2* __restrict__ q, const unsigned* __restrict__ d,
                                   float& ax, float& ay) {
#pragma unroll
  for (int j = 0; j < 8; ++j) {
    const float w = __int_as_float(q[j].y);
    ax += w * __uint_as_float(d[j] << 16);
    ay += w * __uint_as_float(d[j] & 0xffff0000u);
  }
}

// ---------------- layer-1 aggregation: one wave per node, BOTH graphs ----------------
// v4: 2-deep ping-pong gather pipeline (16 structural gathers in flight) + knn batch 0
// issued up-front (concurrent with entire structural pass; kills the serial knn tail).
__global__ __launch_bounds__(256) void k_agg1(
    const int* __restrict__ rp_s, const int2* __restrict__ colw_s, const float* __restrict__ dinv_s,
    const int* __restrict__ rp_k, const int2* __restrict__ colw_k, const float* __restrict__ dinv_k,
    const unsigned short* __restrict__ H, const float* __restrict__ bias,
    unsigned short* __restrict__ out) {
  const int wv = threadIdx.x >> 6, lane = threadIdx.x & 63;
  const int c = blockIdx.x * 4 + wv;
  if (c >= NN) return;
  const unsigned* H32 = (const unsigned*)H;
  const int e0s = __builtin_amdgcn_readfirstlane(rp_s[c]);
  const int e1s = __builtin_amdgcn_readfirstlane(rp_s[c + 1]);
  const int e0k = __builtin_amdgcn_readfirstlane(rp_k[c]);
  const int e1k = __builtin_amdgcn_readfirstlane(rp_k[c + 1]);
  const int nbS = (e1s - e0s + 7) >> 3;   // may be 0
  const int nbK = (e1k - e0k + 7) >> 3;

  int2 q0[8], q1[8], qk[8];
  unsigned d0[8], d1[8], dk[8];
  // issue phase: self row + structural batches 0,1 + knn batch 0 all in flight
  const unsigned pc = H32[(size_t)c * 64 + lane];
  if (nbS > 0) { ld8(colw_s, e0s, e1s, e0s + 8 <= e1s, q0); g8(q0, H32, lane, d0); }
  if (nbS > 1) { ld8(colw_s, e0s + 8, e1s, e0s + 16 <= e1s, q1); g8(q1, H32, lane, d1); }
  if (nbK > 0) { ld8(colw_k, e0k, e1k, e0k + 8 <= e1k, qk); g8(qk, H32, lane, dk); }

  const float dcs = dinv_s[c], dck = dinv_k[c];
  const float slo = __uint_as_float(pc << 16);
  const float shi = __uint_as_float(pc & 0xffff0000u);
  float ax = dcs * slo, ay = dcs * shi;   // structural self
  float bx = dck * slo, by = dck * shi;   // knn self

  // structural: pairwise ping-pong, always ~16 gathers outstanding
  int b = 0;
  while (b + 2 < nbS) {
    f8(q0, d0, ax, ay);                   // consume batch b
    {
      const int bs = e0s + (b + 2) * 8;   // issue batch b+2
      ld8(colw_s, bs, e1s, bs + 8 <= e1s, q0);
      g8(q0, H32, lane, d0);
    }
    f8(q1, d1, ax, ay);                   // consume batch b+1
    if (b + 3 < nbS) {
      const int bs = e0s + (b + 3) * 8;   // issue batch b+3
      ld8(colw_s, bs, e1s, bs + 8 <= e1s, q1);
      g8(q1, H32, lane, d1);
    }
    b += 2;
  }
  if (b < nbS) f8(q0, d0, ax, ay);
  if (b + 1 < nbS) f8(q1, d1, ax, ay);

  // knn: batch 0 already in flight since the top; extra batches are rare (deg>8)
  if (nbK > 0) f8(qk, dk, bx, by);
  for (int bk = 1; bk < nbK; ++bk) {
    const int bs = e0k + bk * 8;
    ld8(colw_k, bs, e1k, bs + 8 <= e1k, qk);
    g8(qk, H32, lane, dk);
    f8(qk, dk, bx, by);
  }

  const float2 bb = ((const float2*)bias)[lane];
  const float o0 = fmaxf(dcs * ax + bb.x, 0.f);
  const float o1 = fmaxf(dcs * ay + bb.y, 0.f);
  const float o2 = fmaxf(dck * bx + bb.x, 0.f);
  const float o3 = fmaxf(dck * by + bb.y, 0.f);
  unsigned* orow = (unsigned*)(out + (size_t)c * K2);
  orow[lane]      = (unsigned)f2bf(o0) | ((unsigned)f2bf(o1) << 16);
  orow[64 + lane] = (unsigned)f2bf(o2) | ((unsigned)f2bf(o3) << 16);
}

// ---------------- tail: logits = agg_s(P) + agg_k(Q) + cb; log_softmax ----------------
// wave per node; 3 groups of 20 lanes gather edges in parallel (strided), combine via shfl
__global__ __launch_bounds__(256) void k_aggf(
    const int* __restrict__ rp_s, const int2* __restrict__ colw_s, const float* __restrict__ dinv_s,
    const int* __restrict__ rp_k, const int2* __restrict__ colw_k, const float* __restrict__ dinv_k,
    const unsigned short* __restrict__ PQ, const float* __restrict__ cb,
    float* __restrict__ out) {
  const int wv = threadIdx.x >> 6, lane = threadIdx.x & 63;
  const int c = blockIdx.x * 4 + wv;
  if (c >= NN) return;
  const unsigned* PQ32 = (const unsigned*)PQ;
  const int g = lane / 20;        // 0..2 active groups (lanes 60-63 idle)
  const int l = lane % 20;        // dword index: P dwords 0-19, Q dwords 20-39
  float sx = 0.f, sy = 0.f, kx = 0.f, ky = 0.f;
  if (g < 3) {
    // structural edges -> P
    {
      const int e1 = rp_s[c + 1];
      int e = rp_s[c] + g;
      for (; e + 9 < e1; e += 12) {
        const int2 q0 = colw_s[e], q1 = colw_s[e + 3], q2 = colw_s[e + 6], q3 = colw_s[e + 9];
        const unsigned d0 = PQ32[(size_t)q0.x * 40 + l];
        const unsigned d1 = PQ32[(size_t)q1.x * 40 + l];
        const unsigned d2 = PQ32[(size_t)q2.x * 40 + l];
        const unsigned d3 = PQ32[(size_t)q3.x * 40 + l];
        const float w0 = __int_as_float(q0.y), w1 = __int_as_float(q1.y);
        const float w2 = __int_as_float(q2.y), w3 = __int_as_float(q3.y);
        sx += w0 * __uint_as_float(d0 << 16) + w1 * __uint_as_float(d1 << 16)
            + w2 * __uint_as_float(d2 << 16) + w3 * __uint_as_float(d3 << 16);
        sy += w0 * __uint_as_float(d0 & 0xffff0000u) + w1 * __uint_as_float(d1 & 0xffff0000u)
            + w2 * __uint_as_float(d2 & 0xffff0000u) + w3 * __uint_as_float(d3 & 0xffff0000u);
      }
      for (; e < e1; e += 3) {
        const int2 q = colw_s[e];
        const unsigned d = PQ32[(size_t)q.x * 40 + l];
        const float w = __int_as_float(q.y);
        sx += w * __uint_as_float(d << 16);
        sy += w * __uint_as_float(d & 0xffff0000u);
      }
    }
    // knn edges -> Q
    {
      const int e1 = rp_k[c + 1];
      int e = rp_k[c] + g;
      for (; e < e1; e += 3) {
        const int2 q = colw_k[e];
        const unsigned d = PQ32[(size_t)q.x * 40 + 20 + l];
        const float w = __int_as_float(q.y);
        kx += w * __uint_as_float(d << 16);
        ky += w * __uint_as_float(d & 0xffff0000u);
      }
    }
  }
  // combine 3 group partials into lanes 0-19
  sx += __shfl(sx, lane + 20) + __shfl(sx, lane + 40);
  sy += __shfl(sy, lane + 20) + __shfl(sy, lane + 40);
  kx += __shfl(kx, lane + 20) + __shfl(kx, lane + 40);
  ky += __shfl(ky, lane + 20) + __shfl(ky, lane + 40);

  float lo = 0.f, hi = 0.f;
  if (lane < 20) {
    const float dcs = dinv_s[c], dck = dinv_k[c];
    const unsigned dP = PQ32[(size_t)c * 40 + lane];
    const unsigned dQ = PQ32[(size_t)c * 40 + 20 + lane];
    const float2 cbb = ((const float2*)cb)[lane];
    lo = dcs * (sx + dcs * __uint_as_float(dP << 16))
       + dck * (kx + dck * __uint_as_float(dQ << 16)) + cbb.x;
    hi = dcs * (sy + dcs * __uint_as_float(dP & 0xffff0000u))
       + dck * (ky + dck * __uint_as_float(dQ & 0xffff0000u)) + cbb.y;
  }
  // log_softmax over 40 (lanes 0-19 hold pairs)
  float m = (lane < 20) ? fmaxf(lo, hi) : -3.4e38f;
#pragma unroll
  for (int off = 1; off < 64; off <<= 1) m = fmaxf(m, __shfl_xor(m, off));
  float s = (lane < 20) ? (expf(lo - m) + expf(hi - m)) : 0.f;
#pragma unroll
  for (int off = 1; off < 64; off <<= 1) s += __shfl_xor(s, off);
  const float lse = m + logf(s);
  if (lane < 20) {
    float2 o; o.x = lo - lse; o.y = hi - lse;
    ((float2*)(out + (size_t)c * CO))[lane] = o;
  }
}

extern "C" void kernel_launch(void* const* d_in, const int* in_sizes, int n_in,
                              void* d_out, int out_size, void* d_ws, size_t ws_size,
                              hipStream_t stream) {
  const float* x  = (const float*)d_in[0];
  const int* ei   = (const int*)d_in[1];   // [2][E]: row0 = src, row1 = tgt
  const int* eik  = (const int*)d_in[2];
  const float* W1 = (const float*)d_in[3];
  const float* b1 = (const float*)d_in[4];
  const float* W2 = (const float*)d_in[5];
  const float* b2 = (const float*)d_in[6];
  const float* Wl = (const float*)d_in[7];
  const float* bl = (const float*)d_in[8];
  float* out = (float*)d_out;
  const int E  = in_sizes[1] / 2;
  const int EK = in_sizes[2] / 2;

  // workspace layout (~125 MB), 256B-aligned slots
  char* p = (char*)d_ws;
  size_t off = 0;
  auto alloc = [&](size_t bytes) -> void* {
    void* r = (void*)(p + off);
    off += (bytes + 255) & ~(size_t)255;
    return r;
  };
  int* gcur_s = (int*)alloc((size_t)NBUCK * 4);
  int* gcur_k = (int*)alloc((size_t)NBUCK * 4);
  void* zbuf = alloc(256);                 // zero redirect target for OOB tiles
  const size_t zero_span = off;            // memset covers gcur_s, gcur_k, zbuf
  int* bscan_s = (int*)alloc((size_t)NBUCK * 4);
  int* bscan_k = (int*)alloc((size_t)NBUCK * 4);
  float* dinv_s = (float*)alloc((size_t)NN * 4);
  float* dinv_k = (float*)alloc((size_t)NN * 4);
  int* rp_s = (int*)alloc((size_t)(NN + 1) * 4);
  int* rp_k = (int*)alloc((size_t)(NN + 1) * 4);
  unsigned short* W1T = (unsigned short*)alloc((size_t)HID * KP1 * 2);
  unsigned short* WpqT = (unsigned short*)alloc((size_t)NPQ * K2 * 2);
  float* cbv = (float*)alloc((size_t)CO * 4);
  int* gbin_s = (int*)alloc((size_t)NBUCK * CAPB_S * 4);    // 14.4 MB
  int* gbin_k = (int*)alloc((size_t)NBUCK * CAPB_K * 4);    // 2.4 MB
  int2* colw_s = (int2*)alloc((size_t)E * 8);               // 25.6 MB
  int2* colw_k = (int2*)alloc((size_t)EK * 8);              // 4 MB
  unsigned short* H1b = (unsigned short*)alloc((size_t)NN * HID * 2);   // 25.6 MB
  unsigned short* R1b = (unsigned short*)alloc((size_t)NN * K2 * 2);    // 51.2 MB
  unsigned short* PQ = H1b;   // alias: H1b dead after agg1; PQ = [NN x 80] bf16 (16 MB)

  hipMemsetAsync(d_ws, 0, zero_span, stream);

  // CSR build: bin -> scan -> per-bucket exact CSR (+dinv) -> fuse dinv[src] into edges
  const int nb1S = (E + 4095) / 4096;
  const int nb1K = (EK + 4095) / 4096;
  k_bin<<<nb1S + nb1K, 256, 0, stream>>>(ei, E, nb1S, gcur_s, gbin_s, eik, EK, gcur_k, gbin_k);
  k_bscan<<<2, 512, 0, stream>>>(gcur_s, bscan_s, gcur_k, bscan_k);
  k_csr<<<2 * NBUCK, 256, 0, stream>>>(gcur_s, gbin_s, bscan_s, rp_s, colw_s, dinv_s,
                                       gcur_k, gbin_k, bscan_k, rp_k, colw_k, dinv_k);
  const int nbF = (E + 255) / 256;
  const int nbFk = (EK + 255) / 256;
  k_fuse<<<nbF + nbFk, 256, 0, stream>>>(colw_s, dinv_s, E, nbF, colw_k, dinv_k, EK);

  // weight prep
  k_w1t<<<(HID * KP1) / 256, 256, 0, stream>>>(W1, W1T);
  k_wpq<<<NPQ, 256, 0, stream>>>(W2, Wl, b2, bl, WpqT, cbv);

  // layer 1: shared GEMM, fused dual aggregation (one wave per node)
  k_gemm1<<<(NN + 127) / 128, 256, 0, stream>>>(x, W1T, (const float*)zbuf, H1b);
  const int nbAgg = (NN + 3) / 4;
  k_agg1<<<nbAgg, 256, 0, stream>>>(rp_s, colw_s, dinv_s, rp_k, colw_k, dinv_k, H1b, b1, R1b);

  // folded tail: PQ GEMM + fused aggregation/log_softmax
  k_gemm2<<<(NN + 127) / 128, 256, 0, stream>>>(R1b, WpqT, (const unsigned short*)zbuf, PQ);
  k_aggf<<<nbAgg, 256, 0, stream>>>(rp_s, colw_s, dinv_s, rp_k, colw_k, dinv_k, PQ, cbv, out);
}

// Round 5
// 714.173 us; speedup vs baseline: 1.0837x; 1.0120x over previous
//
#include <hip/hip_runtime.h>
#include <stdint.h>

// Problem constants (match reference)
#define NN   100000   // nodes
#define FIN  500      // input features
#define HID  128      // hidden
#define KP1  512      // FIN padded to mult of 32 for MFMA K-loop
#define K2   256      // 2*HID (GEMM2 K)
#define CO   40       // classes
#define NPQ  80       // folded tail GEMM N (P|Q)
#define NBUCK 391     // ceil(NN/256) coarse buckets (target>>8)
#define CAPB_S 9216   // structural bucket capacity (mean 8184, +11 sigma)
#define CAPB_K 1536   // knn bucket capacity (mean 1279, +7 sigma)

typedef __attribute__((ext_vector_type(8))) short short8;
typedef __attribute__((ext_vector_type(4))) float float4v;
typedef __attribute__((address_space(3))) unsigned int as3_u32;
typedef __attribute__((address_space(1))) unsigned int as1_u32;

__device__ __forceinline__ unsigned short f2bf(float f) {
  unsigned u = __float_as_uint(f);
  u = u + 0x7fffu + ((u >> 16) & 1u);   // RNE
  return (unsigned short)(u >> 16);
}
__device__ __forceinline__ float bf2f(unsigned short s) {
  return __uint_as_float(((unsigned)s) << 16);
}
__device__ __forceinline__ void gl_lds16(const void* g, void* l) {
  __builtin_amdgcn_global_load_lds((const as1_u32*)g, (as3_u32*)l, 16, 0, 0);
}

// ---------------- phase 1: bin edges by target>>8 (both graphs fused) ----------------
__global__ __launch_bounds__(256) void k_bin(
    const int* __restrict__ ei, int nS, int nb1S, int* __restrict__ gcur_s, int* __restrict__ gbin_s,
    const int* __restrict__ eik, int nK, int* __restrict__ gcur_k, int* __restrict__ gbin_k) {
  __shared__ int cnt[NBUCK];
  __shared__ int base[NBUCK];
  const int b = blockIdx.x;
  const bool knn = (b >= nb1S);
  const int* src = knn ? eik      : ei;
  const int* tgt = knn ? eik + nK : ei + nS;
  const int n    = knn ? nK : nS;
  int* gcur      = knn ? gcur_k : gcur_s;
  int* gbin      = knn ? gbin_k : gbin_s;
  const int capb = knn ? CAPB_K : CAPB_S;
  const int ebase = (knn ? b - nb1S : b) * 4096;
  const int t = threadIdx.x;

  for (int i = t; i < NBUCK; i += 256) cnt[i] = 0;
  __syncthreads();
  int s[16], g[16];
#pragma unroll
  for (int i = 0; i < 16; ++i) {
    const int e = ebase + i * 256 + t;
    const bool v = e < n;
    s[i] = v ? src[e] : 0;
    g[i] = v ? tgt[e] : -1;
    if (v) atomicAdd(&cnt[g[i] >> 8], 1);
  }
  __syncthreads();
  for (int i = t; i < NBUCK; i += 256) {       // reserve global space, reset local cursor
    const int c = cnt[i];
    base[i] = c ? atomicAdd(&gcur[i], c) : 0;
    cnt[i] = 0;
  }
  __syncthreads();
#pragma unroll
  for (int i = 0; i < 16; ++i) {
    if (g[i] >= 0) {
      const int bkt = g[i] >> 8;
      const int pos = base[bkt] + atomicAdd(&cnt[bkt], 1);
      if (pos < capb) gbin[bkt * capb + pos] = (s[i] << 8) | (g[i] & 255);
    }
  }
}

// ---------------- exclusive scan of bucket totals (2 blocks: structural, knn) ----------------
__global__ __launch_bounds__(512) void k_bscan(const int* __restrict__ gcur_s, int* __restrict__ bscan_s,
                                               const int* __restrict__ gcur_k, int* __restrict__ bscan_k) {
  __shared__ int sd[512];
  const int* gcur = blockIdx.x ? gcur_k : gcur_s;
  int* bscan      = blockIdx.x ? bscan_k : bscan_s;
  const int t = threadIdx.x;
  const int v = (t < NBUCK) ? gcur[t] : 0;
  sd[t] = v;
  __syncthreads();
  for (int off = 1; off < 512; off <<= 1) {
    const int x = (t >= off) ? sd[t - off] : 0;
    __syncthreads(); sd[t] += x; __syncthreads();
  }
  if (t < NBUCK) bscan[t] = sd[t] - v;   // exclusive
}

// ---------------- phase 2: per-bucket exact CSR + dinv (both graphs fused) ----------------
// colw entries: {src, w} — w filled later by k_fuse
__global__ __launch_bounds__(256) void k_csr(
    const int* __restrict__ gcur_s, const int* __restrict__ gbin_s, const int* __restrict__ bscan_s,
    int* __restrict__ rp_s, int2* __restrict__ colw_s, float* __restrict__ dinv_s,
    const int* __restrict__ gcur_k, const int* __restrict__ gbin_k, const int* __restrict__ bscan_k,
    int* __restrict__ rp_k, int2* __restrict__ colw_k, float* __restrict__ dinv_k) {
  __shared__ int cnt[256];
  __shared__ int base[256];
  const int b0 = blockIdx.x;
  const bool knn = (b0 >= NBUCK);
  const int b = knn ? b0 - NBUCK : b0;
  const int* gcur  = knn ? gcur_k  : gcur_s;
  const int* gbin  = knn ? gbin_k  : gbin_s;
  const int* bscan = knn ? bscan_k : bscan_s;
  int* rp     = knn ? rp_k   : rp_s;
  int2* colw  = knn ? colw_k : colw_s;
  float* dinv = knn ? dinv_k : dinv_s;
  const int capb = knn ? CAPB_K : CAPB_S;
  const int t = threadIdx.x;
  int nB = gcur[b]; if (nB > capb) nB = capb;
  const int gb0 = b * capb;
  const int gbase = bscan[b];

  cnt[t] = 0;
  __syncthreads();
  for (int i = t; i < nB; i += 256) atomicAdd(&cnt[gbin[gb0 + i] & 255], 1);
  __syncthreads();
  const int myc = cnt[t];
  base[t] = myc;
  __syncthreads();
  for (int off = 1; off < 256; off <<= 1) {   // inclusive Hillis-Steele
    const int x = (t >= off) ? base[t - off] : 0;
    __syncthreads(); base[t] += x; __syncthreads();
  }
  const int excl = base[t] - myc;
  const int tg = b * 256 + t;
  if (tg < NN) { rp[tg] = gbase + excl; dinv[tg] = rsqrtf((float)(myc + 1)); }
  if (tg == NN) rp[NN] = gbase + excl;        // only in last bucket (t=160)
  __syncthreads();
  base[t] = excl; cnt[t] = 0;
  __syncthreads();
  for (int i = t; i < nB; i += 256) {
    const int e = gbin[gb0 + i];
    const int tl = e & 255;
    const int pos = atomicAdd(&cnt[tl], 1);
    colw[gbase + base[tl] + pos] = make_int2(e >> 8, 0);
  }
}

// ---------------- fill w = dinv[src] into colw (both graphs) ----------------
__global__ __launch_bounds__(256) void k_fuse(
    int2* __restrict__ colw_s, const float* __restrict__ dinv_s, int nS, int nbF,
    int2* __restrict__ colw_k, const float* __restrict__ dinv_k, int nK) {
  const int b = blockIdx.x;
  if (b < nbF) {
    const int i = b * 256 + threadIdx.x;
    if (i < nS) {
      const int s = colw_s[i].x;
      colw_s[i].y = __float_as_int(dinv_s[s]);
    }
  } else {
    const int i = (b - nbF) * 256 + threadIdx.x;
    if (i < nK) {
      const int s = colw_k[i].x;
      colw_k[i].y = __float_as_int(dinv_k[s]);
    }
  }
}

// ---------------- weight prep ----------------
__global__ void k_w1t(const float* __restrict__ W1, unsigned short* __restrict__ W1T) {
  int idx = blockIdx.x * 256 + threadIdx.x;      // 128*512
  int n = idx >> 9, k = idx & 511;
  float v = (k < FIN) ? W1[k * HID + n] : 0.f;
  W1T[idx] = f2bf(v);
}
// WpqT[n][k], n<80, k<256: n<40 -> P col o=n (Wlin left), n>=40 -> Q col o=n-40 (Wlin right)
// cb[o] = blin[o] + sum_j b2[j]*(Wl[o][j] + Wl[o][40+j])
__global__ void k_wpq(const float* __restrict__ W2, const float* __restrict__ Wl,
                      const float* __restrict__ b2, const float* __restrict__ bl,
                      unsigned short* __restrict__ WpqT, float* __restrict__ cb) {
  const int idx = blockIdx.x * 256 + threadIdx.x;   // 80*256 = 20480
  const int n = idx >> 8, k = idx & 255;
  const int o = (n < CO) ? n : n - CO;
  const int joff = (n < CO) ? 0 : CO;
  float s = 0.f;
#pragma unroll 8
  for (int j = 0; j < CO; ++j) s += W2[k * CO + j] * Wl[o * NPQ + joff + j];
  WpqT[n * K2 + k] = f2bf(s);
  if (blockIdx.x == 0 && threadIdx.x < CO) {
    const int oo = threadIdx.x;
    float c = bl[oo];
    for (int j = 0; j < CO; ++j) c += b2[j] * (Wl[oo * NPQ + j] + Wl[oo * NPQ + CO + j]);
    cb[oo] = c;
  }
}

// ---------------- GEMM1 v2: H1b = bf16(x @ W1)  [NN x 128] ----------------
// BM=64 tile (grid 1563, ~5 resident blocks/CU) + double-buffered LDS staging with
// counted s_waitcnt vmcnt(4): next K-tile's 4 global_load_lds per wave issue BEFORE
// computing the current tile, so HBM latency hides under MFMA + co-resident blocks.
__global__ __launch_bounds__(256) void k_gemm1(const float* __restrict__ x,
    const unsigned short* __restrict__ W1T, const float* __restrict__ zbuf,
    unsigned short* __restrict__ H1b) {
  __shared__ float Als[2][512 * 4];          // per buf: chunk = kg8*64+m, 4 floats (16B)
  __shared__ unsigned short Bls[2][512 * 8]; // per buf: chunk = kg4*128+n, 8 bf16 (16B)
  const int t = threadIdx.x;
  const int wv = t >> 6, lane = t & 63;
  const int qd = lane >> 4, mr = lane & 15;
  const int m0 = blockIdx.x * 64;

  float4v acc[8];
  const float4v zf4 = {0.f, 0.f, 0.f, 0.f};
#pragma unroll
  for (int b = 0; b < 8; ++b) acc[b] = zf4;

  // stage K-tile kk into buffer pb: 4 gl_lds per wave (2 A + 2 B)
  auto stage = [&](int kk, int pb) {
    const int k0 = kk * 32;
#pragma unroll
    for (int i = 0; i < 2; ++i) {
      const int cb = i * 256 + wv * 64;          // wave-uniform chunk base
      const int q = cb + lane;
      const int kg = q >> 6, m = q & 63;
      const int gm = m0 + m, kb = k0 + kg * 4;   // 500 % 4 == 0 -> never straddles
      const float* gp = (gm < NN && kb < FIN) ? (x + (size_t)gm * FIN + kb) : zbuf;
      gl_lds16(gp, &Als[pb][cb * 4]);
    }
#pragma unroll
    for (int i = 0; i < 2; ++i) {
      const int cb = i * 256 + wv * 64;
      const int q = cb + lane;
      const int kg = q >> 7, n = q & 127;
      gl_lds16(W1T + n * KP1 + k0 + kg * 8, &Bls[pb][cb * 8]);
    }
  };

  stage(0, 0);                                   // prologue: tile 0 in flight
  for (int kk = 0; kk < 16; ++kk) {
    const int cur = kk & 1;
    if (kk + 1 < 16) {
      stage(kk + 1, cur ^ 1);                    // issue next tile (8 outstanding)
      asm volatile("s_waitcnt vmcnt(4)" ::: "memory");   // oldest 4 (tile kk) done
    } else {
      asm volatile("s_waitcnt vmcnt(0)" ::: "memory");
    }
    __builtin_amdgcn_s_barrier();                // all waves' tile-kk writes complete

    short8 af;                                   // A frag: A[m=mr][k=qd*8+j], rows wv*16..+15
    {
      const int m = wv * 16 + mr;
      const float4v a0 = *(const float4v*)&Als[cur][((2 * qd) * 64 + m) * 4];
      const float4v a1 = *(const float4v*)&Als[cur][((2 * qd + 1) * 64 + m) * 4];
      af[0] = (short)f2bf(a0[0]); af[1] = (short)f2bf(a0[1]);
      af[2] = (short)f2bf(a0[2]); af[3] = (short)f2bf(a0[3]);
      af[4] = (short)f2bf(a1[0]); af[5] = (short)f2bf(a1[1]);
      af[6] = (short)f2bf(a1[2]); af[7] = (short)f2bf(a1[3]);
    }
#pragma unroll
    for (int ct = 0; ct < 8; ++ct) {             // B frag: B[k=qd*8+j][n=ct*16+mr]
      const short8 bf = *(const short8*)&Bls[cur][(qd * 128 + ct * 16 + mr) * 8];
      acc[ct] = __builtin_amdgcn_mfma_f32_16x16x32_bf16(af, bf, acc[ct], 0, 0, 0);
    }
    __builtin_amdgcn_s_barrier();                // reads done before next stage overwrites
  }

  // C/D layout: col = lane&15, row = (lane>>4)*4 + j
  const int rb = m0 + wv * 16 + qd * 4;
#pragma unroll
  for (int ct = 0; ct < 8; ++ct) {
    const int col = ct * 16 + mr;
#pragma unroll
    for (int j = 0; j < 4; ++j) {
      const int r = rb + j;
      if (r < NN) H1b[(size_t)r * HID + col] = f2bf(acc[ct][j]);
    }
  }
}

// ---------------- GEMM2: PQ = bf16(R1b @ Wpq)  [NN x 80] ----------------
__global__ __launch_bounds__(256) void k_gemm2(const unsigned short* __restrict__ R1b,
    const unsigned short* __restrict__ WpqT, const unsigned short* __restrict__ zbuf,
    unsigned short* __restrict__ PQ) {
  __shared__ unsigned short Als[512 * 8];  // chunk = kg8*128+m
  __shared__ unsigned short Bls[320 * 8];  // chunk = kg8*80+n
  const int t = threadIdx.x;
  const int wv = t >> 6, lane = t & 63;
  const int qd = lane >> 4, mr = lane & 15;
  const int m0 = blockIdx.x * 128;

  float4v acc[2][5];
  const float4v zf4 = {0.f, 0.f, 0.f, 0.f};
#pragma unroll
  for (int a = 0; a < 2; ++a)
#pragma unroll
    for (int b = 0; b < 5; ++b) acc[a][b] = zf4;

  for (int kk = 0; kk < 8; ++kk) {
    const int k0 = kk * 32;
    __syncthreads();
#pragma unroll
    for (int i = 0; i < 2; ++i) {
      const int cb = (wv * 2 + i) * 64;
      const int q = cb + lane;
      const int kg = q >> 7, m = q & 127;
      const int gm = m0 + m;
      const unsigned short* gp = (gm < NN) ? (R1b + (size_t)gm * K2 + k0 + kg * 8) : zbuf;
      gl_lds16(gp, &Als[cb * 8]);
    }
    // B: 320 chunks = 5 wave-instrs (wv 0..3 do inst wv; wv 0 also inst 4)
    {
      const int cb = wv * 64;
      const int q = cb + lane;
      const int kg = q / 80, n = q % 80;
      gl_lds16(WpqT + n * K2 + k0 + kg * 8, &Bls[cb * 8]);
      if (wv == 0) {
        const int cb2 = 4 * 64;
        const int q2 = cb2 + lane;
        const int kg2 = q2 / 80, n2 = q2 % 80;
        gl_lds16(WpqT + n2 * K2 + k0 + kg2 * 8, &Bls[cb2 * 8]);
      }
    }
    __syncthreads();
    short8 af[2];
#pragma unroll
    for (int rt = 0; rt < 2; ++rt)
      af[rt] = *(const short8*)&Als[(qd * 128 + wv * 32 + rt * 16 + mr) * 8];
#pragma unroll
    for (int ct = 0; ct < 5; ++ct) {
      const short8 bf = *(const short8*)&Bls[(qd * 80 + ct * 16 + mr) * 8];
      acc[0][ct] = __builtin_amdgcn_mfma_f32_16x16x32_bf16(af[0], bf, acc[0][ct], 0, 0, 0);
      acc[1][ct] = __builtin_amdgcn_mfma_f32_16x16x32_bf16(af[1], bf, acc[1][ct], 0, 0, 0);
    }
  }
#pragma unroll
  for (int rt = 0; rt < 2; ++rt) {
    const int rb = m0 + wv * 32 + rt * 16 + qd * 4;
#pragma unroll
    for (int ct = 0; ct < 5; ++ct) {
      const int col = ct * 16 + mr;
#pragma unroll
      for (int j = 0; j < 4; ++j) {
        const int r = rb + j;
        if (r < NN) PQ[(size_t)r * NPQ + col] = f2bf(acc[rt][ct][j]);
      }
    }
  }
}

// ---------------- gather helpers v4: scalar index batches + pipelined gathers ----------------
// ld8: load 8 edge (src,w) pairs. Full batches are contiguous (mergeable s_load);
// tail batches clamp the index to e1-1 (valid row) and zero the weight.
__device__ __forceinline__ void ld8(const int2* __restrict__ cw, int base, int e1, bool full,
                                    int2* __restrict__ q) {
  if (full) {
#pragma unroll
    for (int j = 0; j < 8; ++j) q[j] = cw[base + j];
  } else {
    const int e1c = e1 - 1;
#pragma unroll
    for (int j = 0; j < 8; ++j) {
      const int ee = base + j;
      int2 t = cw[(ee < e1) ? ee : e1c];
      t.y = (ee < e1) ? t.y : 0;
      q[j] = t;
    }
  }
}
// g8: issue the 8 row gathers (SGPR base + lane offset) into VGPR buffer d
__device__ __forceinline__ void g8(const int2* __restrict__ q,
    const unsigned* __restrict__ H32, int lane, unsigned* __restrict__ d) {
#pragma unroll
  for (int j = 0; j < 8; ++j) d[j] = H32[(size_t)q[j].x * 64 + lane];
}
// f8: consume a gathered batch
__device__ __forceinline__ void f8(const int2* __restrict__ q, const unsigned* __restrict__ d,
                                   float& ax, float& ay) {
#pragma unroll
  for (int j = 0; j < 8; ++j) {
    const float w = __int_as_float(q[j].y);
    ax += w * __uint_as_float(d[j] << 16);
    ay += w * __uint_as_float(d[j] & 0xffff0000u);
  }
}

// ---------------- layer-1 aggregation: one wave per node, BOTH graphs ----------------
// v4: 2-deep ping-pong gather pipeline (16 structural gathers in flight) + knn batch 0
// issued up-front (concurrent with entire structural pass; kills the serial knn tail).
__global__ __launch_bounds__(256) void k_agg1(
    const int* __restrict__ rp_s, const int2* __restrict__ colw_s, const float* __restrict__ dinv_s,
    const int* __restrict__ rp_k, const int2* __restrict__ colw_k, const float* __restrict__ dinv_k,
    const unsigned short* __restrict__ H, const float* __restrict__ bias,
    unsigned short* __restrict__ out) {
  const int wv = threadIdx.x >> 6, lane = threadIdx.x & 63;
  const int c = blockIdx.x * 4 + wv;
  if (c >= NN) return;
  const unsigned* H32 = (const unsigned*)H;
  const int e0s = __builtin_amdgcn_readfirstlane(rp_s[c]);
  const int e1s = __builtin_amdgcn_readfirstlane(rp_s[c + 1]);
  const int e0k = __builtin_amdgcn_readfirstlane(rp_k[c]);
  const int e1k = __builtin_amdgcn_readfirstlane(rp_k[c + 1]);
  const int nbS = (e1s - e0s + 7) >> 3;   // may be 0
  const int nbK = (e1k - e0k + 7) >> 3;

  int2 q0[8], q1[8], qk[8];
  unsigned d0[8], d1[8], dk[8];
  // issue phase: self row + structural batches 0,1 + knn batch 0 all in flight
  const unsigned pc = H32[(size_t)c * 64 + lane];
  if (nbS > 0) { ld8(colw_s, e0s, e1s, e0s + 8 <= e1s, q0); g8(q0, H32, lane, d0); }
  if (nbS > 1) { ld8(colw_s, e0s + 8, e1s, e0s + 16 <= e1s, q1); g8(q1, H32, lane, d1); }
  if (nbK > 0) { ld8(colw_k, e0k, e1k, e0k + 8 <= e1k, qk); g8(qk, H32, lane, dk); }

  const float dcs = dinv_s[c], dck = dinv_k[c];
  const float slo = __uint_as_float(pc << 16);
  const float shi = __uint_as_float(pc & 0xffff0000u);
  float ax = dcs * slo, ay = dcs * shi;   // structural self
  float bx = dck * slo, by = dck * shi;   // knn self

  // structural: pairwise ping-pong, always ~16 gathers outstanding
  int b = 0;
  while (b + 2 < nbS) {
    f8(q0, d0, ax, ay);                   // consume batch b
    {
      const int bs = e0s + (b + 2) * 8;   // issue batch b+2
      ld8(colw_s, bs, e1s, bs + 8 <= e1s, q0);
      g8(q0, H32, lane, d0);
    }
    f8(q1, d1, ax, ay);                   // consume batch b+1
    if (b + 3 < nbS) {
      const int bs = e0s + (b + 3) * 8;   // issue batch b+3
      ld8(colw_s, bs, e1s, bs + 8 <= e1s, q1);
      g8(q1, H32, lane, d1);
    }
    b += 2;
  }
  if (b < nbS) f8(q0, d0, ax, ay);
  if (b + 1 < nbS) f8(q1, d1, ax, ay);

  // knn: batch 0 already in flight since the top; extra batches are rare (deg>8)
  if (nbK > 0) f8(qk, dk, bx, by);
  for (int bk = 1; bk < nbK; ++bk) {
    const int bs = e0k + bk * 8;
    ld8(colw_k, bs, e1k, bs + 8 <= e1k, qk);
    g8(qk, H32, lane, dk);
    f8(qk, dk, bx, by);
  }

  const float2 bb = ((const float2*)bias)[lane];
  const float o0 = fmaxf(dcs * ax + bb.x, 0.f);
  const float o1 = fmaxf(dcs * ay + bb.y, 0.f);
  const float o2 = fmaxf(dck * bx + bb.x, 0.f);
  const float o3 = fmaxf(dck * by + bb.y, 0.f);
  unsigned* orow = (unsigned*)(out + (size_t)c * K2);
  orow[lane]      = (unsigned)f2bf(o0) | ((unsigned)f2bf(o1) << 16);
  orow[64 + lane] = (unsigned)f2bf(o2) | ((unsigned)f2bf(o3) << 16);
}

// ---------------- tail: logits = agg_s(P) + agg_k(Q) + cb; log_softmax ----------------
// wave per node; 3 groups of 20 lanes gather edges in parallel (strided), combine via shfl
__global__ __launch_bounds__(256) void k_aggf(
    const int* __restrict__ rp_s, const int2* __restrict__ colw_s, const float* __restrict__ dinv_s,
    const int* __restrict__ rp_k, const int2* __restrict__ colw_k, const float* __restrict__ dinv_k,
    const unsigned short* __restrict__ PQ, const float* __restrict__ cb,
    float* __restrict__ out) {
  const int wv = threadIdx.x >> 6, lane = threadIdx.x & 63;
  const int c = blockIdx.x * 4 + wv;
  if (c >= NN) return;
  const unsigned* PQ32 = (const unsigned*)PQ;
  const int g = lane / 20;        // 0..2 active groups (lanes 60-63 idle)
  const int l = lane % 20;        // dword index: P dwords 0-19, Q dwords 20-39
  float sx = 0.f, sy = 0.f, kx = 0.f, ky = 0.f;
  if (g < 3) {
    // structural edges -> P
    {
      const int e1 = rp_s[c + 1];
      int e = rp_s[c] + g;
      for (; e + 9 < e1; e += 12) {
        const int2 q0 = colw_s[e], q1 = colw_s[e + 3], q2 = colw_s[e + 6], q3 = colw_s[e + 9];
        const unsigned d0 = PQ32[(size_t)q0.x * 40 + l];
        const unsigned d1 = PQ32[(size_t)q1.x * 40 + l];
        const unsigned d2 = PQ32[(size_t)q2.x * 40 + l];
        const unsigned d3 = PQ32[(size_t)q3.x * 40 + l];
        const float w0 = __int_as_float(q0.y), w1 = __int_as_float(q1.y);
        const float w2 = __int_as_float(q2.y), w3 = __int_as_float(q3.y);
        sx += w0 * __uint_as_float(d0 << 16) + w1 * __uint_as_float(d1 << 16)
            + w2 * __uint_as_float(d2 << 16) + w3 * __uint_as_float(d3 << 16);
        sy += w0 * __uint_as_float(d0 & 0xffff0000u) + w1 * __uint_as_float(d1 & 0xffff0000u)
            + w2 * __uint_as_float(d2 & 0xffff0000u) + w3 * __uint_as_float(d3 & 0xffff0000u);
      }
      for (; e < e1; e += 3) {
        const int2 q = colw_s[e];
        const unsigned d = PQ32[(size_t)q.x * 40 + l];
        const float w = __int_as_float(q.y);
        sx += w * __uint_as_float(d << 16);
        sy += w * __uint_as_float(d & 0xffff0000u);
      }
    }
    // knn edges -> Q
    {
      const int e1 = rp_k[c + 1];
      int e = rp_k[c] + g;
      for (; e < e1; e += 3) {
        const int2 q = colw_k[e];
        const unsigned d = PQ32[(size_t)q.x * 40 + 20 + l];
        const float w = __int_as_float(q.y);
        kx += w * __uint_as_float(d << 16);
        ky += w * __uint_as_float(d & 0xffff0000u);
      }
    }
  }
  // combine 3 group partials into lanes 0-19
  sx += __shfl(sx, lane + 20) + __shfl(sx, lane + 40);
  sy += __shfl(sy, lane + 20) + __shfl(sy, lane + 40);
  kx += __shfl(kx, lane + 20) + __shfl(kx, lane + 40);
  ky += __shfl(ky, lane + 20) + __shfl(ky, lane + 40);

  float lo = 0.f, hi = 0.f;
  if (lane < 20) {
    const float dcs = dinv_s[c], dck = dinv_k[c];
    const unsigned dP = PQ32[(size_t)c * 40 + lane];
    const unsigned dQ = PQ32[(size_t)c * 40 + 20 + lane];
    const float2 cbb = ((const float2*)cb)[lane];
    lo = dcs * (sx + dcs * __uint_as_float(dP << 16))
       + dck * (kx + dck * __uint_as_float(dQ << 16)) + cbb.x;
    hi = dcs * (sy + dcs * __uint_as_float(dP & 0xffff0000u))
       + dck * (ky + dck * __uint_as_float(dQ & 0xffff0000u)) + cbb.y;
  }
  // log_softmax over 40 (lanes 0-19 hold pairs)
  float m = (lane < 20) ? fmaxf(lo, hi) : -3.4e38f;
#pragma unroll
  for (int off = 1; off < 64; off <<= 1) m = fmaxf(m, __shfl_xor(m, off));
  float s = (lane < 20) ? (expf(lo - m) + expf(hi - m)) : 0.f;
#pragma unroll
  for (int off = 1; off < 64; off <<= 1) s += __shfl_xor(s, off);
  const float lse = m + logf(s);
  if (lane < 20) {
    float2 o; o.x = lo - lse; o.y = hi - lse;
    ((float2*)(out + (size_t)c * CO))[lane] = o;
  }
}

extern "C" void kernel_launch(void* const* d_in, const int* in_sizes, int n_in,
                              void* d_out, int out_size, void* d_ws, size_t ws_size,
                              hipStream_t stream) {
  const float* x  = (const float*)d_in[0];
  const int* ei   = (const int*)d_in[1];   // [2][E]: row0 = src, row1 = tgt
  const int* eik  = (const int*)d_in[2];
  const float* W1 = (const float*)d_in[3];
  const float* b1 = (const float*)d_in[4];
  const float* W2 = (const float*)d_in[5];
  const float* b2 = (const float*)d_in[6];
  const float* Wl = (const float*)d_in[7];
  const float* bl = (const float*)d_in[8];
  float* out = (float*)d_out;
  const int E  = in_sizes[1] / 2;
  const int EK = in_sizes[2] / 2;

  // workspace layout (~125 MB), 256B-aligned slots
  char* p = (char*)d_ws;
  size_t off = 0;
  auto alloc = [&](size_t bytes) -> void* {
    void* r = (void*)(p + off);
    off += (bytes + 255) & ~(size_t)255;
    return r;
  };
  int* gcur_s = (int*)alloc((size_t)NBUCK * 4);
  int* gcur_k = (int*)alloc((size_t)NBUCK * 4);
  void* zbuf = alloc(256);                 // zero redirect target for OOB tiles
  const size_t zero_span = off;            // memset covers gcur_s, gcur_k, zbuf
  int* bscan_s = (int*)alloc((size_t)NBUCK * 4);
  int* bscan_k = (int*)alloc((size_t)NBUCK * 4);
  float* dinv_s = (float*)alloc((size_t)NN * 4);
  float* dinv_k = (float*)alloc((size_t)NN * 4);
  int* rp_s = (int*)alloc((size_t)(NN + 1) * 4);
  int* rp_k = (int*)alloc((size_t)(NN + 1) * 4);
  unsigned short* W1T = (unsigned short*)alloc((size_t)HID * KP1 * 2);
  unsigned short* WpqT = (unsigned short*)alloc((size_t)NPQ * K2 * 2);
  float* cbv = (float*)alloc((size_t)CO * 4);
  int* gbin_s = (int*)alloc((size_t)NBUCK * CAPB_S * 4);    // 14.4 MB
  int* gbin_k = (int*)alloc((size_t)NBUCK * CAPB_K * 4);    // 2.4 MB
  int2* colw_s = (int2*)alloc((size_t)E * 8);               // 25.6 MB
  int2* colw_k = (int2*)alloc((size_t)EK * 8);              // 4 MB
  unsigned short* H1b = (unsigned short*)alloc((size_t)NN * HID * 2);   // 25.6 MB
  unsigned short* R1b = (unsigned short*)alloc((size_t)NN * K2 * 2);    // 51.2 MB
  unsigned short* PQ = H1b;   // alias: H1b dead after agg1; PQ = [NN x 80] bf16 (16 MB)

  hipMemsetAsync(d_ws, 0, zero_span, stream);

  // CSR build: bin -> scan -> per-bucket exact CSR (+dinv) -> fuse dinv[src] into edges
  const int nb1S = (E + 4095) / 4096;
  const int nb1K = (EK + 4095) / 4096;
  k_bin<<<nb1S + nb1K, 256, 0, stream>>>(ei, E, nb1S, gcur_s, gbin_s, eik, EK, gcur_k, gbin_k);
  k_bscan<<<2, 512, 0, stream>>>(gcur_s, bscan_s, gcur_k, bscan_k);
  k_csr<<<2 * NBUCK, 256, 0, stream>>>(gcur_s, gbin_s, bscan_s, rp_s, colw_s, dinv_s,
                                       gcur_k, gbin_k, bscan_k, rp_k, colw_k, dinv_k);
  const int nbF = (E + 255) / 256;
  const int nbFk = (EK + 255) / 256;
  k_fuse<<<nbF + nbFk, 256, 0, stream>>>(colw_s, dinv_s, E, nbF, colw_k, dinv_k, EK);

  // weight prep
  k_w1t<<<(HID * KP1) / 256, 256, 0, stream>>>(W1, W1T);
  k_wpq<<<NPQ, 256, 0, stream>>>(W2, Wl, b2, bl, WpqT, cbv);

  // layer 1: shared GEMM (BM=64 dbuf), fused dual aggregation (one wave per node)
  k_gemm1<<<(NN + 63) / 64, 256, 0, stream>>>(x, W1T, (const float*)zbuf, H1b);
  const int nbAgg = (NN + 3) / 4;
  k_agg1<<<nbAgg, 256, 0, stream>>>(rp_s, colw_s, dinv_s, rp_k, colw_k, dinv_k, H1b, b1, R1b);

  // folded tail: PQ GEMM + fused aggregation/log_softmax
  k_gemm2<<<(NN + 127) / 128, 256, 0, stream>>>(R1b, WpqT, (const unsigned short*)zbuf, PQ);
  k_aggf<<<nbAgg, 256, 0, stream>>>(rp_s, colw_s, dinv_s, rp_k, colw_k, dinv_k, PQ, cbv, out);
}

// Round 6
// 688.751 us; speedup vs baseline: 1.1237x; 1.0369x over previous
//
#include <hip/hip_runtime.h>
#include <stdint.h>

// Problem constants (match reference)
#define NN   100000   // nodes
#define FIN  500      // input features
#define HID  128      // hidden
#define KP1  512      // FIN padded to mult of 32 for MFMA K-loop
#define K2   256      // 2*HID (GEMM2 K)
#define CO   40       // classes
#define NPQ  80       // folded tail GEMM N (P|Q)
#define NPQP 128      // WpqT padded rows (uniform staging)
#define NBUCK 391     // ceil(NN/256) coarse buckets (target>>8)
#define CAPB_S 9216   // structural bucket capacity (mean 8184, +11 sigma)
#define CAPB_K 1536   // knn bucket capacity (mean 1279, +7 sigma)

typedef __attribute__((ext_vector_type(8))) short short8;
typedef __attribute__((ext_vector_type(4))) float float4v;
typedef __attribute__((address_space(3))) unsigned int as3_u32;
typedef __attribute__((address_space(1))) unsigned int as1_u32;

__device__ __forceinline__ unsigned short f2bf(float f) {
  unsigned u = __float_as_uint(f);
  u = u + 0x7fffu + ((u >> 16) & 1u);   // RNE
  return (unsigned short)(u >> 16);
}
__device__ __forceinline__ float bf2f(unsigned short s) {
  return __uint_as_float(((unsigned)s) << 16);
}
__device__ __forceinline__ void gl_lds16(const void* g, void* l) {
  __builtin_amdgcn_global_load_lds((const as1_u32*)g, (as3_u32*)l, 16, 0, 0);
}

// ---------------- phase 1: bin edges by target>>8 (both graphs fused) ----------------
__global__ __launch_bounds__(256) void k_bin(
    const int* __restrict__ ei, int nS, int nb1S, int* __restrict__ gcur_s, int* __restrict__ gbin_s,
    const int* __restrict__ eik, int nK, int* __restrict__ gcur_k, int* __restrict__ gbin_k) {
  __shared__ int cnt[NBUCK];
  __shared__ int base[NBUCK];
  const int b = blockIdx.x;
  const bool knn = (b >= nb1S);
  const int* src = knn ? eik      : ei;
  const int* tgt = knn ? eik + nK : ei + nS;
  const int n    = knn ? nK : nS;
  int* gcur      = knn ? gcur_k : gcur_s;
  int* gbin      = knn ? gbin_k : gbin_s;
  const int capb = knn ? CAPB_K : CAPB_S;
  const int ebase = (knn ? b - nb1S : b) * 4096;
  const int t = threadIdx.x;

  for (int i = t; i < NBUCK; i += 256) cnt[i] = 0;
  __syncthreads();
  int s[16], g[16];
#pragma unroll
  for (int i = 0; i < 16; ++i) {
    const int e = ebase + i * 256 + t;
    const bool v = e < n;
    s[i] = v ? src[e] : 0;
    g[i] = v ? tgt[e] : -1;
    if (v) atomicAdd(&cnt[g[i] >> 8], 1);
  }
  __syncthreads();
  for (int i = t; i < NBUCK; i += 256) {       // reserve global space, reset local cursor
    const int c = cnt[i];
    base[i] = c ? atomicAdd(&gcur[i], c) : 0;
    cnt[i] = 0;
  }
  __syncthreads();
#pragma unroll
  for (int i = 0; i < 16; ++i) {
    if (g[i] >= 0) {
      const int bkt = g[i] >> 8;
      const int pos = base[bkt] + atomicAdd(&cnt[bkt], 1);
      if (pos < capb) gbin[bkt * capb + pos] = (s[i] << 8) | (g[i] & 255);
    }
  }
}

// ---------------- exclusive scan of bucket totals (2 blocks: structural, knn) ----------------
__global__ __launch_bounds__(512) void k_bscan(const int* __restrict__ gcur_s, int* __restrict__ bscan_s,
                                               const int* __restrict__ gcur_k, int* __restrict__ bscan_k) {
  __shared__ int sd[512];
  const int* gcur = blockIdx.x ? gcur_k : gcur_s;
  int* bscan      = blockIdx.x ? bscan_k : bscan_s;
  const int t = threadIdx.x;
  const int v = (t < NBUCK) ? gcur[t] : 0;
  sd[t] = v;
  __syncthreads();
  for (int off = 1; off < 512; off <<= 1) {
    const int x = (t >= off) ? sd[t - off] : 0;
    __syncthreads(); sd[t] += x; __syncthreads();
  }
  if (t < NBUCK) bscan[t] = sd[t] - v;   // exclusive
}

// ---------------- phase 2: per-bucket exact CSR + dinv (both graphs fused) ----------------
// colw entries: {src, w} — w filled later by k_fuse
__global__ __launch_bounds__(256) void k_csr(
    const int* __restrict__ gcur_s, const int* __restrict__ gbin_s, const int* __restrict__ bscan_s,
    int* __restrict__ rp_s, int2* __restrict__ colw_s, float* __restrict__ dinv_s,
    const int* __restrict__ gcur_k, const int* __restrict__ gbin_k, const int* __restrict__ bscan_k,
    int* __restrict__ rp_k, int2* __restrict__ colw_k, float* __restrict__ dinv_k) {
  __shared__ int cnt[256];
  __shared__ int base[256];
  const int b0 = blockIdx.x;
  const bool knn = (b0 >= NBUCK);
  const int b = knn ? b0 - NBUCK : b0;
  const int* gcur  = knn ? gcur_k  : gcur_s;
  const int* gbin  = knn ? gbin_k  : gbin_s;
  const int* bscan = knn ? bscan_k : bscan_s;
  int* rp     = knn ? rp_k   : rp_s;
  int2* colw  = knn ? colw_k : colw_s;
  float* dinv = knn ? dinv_k : dinv_s;
  const int capb = knn ? CAPB_K : CAPB_S;
  const int t = threadIdx.x;
  int nB = gcur[b]; if (nB > capb) nB = capb;
  const int gb0 = b * capb;
  const int gbase = bscan[b];

  cnt[t] = 0;
  __syncthreads();
  for (int i = t; i < nB; i += 256) atomicAdd(&cnt[gbin[gb0 + i] & 255], 1);
  __syncthreads();
  const int myc = cnt[t];
  base[t] = myc;
  __syncthreads();
  for (int off = 1; off < 256; off <<= 1) {   // inclusive Hillis-Steele
    const int x = (t >= off) ? base[t - off] : 0;
    __syncthreads(); base[t] += x; __syncthreads();
  }
  const int excl = base[t] - myc;
  const int tg = b * 256 + t;
  if (tg < NN) { rp[tg] = gbase + excl; dinv[tg] = rsqrtf((float)(myc + 1)); }
  if (tg == NN) rp[NN] = gbase + excl;        // only in last bucket (t=160)
  __syncthreads();
  base[t] = excl; cnt[t] = 0;
  __syncthreads();
  for (int i = t; i < nB; i += 256) {
    const int e = gbin[gb0 + i];
    const int tl = e & 255;
    const int pos = atomicAdd(&cnt[tl], 1);
    colw[gbase + base[tl] + pos] = make_int2(e >> 8, 0);
  }
}

// ---------------- fill w = dinv[src] into colw (both graphs) ----------------
__global__ __launch_bounds__(256) void k_fuse(
    int2* __restrict__ colw_s, const float* __restrict__ dinv_s, int nS, int nbF,
    int2* __restrict__ colw_k, const float* __restrict__ dinv_k, int nK) {
  const int b = blockIdx.x;
  if (b < nbF) {
    const int i = b * 256 + threadIdx.x;
    if (i < nS) {
      const int s = colw_s[i].x;
      colw_s[i].y = __float_as_int(dinv_s[s]);
    }
  } else {
    const int i = (b - nbF) * 256 + threadIdx.x;
    if (i < nK) {
      const int s = colw_k[i].x;
      colw_k[i].y = __float_as_int(dinv_k[s]);
    }
  }
}

// ---------------- weight prep ----------------
__global__ void k_w1t(const float* __restrict__ W1, unsigned short* __restrict__ W1T) {
  int idx = blockIdx.x * 256 + threadIdx.x;      // 128*512
  int n = idx >> 9, k = idx & 511;
  float v = (k < FIN) ? W1[k * HID + n] : 0.f;
  W1T[idx] = f2bf(v);
}
// WpqT[n][k], n<80, k<256: n<40 -> P col o=n (Wlin left), n>=40 -> Q col o=n-40 (Wlin right)
// cb[o] = blin[o] + sum_j b2[j]*(Wl[o][j] + Wl[o][40+j])
__global__ void k_wpq(const float* __restrict__ W2, const float* __restrict__ Wl,
                      const float* __restrict__ b2, const float* __restrict__ bl,
                      unsigned short* __restrict__ WpqT, float* __restrict__ cb) {
  const int idx = blockIdx.x * 256 + threadIdx.x;   // 80*256 = 20480
  const int n = idx >> 8, k = idx & 255;
  const int o = (n < CO) ? n : n - CO;
  const int joff = (n < CO) ? 0 : CO;
  float s = 0.f;
#pragma unroll 8
  for (int j = 0; j < CO; ++j) s += W2[k * CO + j] * Wl[o * NPQ + joff + j];
  WpqT[n * K2 + k] = f2bf(s);
  if (blockIdx.x == 0 && threadIdx.x < CO) {
    const int oo = threadIdx.x;
    float c = bl[oo];
    for (int j = 0; j < CO; ++j) c += b2[j] * (Wl[oo * NPQ + j] + Wl[oo * NPQ + CO + j]);
    cb[oo] = c;
  }
}

// ---------------- GEMM1 v3: H1b = bf16(x @ W1)  [NN x 128] ----------------
// BM=64, dbuf, counted vmcnt(4). Staging is now COALESCED: LDS elements are m-major
// with an XOR swizzle applied identically to the pre-swizzled global source (stage)
// and the frag read (rule: both-sides-or-neither with global_load_lds).
//   A elem (m,kg 0..7, 16B=4 floats)  at sidx = m*8 + (kg ^ (m&7))
//     -> one instr = 8 rows x 128B contiguous (was: 64 rows x 16B scatter)
//   B elem (n,kg 0..3, 16B=8 bf16)    at sidx = n*4 + (kg ^ ((n>>1)&3))
//     -> one instr = 16 rows x 64B contiguous
// Frag-read bank slots spread across all 8 element slots -> 2-way (free).
__global__ __launch_bounds__(256) void k_gemm1(const float* __restrict__ x,
    const unsigned short* __restrict__ W1T, const float* __restrict__ zbuf,
    unsigned short* __restrict__ H1b) {
  __shared__ float Als[2][512 * 4];          // 64 m x 8 kg elems, swizzled
  __shared__ unsigned short Bls[2][512 * 8]; // 128 n x 4 kg elems, swizzled
  const int t = threadIdx.x;
  const int wv = t >> 6, lane = t & 63;
  const int qd = lane >> 4, mr = lane & 15;
  const int m0 = blockIdx.x * 64;

  float4v acc[8];
  const float4v zf4 = {0.f, 0.f, 0.f, 0.f};
#pragma unroll
  for (int b = 0; b < 8; ++b) acc[b] = zf4;

  // stage K-tile kk into buffer pb: 4 gl_lds per wave (2 A + 2 B)
  auto stage = [&](int kk, int pb) {
    const int k0 = kk * 32;
#pragma unroll
    for (int i = 0; i < 2; ++i) {
      const int q = (wv * 2 + i) * 64 + lane;      // A sidx
      const int m = q >> 3;
      const int kg = (q & 7) ^ (m & 7);            // inverse swizzle on global src
      const int gm = m0 + m, kb = k0 + kg * 4;     // 500 % 4 == 0 -> never straddles
      const float* gp = (gm < NN && kb < FIN) ? (x + (size_t)gm * FIN + kb) : zbuf;
      gl_lds16(gp, &Als[pb][q * 4]);
    }
#pragma unroll
    for (int i = 0; i < 2; ++i) {
      const int q = (wv * 2 + i) * 64 + lane;      // B sidx
      const int n = q >> 2;
      const int kg = (q & 3) ^ ((q >> 3) & 3);     // (n>>1)&3 = (q>>3)&3
      gl_lds16(W1T + n * KP1 + k0 + kg * 8, &Bls[pb][q * 8]);
    }
  };

  stage(0, 0);                                   // prologue: tile 0 in flight
  for (int kk = 0; kk < 16; ++kk) {
    const int cur = kk & 1;
    if (kk + 1 < 16) {
      stage(kk + 1, cur ^ 1);                    // issue next tile (8 outstanding)
      asm volatile("s_waitcnt vmcnt(4)" ::: "memory");   // oldest 4 (tile kk) done
    } else {
      asm volatile("s_waitcnt vmcnt(0)" ::: "memory");
    }
    __builtin_amdgcn_s_barrier();                // all waves' tile-kk writes complete

    short8 af;                                   // A frag: A[m][k=qd*8+j]
    {
      const int m = wv * 16 + mr;
      const int s0 = m * 8 + ((2 * qd) ^ (m & 7));
      const int s1 = m * 8 + ((2 * qd + 1) ^ (m & 7));
      const float4v a0 = *(const float4v*)&Als[cur][s0 * 4];
      const float4v a1 = *(const float4v*)&Als[cur][s1 * 4];
      af[0] = (short)f2bf(a0[0]); af[1] = (short)f2bf(a0[1]);
      af[2] = (short)f2bf(a0[2]); af[3] = (short)f2bf(a0[3]);
      af[4] = (short)f2bf(a1[0]); af[5] = (short)f2bf(a1[1]);
      af[6] = (short)f2bf(a1[2]); af[7] = (short)f2bf(a1[3]);
    }
#pragma unroll
    for (int ct = 0; ct < 8; ++ct) {             // B frag: B[k=qd*8+j][n=ct*16+mr]
      const int n = ct * 16 + mr;
      const int sb = n * 4 + (qd ^ ((n >> 1) & 3));
      const short8 bf = *(const short8*)&Bls[cur][sb * 8];
      acc[ct] = __builtin_amdgcn_mfma_f32_16x16x32_bf16(af, bf, acc[ct], 0, 0, 0);
    }
    __builtin_amdgcn_s_barrier();                // reads done before next stage overwrites
  }

  // C/D layout: col = lane&15, row = (lane>>4)*4 + j
  const int rb = m0 + wv * 16 + qd * 4;
#pragma unroll
  for (int ct = 0; ct < 8; ++ct) {
    const int col = ct * 16 + mr;
#pragma unroll
    for (int j = 0; j < 4; ++j) {
      const int r = rb + j;
      if (r < NN) H1b[(size_t)r * HID + col] = f2bf(acc[ct][j]);
    }
  }
}

// ---------------- GEMM2 v3: PQ = bf16(R1b @ Wpq)  [NN x 80] ----------------
// Same treatment: BM=64, dbuf, vmcnt(3), swizzled coalesced staging.
//   A elem (m,kg 0..3, 8 bf16) at sidx = m*4 + (kg ^ ((m>>1)&3))   (256 elems, 1 instr/wave)
//   B elem (n,kg 0..3, 8 bf16) at sidx = n*4 + (kg ^ ((n>>1)&3))   (n<128 padded, 2 instr/wave)
__global__ __launch_bounds__(256) void k_gemm2(const unsigned short* __restrict__ R1b,
    const unsigned short* __restrict__ WpqT, const unsigned short* __restrict__ zbuf,
    unsigned short* __restrict__ PQ) {
  __shared__ unsigned short Als[2][256 * 8];   // 64 m x 4 kg elems
  __shared__ unsigned short Bls[2][512 * 8];   // 128 n x 4 kg elems (rows 80..127 pad)
  const int t = threadIdx.x;
  const int wv = t >> 6, lane = t & 63;
  const int qd = lane >> 4, mr = lane & 15;
  const int m0 = blockIdx.x * 64;

  float4v acc[5];
  const float4v zf4 = {0.f, 0.f, 0.f, 0.f};
#pragma unroll
  for (int b = 0; b < 5; ++b) acc[b] = zf4;

  auto stage = [&](int kk, int pb) {
    const int k0 = kk * 32;
    {
      const int q = wv * 64 + lane;              // A sidx (256 total)
      const int m = q >> 2;
      const int kg = (q & 3) ^ ((q >> 3) & 3);
      const int gm = m0 + m;
      const unsigned short* gp = (gm < NN) ? (R1b + (size_t)gm * K2 + k0 + kg * 8) : zbuf;
      gl_lds16(gp, &Als[pb][q * 8]);
    }
#pragma unroll
    for (int i = 0; i < 2; ++i) {
      const int q = (wv * 2 + i) * 64 + lane;    // B sidx (512 total)
      const int n = q >> 2;
      const int kg = (q & 3) ^ ((q >> 3) & 3);
      gl_lds16(WpqT + n * K2 + k0 + kg * 8, &Bls[pb][q * 8]);
    }
  };

  stage(0, 0);
  for (int kk = 0; kk < 8; ++kk) {
    const int cur = kk & 1;
    if (kk + 1 < 8) {
      stage(kk + 1, cur ^ 1);
      asm volatile("s_waitcnt vmcnt(3)" ::: "memory");
    } else {
      asm volatile("s_waitcnt vmcnt(0)" ::: "memory");
    }
    __builtin_amdgcn_s_barrier();

    short8 af;
    {
      const int m = wv * 16 + mr;
      const int sa = m * 4 + (qd ^ ((m >> 1) & 3));
      af = *(const short8*)&Als[cur][sa * 8];
    }
#pragma unroll
    for (int ct = 0; ct < 5; ++ct) {
      const int n = ct * 16 + mr;
      const int sb = n * 4 + (qd ^ ((n >> 1) & 3));
      const short8 bf = *(const short8*)&Bls[cur][sb * 8];
      acc[ct] = __builtin_amdgcn_mfma_f32_16x16x32_bf16(af, bf, acc[ct], 0, 0, 0);
    }
    __builtin_amdgcn_s_barrier();
  }

  const int rb = m0 + wv * 16 + qd * 4;
#pragma unroll
  for (int ct = 0; ct < 5; ++ct) {
    const int col = ct * 16 + mr;
#pragma unroll
    for (int j = 0; j < 4; ++j) {
      const int r = rb + j;
      if (r < NN) PQ[(size_t)r * NPQ + col] = f2bf(acc[ct][j]);
    }
  }
}

// ---------------- gather helpers v4: scalar index batches + pipelined gathers ----------------
// ld8: load 8 edge (src,w) pairs. Full batches are contiguous (mergeable s_load);
// tail batches clamp the index to e1-1 (valid row) and zero the weight.
__device__ __forceinline__ void ld8(const int2* __restrict__ cw, int base, int e1, bool full,
                                    int2* __restrict__ q) {
  if (full) {
#pragma unroll
    for (int j = 0; j < 8; ++j) q[j] = cw[base + j];
  } else {
    const int e1c = e1 - 1;
#pragma unroll
    for (int j = 0; j < 8; ++j) {
      const int ee = base + j;
      int2 t = cw[(ee < e1) ? ee : e1c];
      t.y = (ee < e1) ? t.y : 0;
      q[j] = t;
    }
  }
}
// g8: issue the 8 row gathers (SGPR base + lane offset) into VGPR buffer d
__device__ __forceinline__ void g8(const int2* __restrict__ q,
    const unsigned* __restrict__ H32, int lane, unsigned* __restrict__ d) {
#pragma unroll
  for (int j = 0; j < 8; ++j) d[j] = H32[(size_t)q[j].x * 64 + lane];
}
// f8: consume a gathered batch
__device__ __forceinline__ void f8(const int2* __restrict__ q, const unsigned* __restrict__ d,
                                   float& ax, float& ay) {
#pragma unroll
  for (int j = 0; j < 8; ++j) {
    const float w = __int_as_float(q[j].y);
    ax += w * __uint_as_float(d[j] << 16);
    ay += w * __uint_as_float(d[j] & 0xffff0000u);
  }
}

// ---------------- layer-1 aggregation: one wave per node, BOTH graphs ----------------
// v4: 2-deep ping-pong gather pipeline (16 structural gathers in flight) + knn batch 0
// issued up-front (concurrent with entire structural pass; kills the serial knn tail).
__global__ __launch_bounds__(256) void k_agg1(
    const int* __restrict__ rp_s, const int2* __restrict__ colw_s, const float* __restrict__ dinv_s,
    const int* __restrict__ rp_k, const int2* __restrict__ colw_k, const float* __restrict__ dinv_k,
    const unsigned short* __restrict__ H, const float* __restrict__ bias,
    unsigned short* __restrict__ out) {
  const int wv = threadIdx.x >> 6, lane = threadIdx.x & 63;
  const int c = blockIdx.x * 4 + wv;
  if (c >= NN) return;
  const unsigned* H32 = (const unsigned*)H;
  const int e0s = __builtin_amdgcn_readfirstlane(rp_s[c]);
  const int e1s = __builtin_amdgcn_readfirstlane(rp_s[c + 1]);
  const int e0k = __builtin_amdgcn_readfirstlane(rp_k[c]);
  const int e1k = __builtin_amdgcn_readfirstlane(rp_k[c + 1]);
  const int nbS = (e1s - e0s + 7) >> 3;   // may be 0
  const int nbK = (e1k - e0k + 7) >> 3;

  int2 q0[8], q1[8], qk[8];
  unsigned d0[8], d1[8], dk[8];
  // issue phase: self row + structural batches 0,1 + knn batch 0 all in flight
  const unsigned pc = H32[(size_t)c * 64 + lane];
  if (nbS > 0) { ld8(colw_s, e0s, e1s, e0s + 8 <= e1s, q0); g8(q0, H32, lane, d0); }
  if (nbS > 1) { ld8(colw_s, e0s + 8, e1s, e0s + 16 <= e1s, q1); g8(q1, H32, lane, d1); }
  if (nbK > 0) { ld8(colw_k, e0k, e1k, e0k + 8 <= e1k, qk); g8(qk, H32, lane, dk); }

  const float dcs = dinv_s[c], dck = dinv_k[c];
  const float slo = __uint_as_float(pc << 16);
  const float shi = __uint_as_float(pc & 0xffff0000u);
  float ax = dcs * slo, ay = dcs * shi;   // structural self
  float bx = dck * slo, by = dck * shi;   // knn self

  // structural: pairwise ping-pong, always ~16 gathers outstanding
  int b = 0;
  while (b + 2 < nbS) {
    f8(q0, d0, ax, ay);                   // consume batch b
    {
      const int bs = e0s + (b + 2) * 8;   // issue batch b+2
      ld8(colw_s, bs, e1s, bs + 8 <= e1s, q0);
      g8(q0, H32, lane, d0);
    }
    f8(q1, d1, ax, ay);                   // consume batch b+1
    if (b + 3 < nbS) {
      const int bs = e0s + (b + 3) * 8;   // issue batch b+3
      ld8(colw_s, bs, e1s, bs + 8 <= e1s, q1);
      g8(q1, H32, lane, d1);
    }
    b += 2;
  }
  if (b < nbS) f8(q0, d0, ax, ay);
  if (b + 1 < nbS) f8(q1, d1, ax, ay);

  // knn: batch 0 already in flight since the top; extra batches are rare (deg>8)
  if (nbK > 0) f8(qk, dk, bx, by);
  for (int bk = 1; bk < nbK; ++bk) {
    const int bs = e0k + bk * 8;
    ld8(colw_k, bs, e1k, bs + 8 <= e1k, qk);
    g8(qk, H32, lane, dk);
    f8(qk, dk, bx, by);
  }

  const float2 bb = ((const float2*)bias)[lane];
  const float o0 = fmaxf(dcs * ax + bb.x, 0.f);
  const float o1 = fmaxf(dcs * ay + bb.y, 0.f);
  const float o2 = fmaxf(dck * bx + bb.x, 0.f);
  const float o3 = fmaxf(dck * by + bb.y, 0.f);
  unsigned* orow = (unsigned*)(out + (size_t)c * K2);
  orow[lane]      = (unsigned)f2bf(o0) | ((unsigned)f2bf(o1) << 16);
  orow[64 + lane] = (unsigned)f2bf(o2) | ((unsigned)f2bf(o3) << 16);
}

// ---------------- tail: logits = agg_s(P) + agg_k(Q) + cb; log_softmax ----------------
// wave per node; 3 groups of 20 lanes gather edges in parallel (strided), combine via shfl
__global__ __launch_bounds__(256) void k_aggf(
    const int* __restrict__ rp_s, const int2* __restrict__ colw_s, const float* __restrict__ dinv_s,
    const int* __restrict__ rp_k, const int2* __restrict__ colw_k, const float* __restrict__ dinv_k,
    const unsigned short* __restrict__ PQ, const float* __restrict__ cb,
    float* __restrict__ out) {
  const int wv = threadIdx.x >> 6, lane = threadIdx.x & 63;
  const int c = blockIdx.x * 4 + wv;
  if (c >= NN) return;
  const unsigned* PQ32 = (const unsigned*)PQ;
  const int g = lane / 20;        // 0..2 active groups (lanes 60-63 idle)
  const int l = lane % 20;        // dword index: P dwords 0-19, Q dwords 20-39
  float sx = 0.f, sy = 0.f, kx = 0.f, ky = 0.f;
  if (g < 3) {
    // structural edges -> P
    {
      const int e1 = rp_s[c + 1];
      int e = rp_s[c] + g;
      for (; e + 9 < e1; e += 12) {
        const int2 q0 = colw_s[e], q1 = colw_s[e + 3], q2 = colw_s[e + 6], q3 = colw_s[e + 9];
        const unsigned d0 = PQ32[(size_t)q0.x * 40 + l];
        const unsigned d1 = PQ32[(size_t)q1.x * 40 + l];
        const unsigned d2 = PQ32[(size_t)q2.x * 40 + l];
        const unsigned d3 = PQ32[(size_t)q3.x * 40 + l];
        const float w0 = __int_as_float(q0.y), w1 = __int_as_float(q1.y);
        const float w2 = __int_as_float(q2.y), w3 = __int_as_float(q3.y);
        sx += w0 * __uint_as_float(d0 << 16) + w1 * __uint_as_float(d1 << 16)
            + w2 * __uint_as_float(d2 << 16) + w3 * __uint_as_float(d3 << 16);
        sy += w0 * __uint_as_float(d0 & 0xffff0000u) + w1 * __uint_as_float(d1 & 0xffff0000u)
            + w2 * __uint_as_float(d2 & 0xffff0000u) + w3 * __uint_as_float(d3 & 0xffff0000u);
      }
      for (; e < e1; e += 3) {
        const int2 q = colw_s[e];
        const unsigned d = PQ32[(size_t)q.x * 40 + l];
        const float w = __int_as_float(q.y);
        sx += w * __uint_as_float(d << 16);
        sy += w * __uint_as_float(d & 0xffff0000u);
      }
    }
    // knn edges -> Q
    {
      const int e1 = rp_k[c + 1];
      int e = rp_k[c] + g;
      for (; e < e1; e += 3) {
        const int2 q = colw_k[e];
        const unsigned d = PQ32[(size_t)q.x * 40 + 20 + l];
        const float w = __int_as_float(q.y);
        kx += w * __uint_as_float(d << 16);
        ky += w * __uint_as_float(d & 0xffff0000u);
      }
    }
  }
  // combine 3 group partials into lanes 0-19
  sx += __shfl(sx, lane + 20) + __shfl(sx, lane + 40);
  sy += __shfl(sy, lane + 20) + __shfl(sy, lane + 40);
  kx += __shfl(kx, lane + 20) + __shfl(kx, lane + 40);
  ky += __shfl(ky, lane + 20) + __shfl(ky, lane + 40);

  float lo = 0.f, hi = 0.f;
  if (lane < 20) {
    const float dcs = dinv_s[c], dck = dinv_k[c];
    const unsigned dP = PQ32[(size_t)c * 40 + lane];
    const unsigned dQ = PQ32[(size_t)c * 40 + 20 + lane];
    const float2 cbb = ((const float2*)cb)[lane];
    lo = dcs * (sx + dcs * __uint_as_float(dP << 16))
       + dck * (kx + dck * __uint_as_float(dQ << 16)) + cbb.x;
    hi = dcs * (sy + dcs * __uint_as_float(dP & 0xffff0000u))
       + dck * (ky + dck * __uint_as_float(dQ & 0xffff0000u)) + cbb.y;
  }
  // log_softmax over 40 (lanes 0-19 hold pairs)
  float m = (lane < 20) ? fmaxf(lo, hi) : -3.4e38f;
#pragma unroll
  for (int off = 1; off < 64; off <<= 1) m = fmaxf(m, __shfl_xor(m, off));
  float s = (lane < 20) ? (expf(lo - m) + expf(hi - m)) : 0.f;
#pragma unroll
  for (int off = 1; off < 64; off <<= 1) s += __shfl_xor(s, off);
  const float lse = m + logf(s);
  if (lane < 20) {
    float2 o; o.x = lo - lse; o.y = hi - lse;
    ((float2*)(out + (size_t)c * CO))[lane] = o;
  }
}

extern "C" void kernel_launch(void* const* d_in, const int* in_sizes, int n_in,
                              void* d_out, int out_size, void* d_ws, size_t ws_size,
                              hipStream_t stream) {
  const float* x  = (const float*)d_in[0];
  const int* ei   = (const int*)d_in[1];   // [2][E]: row0 = src, row1 = tgt
  const int* eik  = (const int*)d_in[2];
  const float* W1 = (const float*)d_in[3];
  const float* b1 = (const float*)d_in[4];
  const float* W2 = (const float*)d_in[5];
  const float* b2 = (const float*)d_in[6];
  const float* Wl = (const float*)d_in[7];
  const float* bl = (const float*)d_in[8];
  float* out = (float*)d_out;
  const int E  = in_sizes[1] / 2;
  const int EK = in_sizes[2] / 2;

  // workspace layout (~125 MB), 256B-aligned slots
  char* p = (char*)d_ws;
  size_t off = 0;
  auto alloc = [&](size_t bytes) -> void* {
    void* r = (void*)(p + off);
    off += (bytes + 255) & ~(size_t)255;
    return r;
  };
  int* gcur_s = (int*)alloc((size_t)NBUCK * 4);
  int* gcur_k = (int*)alloc((size_t)NBUCK * 4);
  void* zbuf = alloc(256);                 // zero redirect target for OOB tiles
  const size_t zero_span = off;            // memset covers gcur_s, gcur_k, zbuf
  int* bscan_s = (int*)alloc((size_t)NBUCK * 4);
  int* bscan_k = (int*)alloc((size_t)NBUCK * 4);
  float* dinv_s = (float*)alloc((size_t)NN * 4);
  float* dinv_k = (float*)alloc((size_t)NN * 4);
  int* rp_s = (int*)alloc((size_t)(NN + 1) * 4);
  int* rp_k = (int*)alloc((size_t)(NN + 1) * 4);
  unsigned short* W1T = (unsigned short*)alloc((size_t)HID * KP1 * 2);
  unsigned short* WpqT = (unsigned short*)alloc((size_t)NPQP * K2 * 2);  // rows 80..127 pad (staged, never consumed)
  float* cbv = (float*)alloc((size_t)CO * 4);
  int* gbin_s = (int*)alloc((size_t)NBUCK * CAPB_S * 4);    // 14.4 MB
  int* gbin_k = (int*)alloc((size_t)NBUCK * CAPB_K * 4);    // 2.4 MB
  int2* colw_s = (int2*)alloc((size_t)E * 8);               // 25.6 MB
  int2* colw_k = (int2*)alloc((size_t)EK * 8);              // 4 MB
  unsigned short* H1b = (unsigned short*)alloc((size_t)NN * HID * 2);   // 25.6 MB
  unsigned short* R1b = (unsigned short*)alloc((size_t)NN * K2 * 2);    // 51.2 MB
  unsigned short* PQ = H1b;   // alias: H1b dead after agg1; PQ = [NN x 80] bf16 (16 MB)

  hipMemsetAsync(d_ws, 0, zero_span, stream);

  // CSR build: bin -> scan -> per-bucket exact CSR (+dinv) -> fuse dinv[src] into edges
  const int nb1S = (E + 4095) / 4096;
  const int nb1K = (EK + 4095) / 4096;
  k_bin<<<nb1S + nb1K, 256, 0, stream>>>(ei, E, nb1S, gcur_s, gbin_s, eik, EK, gcur_k, gbin_k);
  k_bscan<<<2, 512, 0, stream>>>(gcur_s, bscan_s, gcur_k, bscan_k);
  k_csr<<<2 * NBUCK, 256, 0, stream>>>(gcur_s, gbin_s, bscan_s, rp_s, colw_s, dinv_s,
                                       gcur_k, gbin_k, bscan_k, rp_k, colw_k, dinv_k);
  const int nbF = (E + 255) / 256;
  const int nbFk = (EK + 255) / 256;
  k_fuse<<<nbF + nbFk, 256, 0, stream>>>(colw_s, dinv_s, E, nbF, colw_k, dinv_k, EK);

  // weight prep
  k_w1t<<<(HID * KP1) / 256, 256, 0, stream>>>(W1, W1T);
  k_wpq<<<NPQ, 256, 0, stream>>>(W2, Wl, b2, bl, WpqT, cbv);

  // layer 1: shared GEMM (BM=64 dbuf, swizzled staging), fused dual aggregation
  k_gemm1<<<(NN + 63) / 64, 256, 0, stream>>>(x, W1T, (const float*)zbuf, H1b);
  const int nbAgg = (NN + 3) / 4;
  k_agg1<<<nbAgg, 256, 0, stream>>>(rp_s, colw_s, dinv_s, rp_k, colw_k, dinv_k, H1b, b1, R1b);

  // folded tail: PQ GEMM (BM=64 dbuf, swizzled staging) + fused aggregation/log_softmax
  k_gemm2<<<(NN + 63) / 64, 256, 0, stream>>>(R1b, WpqT, (const unsigned short*)zbuf, PQ);
  k_aggf<<<nbAgg, 256, 0, stream>>>(rp_s, colw_s, dinv_s, rp_k, colw_k, dinv_k, PQ, cbv, out);
}

// Round 7
// 671.765 us; speedup vs baseline: 1.1521x; 1.0253x over previous
//
#include <hip/hip_runtime.h>
#include <stdint.h>

// Problem constants (match reference)
#define NN   100000   // nodes
#define FIN  500      // input features
#define HID  128      // hidden
#define KP1  512      // FIN padded to mult of 32 for MFMA K-loop
#define K2   256      // 2*HID (GEMM2 K)
#define CO   40       // classes
#define NPQ  80       // folded tail GEMM N (P|Q)
#define NPQP 128      // WpqT padded rows (uniform staging)
#define NBUCK 391     // ceil(NN/256) coarse buckets (target>>8)
#define CAPB_S 9216   // structural bucket capacity (mean 8184, +11 sigma)
#define CAPB_K 1536   // knn bucket capacity (mean 1279, +7 sigma)

typedef __attribute__((ext_vector_type(8))) short short8;
typedef __attribute__((ext_vector_type(4))) float float4v;
typedef __attribute__((address_space(3))) unsigned int as3_u32;
typedef __attribute__((address_space(1))) unsigned int as1_u32;

__device__ __forceinline__ unsigned short f2bf(float f) {
  unsigned u = __float_as_uint(f);
  u = u + 0x7fffu + ((u >> 16) & 1u);   // RNE
  return (unsigned short)(u >> 16);
}
__device__ __forceinline__ float bf2f(unsigned short s) {
  return __uint_as_float(((unsigned)s) << 16);
}
__device__ __forceinline__ void gl_lds16(const void* g, void* l) {
  __builtin_amdgcn_global_load_lds((const as1_u32*)g, (as3_u32*)l, 16, 0, 0);
}

// ---------------- phase 1: bin edges by target>>8 (both graphs fused) ----------------
__global__ __launch_bounds__(256) void k_bin(
    const int* __restrict__ ei, int nS, int nb1S, int* __restrict__ gcur_s, int* __restrict__ gbin_s,
    const int* __restrict__ eik, int nK, int* __restrict__ gcur_k, int* __restrict__ gbin_k) {
  __shared__ int cnt[NBUCK];
  __shared__ int base[NBUCK];
  const int b = blockIdx.x;
  const bool knn = (b >= nb1S);
  const int* src = knn ? eik      : ei;
  const int* tgt = knn ? eik + nK : ei + nS;
  const int n    = knn ? nK : nS;
  int* gcur      = knn ? gcur_k : gcur_s;
  int* gbin      = knn ? gbin_k : gbin_s;
  const int capb = knn ? CAPB_K : CAPB_S;
  const int ebase = (knn ? b - nb1S : b) * 4096;
  const int t = threadIdx.x;

  for (int i = t; i < NBUCK; i += 256) cnt[i] = 0;
  __syncthreads();
  int s[16], g[16];
#pragma unroll
  for (int i = 0; i < 16; ++i) {
    const int e = ebase + i * 256 + t;
    const bool v = e < n;
    s[i] = v ? src[e] : 0;
    g[i] = v ? tgt[e] : -1;
    if (v) atomicAdd(&cnt[g[i] >> 8], 1);
  }
  __syncthreads();
  for (int i = t; i < NBUCK; i += 256) {       // reserve global space, reset local cursor
    const int c = cnt[i];
    base[i] = c ? atomicAdd(&gcur[i], c) : 0;
    cnt[i] = 0;
  }
  __syncthreads();
#pragma unroll
  for (int i = 0; i < 16; ++i) {
    if (g[i] >= 0) {
      const int bkt = g[i] >> 8;
      const int pos = base[bkt] + atomicAdd(&cnt[bkt], 1);
      if (pos < capb) gbin[bkt * capb + pos] = (s[i] << 8) | (g[i] & 255);
    }
  }
}

// ---------------- exclusive scan of bucket totals (2 blocks: structural, knn) ----------------
__global__ __launch_bounds__(512) void k_bscan(const int* __restrict__ gcur_s, int* __restrict__ bscan_s,
                                               const int* __restrict__ gcur_k, int* __restrict__ bscan_k) {
  __shared__ int sd[512];
  const int* gcur = blockIdx.x ? gcur_k : gcur_s;
  int* bscan      = blockIdx.x ? bscan_k : bscan_s;
  const int t = threadIdx.x;
  const int v = (t < NBUCK) ? gcur[t] : 0;
  sd[t] = v;
  __syncthreads();
  for (int off = 1; off < 512; off <<= 1) {
    const int x = (t >= off) ? sd[t - off] : 0;
    __syncthreads(); sd[t] += x; __syncthreads();
  }
  if (t < NBUCK) bscan[t] = sd[t] - v;   // exclusive
}

// ---------------- phase 2: per-bucket exact CSR + dinv (both graphs fused) ----------------
// colw entries: {src, w} — w filled later by k_fuse
__global__ __launch_bounds__(256) void k_csr(
    const int* __restrict__ gcur_s, const int* __restrict__ gbin_s, const int* __restrict__ bscan_s,
    int* __restrict__ rp_s, int2* __restrict__ colw_s, float* __restrict__ dinv_s,
    const int* __restrict__ gcur_k, const int* __restrict__ gbin_k, const int* __restrict__ bscan_k,
    int* __restrict__ rp_k, int2* __restrict__ colw_k, float* __restrict__ dinv_k) {
  __shared__ int cnt[256];
  __shared__ int base[256];
  const int b0 = blockIdx.x;
  const bool knn = (b0 >= NBUCK);
  const int b = knn ? b0 - NBUCK : b0;
  const int* gcur  = knn ? gcur_k  : gcur_s;
  const int* gbin  = knn ? gbin_k  : gbin_s;
  const int* bscan = knn ? bscan_k : bscan_s;
  int* rp     = knn ? rp_k   : rp_s;
  int2* colw  = knn ? colw_k : colw_s;
  float* dinv = knn ? dinv_k : dinv_s;
  const int capb = knn ? CAPB_K : CAPB_S;
  const int t = threadIdx.x;
  int nB = gcur[b]; if (nB > capb) nB = capb;
  const int gb0 = b * capb;
  const int gbase = bscan[b];

  cnt[t] = 0;
  __syncthreads();
  for (int i = t; i < nB; i += 256) atomicAdd(&cnt[gbin[gb0 + i] & 255], 1);
  __syncthreads();
  const int myc = cnt[t];
  base[t] = myc;
  __syncthreads();
  for (int off = 1; off < 256; off <<= 1) {   // inclusive Hillis-Steele
    const int x = (t >= off) ? base[t - off] : 0;
    __syncthreads(); base[t] += x; __syncthreads();
  }
  const int excl = base[t] - myc;
  const int tg = b * 256 + t;
  if (tg < NN) { rp[tg] = gbase + excl; dinv[tg] = rsqrtf((float)(myc + 1)); }
  if (tg == NN) rp[NN] = gbase + excl;        // only in last bucket (t=160)
  __syncthreads();
  base[t] = excl; cnt[t] = 0;
  __syncthreads();
  for (int i = t; i < nB; i += 256) {
    const int e = gbin[gb0 + i];
    const int tl = e & 255;
    const int pos = atomicAdd(&cnt[tl], 1);
    colw[gbase + base[tl] + pos] = make_int2(e >> 8, 0);
  }
}

// ---------------- fill w = dinv[src] into colw (both graphs) ----------------
__global__ __launch_bounds__(256) void k_fuse(
    int2* __restrict__ colw_s, const float* __restrict__ dinv_s, int nS, int nbF,
    int2* __restrict__ colw_k, const float* __restrict__ dinv_k, int nK) {
  const int b = blockIdx.x;
  if (b < nbF) {
    const int i = b * 256 + threadIdx.x;
    if (i < nS) {
      const int s = colw_s[i].x;
      colw_s[i].y = __float_as_int(dinv_s[s]);
    }
  } else {
    const int i = (b - nbF) * 256 + threadIdx.x;
    if (i < nK) {
      const int s = colw_k[i].x;
      colw_k[i].y = __float_as_int(dinv_k[s]);
    }
  }
}

// ---------------- weight prep ----------------
__global__ void k_w1t(const float* __restrict__ W1, unsigned short* __restrict__ W1T) {
  int idx = blockIdx.x * 256 + threadIdx.x;      // 128*512
  int n = idx >> 9, k = idx & 511;
  float v = (k < FIN) ? W1[k * HID + n] : 0.f;
  W1T[idx] = f2bf(v);
}
// WpqT[n][k], n<80, k<256: n<40 -> P col o=n (Wlin left), n>=40 -> Q col o=n-40 (Wlin right)
// cb[o] = blin[o] + sum_j b2[j]*(Wl[o][j] + Wl[o][40+j])
__global__ void k_wpq(const float* __restrict__ W2, const float* __restrict__ Wl,
                      const float* __restrict__ b2, const float* __restrict__ bl,
                      unsigned short* __restrict__ WpqT, float* __restrict__ cb) {
  const int idx = blockIdx.x * 256 + threadIdx.x;   // 80*256 = 20480
  const int n = idx >> 8, k = idx & 255;
  const int o = (n < CO) ? n : n - CO;
  const int joff = (n < CO) ? 0 : CO;
  float s = 0.f;
#pragma unroll 8
  for (int j = 0; j < CO; ++j) s += W2[k * CO + j] * Wl[o * NPQ + joff + j];
  WpqT[n * K2 + k] = f2bf(s);
  if (blockIdx.x == 0 && threadIdx.x < CO) {
    const int oo = threadIdx.x;
    float c = bl[oo];
    for (int j = 0; j < CO; ++j) c += b2[j] * (Wl[oo * NPQ + j] + Wl[oo * NPQ + CO + j]);
    cb[oo] = c;
  }
}

// ---------------- GEMM1 v3: H1b = bf16(x @ W1)  [NN x 128] ----------------
// BM=64, dbuf, counted vmcnt(4). Staging is COALESCED: LDS elements are m-major
// with an XOR swizzle applied identically to the pre-swizzled global source (stage)
// and the frag read (rule: both-sides-or-neither with global_load_lds).
__global__ __launch_bounds__(256) void k_gemm1(const float* __restrict__ x,
    const unsigned short* __restrict__ W1T, const float* __restrict__ zbuf,
    unsigned short* __restrict__ H1b) {
  __shared__ float Als[2][512 * 4];          // 64 m x 8 kg elems, swizzled
  __shared__ unsigned short Bls[2][512 * 8]; // 128 n x 4 kg elems, swizzled
  const int t = threadIdx.x;
  const int wv = t >> 6, lane = t & 63;
  const int qd = lane >> 4, mr = lane & 15;
  const int m0 = blockIdx.x * 64;

  float4v acc[8];
  const float4v zf4 = {0.f, 0.f, 0.f, 0.f};
#pragma unroll
  for (int b = 0; b < 8; ++b) acc[b] = zf4;

  // stage K-tile kk into buffer pb: 4 gl_lds per wave (2 A + 2 B)
  auto stage = [&](int kk, int pb) {
    const int k0 = kk * 32;
#pragma unroll
    for (int i = 0; i < 2; ++i) {
      const int q = (wv * 2 + i) * 64 + lane;      // A sidx
      const int m = q >> 3;
      const int kg = (q & 7) ^ (m & 7);            // inverse swizzle on global src
      const int gm = m0 + m, kb = k0 + kg * 4;     // 500 % 4 == 0 -> never straddles
      const float* gp = (gm < NN && kb < FIN) ? (x + (size_t)gm * FIN + kb) : zbuf;
      gl_lds16(gp, &Als[pb][q * 4]);
    }
#pragma unroll
    for (int i = 0; i < 2; ++i) {
      const int q = (wv * 2 + i) * 64 + lane;      // B sidx
      const int n = q >> 2;
      const int kg = (q & 3) ^ ((q >> 3) & 3);     // (n>>1)&3 = (q>>3)&3
      gl_lds16(W1T + n * KP1 + k0 + kg * 8, &Bls[pb][q * 8]);
    }
  };

  stage(0, 0);                                   // prologue: tile 0 in flight
  for (int kk = 0; kk < 16; ++kk) {
    const int cur = kk & 1;
    if (kk + 1 < 16) {
      stage(kk + 1, cur ^ 1);                    // issue next tile (8 outstanding)
      asm volatile("s_waitcnt vmcnt(4)" ::: "memory");   // oldest 4 (tile kk) done
    } else {
      asm volatile("s_waitcnt vmcnt(0)" ::: "memory");
    }
    __builtin_amdgcn_s_barrier();                // all waves' tile-kk writes complete

    short8 af;                                   // A frag: A[m][k=qd*8+j]
    {
      const int m = wv * 16 + mr;
      const int s0 = m * 8 + ((2 * qd) ^ (m & 7));
      const int s1 = m * 8 + ((2 * qd + 1) ^ (m & 7));
      const float4v a0 = *(const float4v*)&Als[cur][s0 * 4];
      const float4v a1 = *(const float4v*)&Als[cur][s1 * 4];
      af[0] = (short)f2bf(a0[0]); af[1] = (short)f2bf(a0[1]);
      af[2] = (short)f2bf(a0[2]); af[3] = (short)f2bf(a0[3]);
      af[4] = (short)f2bf(a1[0]); af[5] = (short)f2bf(a1[1]);
      af[6] = (short)f2bf(a1[2]); af[7] = (short)f2bf(a1[3]);
    }
#pragma unroll
    for (int ct = 0; ct < 8; ++ct) {             // B frag: B[k=qd*8+j][n=ct*16+mr]
      const int n = ct * 16 + mr;
      const int sb = n * 4 + (qd ^ ((n >> 1) & 3));
      const short8 bf = *(const short8*)&Bls[cur][sb * 8];
      acc[ct] = __builtin_amdgcn_mfma_f32_16x16x32_bf16(af, bf, acc[ct], 0, 0, 0);
    }
    __builtin_amdgcn_s_barrier();                // reads done before next stage overwrites
  }

  // C/D layout: col = lane&15, row = (lane>>4)*4 + j
  const int rb = m0 + wv * 16 + qd * 4;
#pragma unroll
  for (int ct = 0; ct < 8; ++ct) {
    const int col = ct * 16 + mr;
#pragma unroll
    for (int j = 0; j < 4; ++j) {
      const int r = rb + j;
      if (r < NN) H1b[(size_t)r * HID + col] = f2bf(acc[ct][j]);
    }
  }
}

// ---------------- GEMM2 v3: PQ = bf16(R1b @ Wpq)  [NN x 80] ----------------
// Same treatment: BM=64, dbuf, vmcnt(3), swizzled coalesced staging.
__global__ __launch_bounds__(256) void k_gemm2(const unsigned short* __restrict__ R1b,
    const unsigned short* __restrict__ WpqT, const unsigned short* __restrict__ zbuf,
    unsigned short* __restrict__ PQ) {
  __shared__ unsigned short Als[2][256 * 8];   // 64 m x 4 kg elems
  __shared__ unsigned short Bls[2][512 * 8];   // 128 n x 4 kg elems (rows 80..127 pad)
  const int t = threadIdx.x;
  const int wv = t >> 6, lane = t & 63;
  const int qd = lane >> 4, mr = lane & 15;
  const int m0 = blockIdx.x * 64;

  float4v acc[5];
  const float4v zf4 = {0.f, 0.f, 0.f, 0.f};
#pragma unroll
  for (int b = 0; b < 5; ++b) acc[b] = zf4;

  auto stage = [&](int kk, int pb) {
    const int k0 = kk * 32;
    {
      const int q = wv * 64 + lane;              // A sidx (256 total)
      const int m = q >> 2;
      const int kg = (q & 3) ^ ((q >> 3) & 3);
      const int gm = m0 + m;
      const unsigned short* gp = (gm < NN) ? (R1b + (size_t)gm * K2 + k0 + kg * 8) : zbuf;
      gl_lds16(gp, &Als[pb][q * 8]);
    }
#pragma unroll
    for (int i = 0; i < 2; ++i) {
      const int q = (wv * 2 + i) * 64 + lane;    // B sidx (512 total)
      const int n = q >> 2;
      const int kg = (q & 3) ^ ((q >> 3) & 3);
      gl_lds16(WpqT + n * K2 + k0 + kg * 8, &Bls[pb][q * 8]);
    }
  };

  stage(0, 0);
  for (int kk = 0; kk < 8; ++kk) {
    const int cur = kk & 1;
    if (kk + 1 < 8) {
      stage(kk + 1, cur ^ 1);
      asm volatile("s_waitcnt vmcnt(3)" ::: "memory");
    } else {
      asm volatile("s_waitcnt vmcnt(0)" ::: "memory");
    }
    __builtin_amdgcn_s_barrier();

    short8 af;
    {
      const int m = wv * 16 + mr;
      const int sa = m * 4 + (qd ^ ((m >> 1) & 3));
      af = *(const short8*)&Als[cur][sa * 8];
    }
#pragma unroll
    for (int ct = 0; ct < 5; ++ct) {
      const int n = ct * 16 + mr;
      const int sb = n * 4 + (qd ^ ((n >> 1) & 3));
      const short8 bf = *(const short8*)&Bls[cur][sb * 8];
      acc[ct] = __builtin_amdgcn_mfma_f32_16x16x32_bf16(af, bf, acc[ct], 0, 0, 0);
    }
    __builtin_amdgcn_s_barrier();
  }

  const int rb = m0 + wv * 16 + qd * 4;
#pragma unroll
  for (int ct = 0; ct < 5; ++ct) {
    const int col = ct * 16 + mr;
#pragma unroll
    for (int j = 0; j < 4; ++j) {
      const int r = rb + j;
      if (r < NN) PQ[(size_t)r * NPQ + col] = f2bf(acc[ct][j]);
    }
  }
}

// ---------------- gather helpers v4: scalar index batches + pipelined gathers ----------------
// ld8: load 8 edge (src,w) pairs. Full batches are contiguous (mergeable s_load);
// tail batches clamp the index to e1-1 (valid row) and zero the weight.
__device__ __forceinline__ void ld8(const int2* __restrict__ cw, int base, int e1, bool full,
                                    int2* __restrict__ q) {
  if (full) {
#pragma unroll
    for (int j = 0; j < 8; ++j) q[j] = cw[base + j];
  } else {
    const int e1c = e1 - 1;
#pragma unroll
    for (int j = 0; j < 8; ++j) {
      const int ee = base + j;
      int2 t = cw[(ee < e1) ? ee : e1c];
      t.y = (ee < e1) ? t.y : 0;
      q[j] = t;
    }
  }
}
// g8: issue the 8 row gathers (SGPR base + lane offset) into VGPR buffer d
__device__ __forceinline__ void g8(const int2* __restrict__ q,
    const unsigned* __restrict__ H32, int lane, unsigned* __restrict__ d) {
#pragma unroll
  for (int j = 0; j < 8; ++j) d[j] = H32[(size_t)q[j].x * 64 + lane];
}
// f8: consume a gathered batch
__device__ __forceinline__ void f8(const int2* __restrict__ q, const unsigned* __restrict__ d,
                                   float& ax, float& ay) {
#pragma unroll
  for (int j = 0; j < 8; ++j) {
    const float w = __int_as_float(q[j].y);
    ax += w * __uint_as_float(d[j] << 16);
    ay += w * __uint_as_float(d[j] & 0xffff0000u);
  }
}

// ---------------- layer-1 aggregation: one wave per node, BOTH graphs ----------------
// v4: 2-deep ping-pong gather pipeline (16 structural gathers in flight) + knn batch 0
// issued up-front (concurrent with entire structural pass; kills the serial knn tail).
__global__ __launch_bounds__(256) void k_agg1(
    const int* __restrict__ rp_s, const int2* __restrict__ colw_s, const float* __restrict__ dinv_s,
    const int* __restrict__ rp_k, const int2* __restrict__ colw_k, const float* __restrict__ dinv_k,
    const unsigned short* __restrict__ H, const float* __restrict__ bias,
    unsigned short* __restrict__ out) {
  const int wv = threadIdx.x >> 6, lane = threadIdx.x & 63;
  const int c = blockIdx.x * 4 + wv;
  if (c >= NN) return;
  const unsigned* H32 = (const unsigned*)H;
  const int e0s = __builtin_amdgcn_readfirstlane(rp_s[c]);
  const int e1s = __builtin_amdgcn_readfirstlane(rp_s[c + 1]);
  const int e0k = __builtin_amdgcn_readfirstlane(rp_k[c]);
  const int e1k = __builtin_amdgcn_readfirstlane(rp_k[c + 1]);
  const int nbS = (e1s - e0s + 7) >> 3;   // may be 0
  const int nbK = (e1k - e0k + 7) >> 3;

  int2 q0[8], q1[8], qk[8];
  unsigned d0[8], d1[8], dk[8];
  // issue phase: self row + structural batches 0,1 + knn batch 0 all in flight
  const unsigned pc = H32[(size_t)c * 64 + lane];
  if (nbS > 0) { ld8(colw_s, e0s, e1s, e0s + 8 <= e1s, q0); g8(q0, H32, lane, d0); }
  if (nbS > 1) { ld8(colw_s, e0s + 8, e1s, e0s + 16 <= e1s, q1); g8(q1, H32, lane, d1); }
  if (nbK > 0) { ld8(colw_k, e0k, e1k, e0k + 8 <= e1k, qk); g8(qk, H32, lane, dk); }

  const float dcs = dinv_s[c], dck = dinv_k[c];
  const float slo = __uint_as_float(pc << 16);
  const float shi = __uint_as_float(pc & 0xffff0000u);
  float ax = dcs * slo, ay = dcs * shi;   // structural self
  float bx = dck * slo, by = dck * shi;   // knn self

  // structural: pairwise ping-pong, always ~16 gathers outstanding
  int b = 0;
  while (b + 2 < nbS) {
    f8(q0, d0, ax, ay);                   // consume batch b
    {
      const int bs = e0s + (b + 2) * 8;   // issue batch b+2
      ld8(colw_s, bs, e1s, bs + 8 <= e1s, q0);
      g8(q0, H32, lane, d0);
    }
    f8(q1, d1, ax, ay);                   // consume batch b+1
    if (b + 3 < nbS) {
      const int bs = e0s + (b + 3) * 8;   // issue batch b+3
      ld8(colw_s, bs, e1s, bs + 8 <= e1s, q1);
      g8(q1, H32, lane, d1);
    }
    b += 2;
  }
  if (b < nbS) f8(q0, d0, ax, ay);
  if (b + 1 < nbS) f8(q1, d1, ax, ay);

  // knn: batch 0 already in flight since the top; extra batches are rare (deg>8)
  if (nbK > 0) f8(qk, dk, bx, by);
  for (int bk = 1; bk < nbK; ++bk) {
    const int bs = e0k + bk * 8;
    ld8(colw_k, bs, e1k, bs + 8 <= e1k, qk);
    g8(qk, H32, lane, dk);
    f8(qk, dk, bx, by);
  }

  const float2 bb = ((const float2*)bias)[lane];
  const float o0 = fmaxf(dcs * ax + bb.x, 0.f);
  const float o1 = fmaxf(dcs * ay + bb.y, 0.f);
  const float o2 = fmaxf(dck * bx + bb.x, 0.f);
  const float o3 = fmaxf(dck * by + bb.y, 0.f);
  unsigned* orow = (unsigned*)(out + (size_t)c * K2);
  orow[lane]      = (unsigned)f2bf(o0) | ((unsigned)f2bf(o1) << 16);
  orow[64 + lane] = (unsigned)f2bf(o2) | ((unsigned)f2bf(o3) << 16);
}

// ---------------- tail v2: logits = agg_s(P) + agg_k(Q) + cb; log_softmax ----------------
// agg1-v4 recipe ported to the 3x20-lane layout: scalar (wave-uniform) edge batches of
// 12 (4 triples), per-lane triple select via static ?: (cndmask), 4 gathers/batch issued
// together, 2-batch ping-pong (8 outstanding), knn batch 0 + self rows issued up-front.
__device__ __forceinline__ void ld12(const int2* __restrict__ cw, int base, int e1, bool full,
                                     int2* __restrict__ q) {
  if (full) {
#pragma unroll
    for (int j = 0; j < 12; ++j) q[j] = cw[base + j];
  } else {
    const int e1c = e1 - 1;
#pragma unroll
    for (int j = 0; j < 12; ++j) {
      const int ee = base + j;
      int2 t = cw[(ee < e1) ? ee : e1c];
      t.y = (ee < e1) ? t.y : 0;
      q[j] = t;
    }
  }
}
// issue 4 triple-gathers: group g takes edge 3t+g of the batch; w kept for consume
__device__ __forceinline__ void gt4(const int2* __restrict__ q, const unsigned* __restrict__ PQ32,
                                    int g, int l, int off, float* __restrict__ w,
                                    unsigned* __restrict__ d) {
#pragma unroll
  for (int t = 0; t < 4; ++t) {
    const int2 qa = q[3 * t], qb = q[3 * t + 1], qc = q[3 * t + 2];
    const int xs = (g == 0) ? qa.x : ((g == 1) ? qb.x : qc.x);
    const int wi = (g == 0) ? qa.y : ((g == 1) ? qb.y : qc.y);
    w[t] = __int_as_float(wi);
    d[t] = PQ32[(size_t)xs * 40 + off + l];
  }
}
__device__ __forceinline__ void ct4(const float* __restrict__ w, const unsigned* __restrict__ d,
                                    float& sx, float& sy) {
#pragma unroll
  for (int t = 0; t < 4; ++t) {
    sx += w[t] * __uint_as_float(d[t] << 16);
    sy += w[t] * __uint_as_float(d[t] & 0xffff0000u);
  }
}

__global__ __launch_bounds__(256) void k_aggf(
    const int* __restrict__ rp_s, const int2* __restrict__ colw_s, const float* __restrict__ dinv_s,
    const int* __restrict__ rp_k, const int2* __restrict__ colw_k, const float* __restrict__ dinv_k,
    const unsigned short* __restrict__ PQ, const float* __restrict__ cb,
    float* __restrict__ out) {
  const int wv = threadIdx.x >> 6, lane = threadIdx.x & 63;
  const int c = blockIdx.x * 4 + wv;
  if (c >= NN) return;
  const unsigned* PQ32 = (const unsigned*)PQ;
  const int g = (lane < 60) ? (lane / 20) : 2;   // lanes 60-63 ride with g=2 (results unused)
  const int l = lane - 20 * g;                   // 0..19 active; 20..23 for lanes 60-63 (safe)

  const int e0s = __builtin_amdgcn_readfirstlane(rp_s[c]);
  const int e1s = __builtin_amdgcn_readfirstlane(rp_s[c + 1]);
  const int e0k = __builtin_amdgcn_readfirstlane(rp_k[c]);
  const int e1k = __builtin_amdgcn_readfirstlane(rp_k[c + 1]);
  const int nbS = (e1s - e0s + 11) / 12;
  const int nbK = (e1k - e0k + 11) / 12;

  // self rows issued up-front (consumed at the end)
  unsigned dP = 0, dQ = 0;
  if (lane < 20) {
    dP = PQ32[(size_t)c * 40 + lane];
    dQ = PQ32[(size_t)c * 40 + 20 + lane];
  }

  int2 q0[12], q1[12], qk[12];
  float w0[4], w1[4], wk[4];
  unsigned d0[4], d1[4], dk[4];
  if (nbS > 0) { ld12(colw_s, e0s, e1s, e0s + 12 <= e1s, q0); gt4(q0, PQ32, g, l, 0, w0, d0); }
  if (nbS > 1) { ld12(colw_s, e0s + 12, e1s, e0s + 24 <= e1s, q1); gt4(q1, PQ32, g, l, 0, w1, d1); }
  if (nbK > 0) { ld12(colw_k, e0k, e1k, e0k + 12 <= e1k, qk); gt4(qk, PQ32, g, l, 20, wk, dk); }

  float sx = 0.f, sy = 0.f, kx = 0.f, ky = 0.f;
  int b = 0;
  while (b + 2 < nbS) {
    ct4(w0, d0, sx, sy);
    {
      const int bs = e0s + (b + 2) * 12;
      ld12(colw_s, bs, e1s, bs + 12 <= e1s, q0);
      gt4(q0, PQ32, g, l, 0, w0, d0);
    }
    ct4(w1, d1, sx, sy);
    if (b + 3 < nbS) {
      const int bs = e0s + (b + 3) * 12;
      ld12(colw_s, bs, e1s, bs + 12 <= e1s, q1);
      gt4(q1, PQ32, g, l, 0, w1, d1);
    }
    b += 2;
  }
  if (b < nbS) ct4(w0, d0, sx, sy);
  if (b + 1 < nbS) ct4(w1, d1, sx, sy);

  if (nbK > 0) ct4(wk, dk, kx, ky);
  for (int bk = 1; bk < nbK; ++bk) {
    const int bs = e0k + bk * 12;
    ld12(colw_k, bs, e1k, bs + 12 <= e1k, qk);
    gt4(qk, PQ32, g, l, 20, wk, dk);
    ct4(wk, dk, kx, ky);
  }

  // combine 3 group partials into lanes 0-19
  sx += __shfl(sx, lane + 20) + __shfl(sx, lane + 40);
  sy += __shfl(sy, lane + 20) + __shfl(sy, lane + 40);
  kx += __shfl(kx, lane + 20) + __shfl(kx, lane + 40);
  ky += __shfl(ky, lane + 20) + __shfl(ky, lane + 40);

  float lo = 0.f, hi = 0.f;
  if (lane < 20) {
    const float dcs = dinv_s[c], dck = dinv_k[c];
    const float2 cbb = ((const float2*)cb)[lane];
    lo = dcs * (sx + dcs * __uint_as_float(dP << 16))
       + dck * (kx + dck * __uint_as_float(dQ << 16)) + cbb.x;
    hi = dcs * (sy + dcs * __uint_as_float(dP & 0xffff0000u))
       + dck * (ky + dck * __uint_as_float(dQ & 0xffff0000u)) + cbb.y;
  }
  // log_softmax over 40 (lanes 0-19 hold pairs)
  float m = (lane < 20) ? fmaxf(lo, hi) : -3.4e38f;
#pragma unroll
  for (int off = 1; off < 64; off <<= 1) m = fmaxf(m, __shfl_xor(m, off));
  float s = (lane < 20) ? (expf(lo - m) + expf(hi - m)) : 0.f;
#pragma unroll
  for (int off = 1; off < 64; off <<= 1) s += __shfl_xor(s, off);
  const float lse = m + logf(s);
  if (lane < 20) {
    float2 o; o.x = lo - lse; o.y = hi - lse;
    ((float2*)(out + (size_t)c * CO))[lane] = o;
  }
}

extern "C" void kernel_launch(void* const* d_in, const int* in_sizes, int n_in,
                              void* d_out, int out_size, void* d_ws, size_t ws_size,
                              hipStream_t stream) {
  const float* x  = (const float*)d_in[0];
  const int* ei   = (const int*)d_in[1];   // [2][E]: row0 = src, row1 = tgt
  const int* eik  = (const int*)d_in[2];
  const float* W1 = (const float*)d_in[3];
  const float* b1 = (const float*)d_in[4];
  const float* W2 = (const float*)d_in[5];
  const float* b2 = (const float*)d_in[6];
  const float* Wl = (const float*)d_in[7];
  const float* bl = (const float*)d_in[8];
  float* out = (float*)d_out;
  const int E  = in_sizes[1] / 2;
  const int EK = in_sizes[2] / 2;

  // workspace layout (~125 MB), 256B-aligned slots
  char* p = (char*)d_ws;
  size_t off = 0;
  auto alloc = [&](size_t bytes) -> void* {
    void* r = (void*)(p + off);
    off += (bytes + 255) & ~(size_t)255;
    return r;
  };
  int* gcur_s = (int*)alloc((size_t)NBUCK * 4);
  int* gcur_k = (int*)alloc((size_t)NBUCK * 4);
  void* zbuf = alloc(256);                 // zero redirect target for OOB tiles
  const size_t zero_span = off;            // memset covers gcur_s, gcur_k, zbuf
  int* bscan_s = (int*)alloc((size_t)NBUCK * 4);
  int* bscan_k = (int*)alloc((size_t)NBUCK * 4);
  float* dinv_s = (float*)alloc((size_t)NN * 4);
  float* dinv_k = (float*)alloc((size_t)NN * 4);
  int* rp_s = (int*)alloc((size_t)(NN + 1) * 4);
  int* rp_k = (int*)alloc((size_t)(NN + 1) * 4);
  unsigned short* W1T = (unsigned short*)alloc((size_t)HID * KP1 * 2);
  unsigned short* WpqT = (unsigned short*)alloc((size_t)NPQP * K2 * 2);  // rows 80..127 pad (staged, never consumed)
  float* cbv = (float*)alloc((size_t)CO * 4);
  int* gbin_s = (int*)alloc((size_t)NBUCK * CAPB_S * 4);    // 14.4 MB
  int* gbin_k = (int*)alloc((size_t)NBUCK * CAPB_K * 4);    // 2.4 MB
  int2* colw_s = (int2*)alloc((size_t)E * 8);               // 25.6 MB
  int2* colw_k = (int2*)alloc((size_t)EK * 8);              // 4 MB
  unsigned short* H1b = (unsigned short*)alloc((size_t)NN * HID * 2);   // 25.6 MB
  unsigned short* R1b = (unsigned short*)alloc((size_t)NN * K2 * 2);    // 51.2 MB
  unsigned short* PQ = H1b;   // alias: H1b dead after agg1; PQ = [NN x 80] bf16 (16 MB)

  hipMemsetAsync(d_ws, 0, zero_span, stream);

  // CSR build: bin -> scan -> per-bucket exact CSR (+dinv) -> fuse dinv[src] into edges
  const int nb1S = (E + 4095) / 4096;
  const int nb1K = (EK + 4095) / 4096;
  k_bin<<<nb1S + nb1K, 256, 0, stream>>>(ei, E, nb1S, gcur_s, gbin_s, eik, EK, gcur_k, gbin_k);
  k_bscan<<<2, 512, 0, stream>>>(gcur_s, bscan_s, gcur_k, bscan_k);
  k_csr<<<2 * NBUCK, 256, 0, stream>>>(gcur_s, gbin_s, bscan_s, rp_s, colw_s, dinv_s,
                                       gcur_k, gbin_k, bscan_k, rp_k, colw_k, dinv_k);
  const int nbF = (E + 255) / 256;
  const int nbFk = (EK + 255) / 256;
  k_fuse<<<nbF + nbFk, 256, 0, stream>>>(colw_s, dinv_s, E, nbF, colw_k, dinv_k, EK);

  // weight prep
  k_w1t<<<(HID * KP1) / 256, 256, 0, stream>>>(W1, W1T);
  k_wpq<<<NPQ, 256, 0, stream>>>(W2, Wl, b2, bl, WpqT, cbv);

  // layer 1: shared GEMM (BM=64 dbuf, swizzled staging), fused dual aggregation
  k_gemm1<<<(NN + 63) / 64, 256, 0, stream>>>(x, W1T, (const float*)zbuf, H1b);
  const int nbAgg = (NN + 3) / 4;
  k_agg1<<<nbAgg, 256, 0, stream>>>(rp_s, colw_s, dinv_s, rp_k, colw_k, dinv_k, H1b, b1, R1b);

  // folded tail: PQ GEMM (BM=64 dbuf, swizzled staging) + fused aggregation/log_softmax
  k_gemm2<<<(NN + 63) / 64, 256, 0, stream>>>(R1b, WpqT, (const unsigned short*)zbuf, PQ);
  k_aggf<<<nbAgg, 256, 0, stream>>>(rp_s, colw_s, dinv_s, rp_k, colw_k, dinv_k, PQ, cbv, out);
}

// Round 8
// 669.695 us; speedup vs baseline: 1.1556x; 1.0031x over previous
//
#include <hip/hip_runtime.h>
#include <stdint.h>

// Problem constants (match reference)
#define NN   100000   // nodes
#define FIN  500      // input features
#define HID  128      // hidden
#define KP1  512      // FIN padded to mult of 32 for MFMA K-loop
#define K2   256      // 2*HID (GEMM2 K)
#define CO   40       // classes
#define NPQ  80       // folded tail GEMM N (P|Q)
#define NPQP 128      // WpqT padded rows (uniform staging)
#define NBUCK 391     // ceil(NN/256) coarse buckets (target>>8)
#define CAPB_S 9216   // structural bucket capacity (mean 8184, +11 sigma)
#define CAPB_K 1536   // knn bucket capacity (mean 1279, +7 sigma)

typedef __attribute__((ext_vector_type(8))) short short8;
typedef __attribute__((ext_vector_type(4))) float float4v;
typedef __attribute__((address_space(3))) unsigned int as3_u32;
typedef __attribute__((address_space(1))) unsigned int as1_u32;

__device__ __forceinline__ unsigned short f2bf(float f) {
  unsigned u = __float_as_uint(f);
  u = u + 0x7fffu + ((u >> 16) & 1u);   // RNE
  return (unsigned short)(u >> 16);
}
__device__ __forceinline__ float bf2f(unsigned short s) {
  return __uint_as_float(((unsigned)s) << 16);
}
__device__ __forceinline__ void gl_lds16(const void* g, void* l) {
  __builtin_amdgcn_global_load_lds((const as1_u32*)g, (as3_u32*)l, 16, 0, 0);
}

// ---------------- fused phase 1: bin edges  ||  weight prep (w1t, wpq) ----------------
// blocks [0,nbBin): bin; [nbBin,nbBin+256): w1t; [nbBin+256,nbBin+256+80): wpq.
// All three depend only on kernel inputs -> safe to co-schedule in one dispatch.
__global__ __launch_bounds__(256) void k_binw(
    const int* __restrict__ ei, int nS, int nb1S, int* __restrict__ gcur_s, int* __restrict__ gbin_s,
    const int* __restrict__ eik, int nK, int nbBin, int* __restrict__ gcur_k, int* __restrict__ gbin_k,
    const float* __restrict__ W1, unsigned short* __restrict__ W1T,
    const float* __restrict__ W2, const float* __restrict__ Wl,
    const float* __restrict__ b2, const float* __restrict__ bl,
    unsigned short* __restrict__ WpqT, float* __restrict__ cb) {
  __shared__ int cnt[NBUCK];
  __shared__ int base[NBUCK];
  const int t = threadIdx.x;

  if (blockIdx.x >= nbBin) {
    const int wb = blockIdx.x - nbBin;
    if (wb < 256) {                          // ---- w1t path ----
      const int idx = wb * 256 + t;          // 128*512
      const int n = idx >> 9, k = idx & 511;
      const float v = (k < FIN) ? W1[k * HID + n] : 0.f;
      W1T[idx] = f2bf(v);
    } else {                                 // ---- wpq path ----
      const int lb = wb - 256;               // 0..79
      const int idx = lb * 256 + t;
      const int n = idx >> 8, k = idx & 255;
      const int o = (n < CO) ? n : n - CO;
      const int joff = (n < CO) ? 0 : CO;
      float s = 0.f;
#pragma unroll 8
      for (int j = 0; j < CO; ++j) s += W2[k * CO + j] * Wl[o * NPQ + joff + j];
      WpqT[n * K2 + k] = f2bf(s);
      if (lb == 0 && t < CO) {
        const int oo = t;
        float c = bl[oo];
        for (int j = 0; j < CO; ++j) c += b2[j] * (Wl[oo * NPQ + j] + Wl[oo * NPQ + CO + j]);
        cb[oo] = c;
      }
    }
    return;
  }

  // ---- bin path (unchanged) ----
  const int b = blockIdx.x;
  const bool knn = (b >= nb1S);
  const int* src = knn ? eik      : ei;
  const int* tgt = knn ? eik + nK : ei + nS;
  const int n    = knn ? nK : nS;
  int* gcur      = knn ? gcur_k : gcur_s;
  int* gbin      = knn ? gbin_k : gbin_s;
  const int capb = knn ? CAPB_K : CAPB_S;
  const int ebase = (knn ? b - nb1S : b) * 4096;

  for (int i = t; i < NBUCK; i += 256) cnt[i] = 0;
  __syncthreads();
  int s[16], g[16];
#pragma unroll
  for (int i = 0; i < 16; ++i) {
    const int e = ebase + i * 256 + t;
    const bool v = e < n;
    s[i] = v ? src[e] : 0;
    g[i] = v ? tgt[e] : -1;
    if (v) atomicAdd(&cnt[g[i] >> 8], 1);
  }
  __syncthreads();
  for (int i = t; i < NBUCK; i += 256) {       // reserve global space, reset local cursor
    const int c = cnt[i];
    base[i] = c ? atomicAdd(&gcur[i], c) : 0;
    cnt[i] = 0;
  }
  __syncthreads();
#pragma unroll
  for (int i = 0; i < 16; ++i) {
    if (g[i] >= 0) {
      const int bkt = g[i] >> 8;
      const int pos = base[bkt] + atomicAdd(&cnt[bkt], 1);
      if (pos < capb) gbin[bkt * capb + pos] = (s[i] << 8) | (g[i] & 255);
    }
  }
}

// ---------------- exclusive scan of bucket totals (2 blocks: structural, knn) ----------------
__global__ __launch_bounds__(512) void k_bscan(const int* __restrict__ gcur_s, int* __restrict__ bscan_s,
                                               const int* __restrict__ gcur_k, int* __restrict__ bscan_k) {
  __shared__ int sd[512];
  const int* gcur = blockIdx.x ? gcur_k : gcur_s;
  int* bscan      = blockIdx.x ? bscan_k : bscan_s;
  const int t = threadIdx.x;
  const int v = (t < NBUCK) ? gcur[t] : 0;
  sd[t] = v;
  __syncthreads();
  for (int off = 1; off < 512; off <<= 1) {
    const int x = (t >= off) ? sd[t - off] : 0;
    __syncthreads(); sd[t] += x; __syncthreads();
  }
  if (t < NBUCK) bscan[t] = sd[t] - v;   // exclusive
}

// ---------------- fused: per-bucket exact CSR  ||  GEMM1 ----------------
// blocks [0, 2*NBUCK): csr (needs bin+bscan); [2*NBUCK, +nbG1): gemm1 (needs x, W1T).
// The two paths are data-independent; fusing them co-schedules a latency-bound MFMA
// kernel with an LDS-atomic-bound build kernel on the same CUs (both leave pipes idle
// solo). LDS shared via union (32 KB -> 5 blocks/CU).
union SMemCG {
  struct { int cnt[256]; int base[256]; } c;
  struct { float A[2][2048]; unsigned short B[2][4096]; } g;
};

__global__ __launch_bounds__(256) void k_csrg1(
    // csr args
    const int* __restrict__ gcur_s, const int* __restrict__ gbin_s, const int* __restrict__ bscan_s,
    int* __restrict__ rp_s, int2* __restrict__ colw_s, float* __restrict__ dinv_s,
    const int* __restrict__ gcur_k, const int* __restrict__ gbin_k, const int* __restrict__ bscan_k,
    int* __restrict__ rp_k, int2* __restrict__ colw_k, float* __restrict__ dinv_k,
    // gemm1 args
    const float* __restrict__ x, const unsigned short* __restrict__ W1T,
    const float* __restrict__ zbuf, unsigned short* __restrict__ H1b) {
  __shared__ SMemCG sm;
  const int t = threadIdx.x;

  if (blockIdx.x < 2 * NBUCK) {
    // ================= csr path (unchanged logic) =================
    int* cnt  = sm.c.cnt;
    int* base = sm.c.base;
    const int b0 = blockIdx.x;
    const bool knn = (b0 >= NBUCK);
    const int b = knn ? b0 - NBUCK : b0;
    const int* gcur  = knn ? gcur_k  : gcur_s;
    const int* gbin  = knn ? gbin_k  : gbin_s;
    const int* bscan = knn ? bscan_k : bscan_s;
    int* rp     = knn ? rp_k   : rp_s;
    int2* colw  = knn ? colw_k : colw_s;
    float* dinv = knn ? dinv_k : dinv_s;
    const int capb = knn ? CAPB_K : CAPB_S;
    int nB = gcur[b]; if (nB > capb) nB = capb;
    const int gb0 = b * capb;
    const int gbase = bscan[b];

    cnt[t] = 0;
    __syncthreads();
    for (int i = t; i < nB; i += 256) atomicAdd(&cnt[gbin[gb0 + i] & 255], 1);
    __syncthreads();
    const int myc = cnt[t];
    base[t] = myc;
    __syncthreads();
    for (int off = 1; off < 256; off <<= 1) {   // inclusive Hillis-Steele
      const int x2 = (t >= off) ? base[t - off] : 0;
      __syncthreads(); base[t] += x2; __syncthreads();
    }
    const int excl = base[t] - myc;
    const int tg = b * 256 + t;
    if (tg < NN) { rp[tg] = gbase + excl; dinv[tg] = rsqrtf((float)(myc + 1)); }
    if (tg == NN) rp[NN] = gbase + excl;        // only in last bucket (t=160)
    __syncthreads();
    base[t] = excl; cnt[t] = 0;
    __syncthreads();
    for (int i = t; i < nB; i += 256) {
      const int e = gbin[gb0 + i];
      const int tl = e & 255;
      const int pos = atomicAdd(&cnt[tl], 1);
      colw[gbase + base[tl] + pos] = make_int2(e >> 8, 0);
    }
    return;
  }

  // ================= gemm1 path (unchanged logic; BM=64, dbuf, vmcnt(4), swizzle) ====
  const int wv = t >> 6, lane = t & 63;
  const int qd = lane >> 4, mr = lane & 15;
  const int m0 = (blockIdx.x - 2 * NBUCK) * 64;

  float4v acc[8];
  const float4v zf4 = {0.f, 0.f, 0.f, 0.f};
#pragma unroll
  for (int b = 0; b < 8; ++b) acc[b] = zf4;

  auto stage = [&](int kk, int pb) {
    const int k0 = kk * 32;
#pragma unroll
    for (int i = 0; i < 2; ++i) {
      const int q = (wv * 2 + i) * 64 + lane;      // A sidx
      const int m = q >> 3;
      const int kg = (q & 7) ^ (m & 7);            // inverse swizzle on global src
      const int gm = m0 + m, kb = k0 + kg * 4;     // 500 % 4 == 0 -> never straddles
      const float* gp = (gm < NN && kb < FIN) ? (x + (size_t)gm * FIN + kb) : zbuf;
      gl_lds16(gp, &sm.g.A[pb][q * 4]);
    }
#pragma unroll
    for (int i = 0; i < 2; ++i) {
      const int q = (wv * 2 + i) * 64 + lane;      // B sidx
      const int n = q >> 2;
      const int kg = (q & 3) ^ ((q >> 3) & 3);     // (n>>1)&3 = (q>>3)&3
      gl_lds16(W1T + n * KP1 + k0 + kg * 8, &sm.g.B[pb][q * 8]);
    }
  };

  stage(0, 0);                                   // prologue: tile 0 in flight
  for (int kk = 0; kk < 16; ++kk) {
    const int cur = kk & 1;
    if (kk + 1 < 16) {
      stage(kk + 1, cur ^ 1);                    // issue next tile (8 outstanding)
      asm volatile("s_waitcnt vmcnt(4)" ::: "memory");   // oldest 4 (tile kk) done
    } else {
      asm volatile("s_waitcnt vmcnt(0)" ::: "memory");
    }
    __builtin_amdgcn_s_barrier();                // all waves' tile-kk writes complete

    short8 af;                                   // A frag: A[m][k=qd*8+j]
    {
      const int m = wv * 16 + mr;
      const int s0 = m * 8 + ((2 * qd) ^ (m & 7));
      const int s1 = m * 8 + ((2 * qd + 1) ^ (m & 7));
      const float4v a0 = *(const float4v*)&sm.g.A[cur][s0 * 4];
      const float4v a1 = *(const float4v*)&sm.g.A[cur][s1 * 4];
      af[0] = (short)f2bf(a0[0]); af[1] = (short)f2bf(a0[1]);
      af[2] = (short)f2bf(a0[2]); af[3] = (short)f2bf(a0[3]);
      af[4] = (short)f2bf(a1[0]); af[5] = (short)f2bf(a1[1]);
      af[6] = (short)f2bf(a1[2]); af[7] = (short)f2bf(a1[3]);
    }
#pragma unroll
    for (int ct = 0; ct < 8; ++ct) {             // B frag: B[k=qd*8+j][n=ct*16+mr]
      const int n = ct * 16 + mr;
      const int sb = n * 4 + (qd ^ ((n >> 1) & 3));
      const short8 bf = *(const short8*)&sm.g.B[cur][sb * 8];
      acc[ct] = __builtin_amdgcn_mfma_f32_16x16x32_bf16(af, bf, acc[ct], 0, 0, 0);
    }
    __builtin_amdgcn_s_barrier();                // reads done before next stage overwrites
  }

  // C/D layout: col = lane&15, row = (lane>>4)*4 + j
  const int rb = m0 + wv * 16 + qd * 4;
#pragma unroll
  for (int ct = 0; ct < 8; ++ct) {
    const int col = ct * 16 + mr;
#pragma unroll
    for (int j = 0; j < 4; ++j) {
      const int r = rb + j;
      if (r < NN) H1b[(size_t)r * HID + col] = f2bf(acc[ct][j]);
    }
  }
}

// ---------------- fill w = dinv[src] into colw (both graphs) ----------------
__global__ __launch_bounds__(256) void k_fuse(
    int2* __restrict__ colw_s, const float* __restrict__ dinv_s, int nS, int nbF,
    int2* __restrict__ colw_k, const float* __restrict__ dinv_k, int nK) {
  const int b = blockIdx.x;
  if (b < nbF) {
    const int i = b * 256 + threadIdx.x;
    if (i < nS) {
      const int s = colw_s[i].x;
      colw_s[i].y = __float_as_int(dinv_s[s]);
    }
  } else {
    const int i = (b - nbF) * 256 + threadIdx.x;
    if (i < nK) {
      const int s = colw_k[i].x;
      colw_k[i].y = __float_as_int(dinv_k[s]);
    }
  }
}

// ---------------- GEMM2 v3: PQ = bf16(R1b @ Wpq)  [NN x 80] ----------------
// BM=64, dbuf, vmcnt(3), swizzled coalesced staging.
__global__ __launch_bounds__(256) void k_gemm2(const unsigned short* __restrict__ R1b,
    const unsigned short* __restrict__ WpqT, const unsigned short* __restrict__ zbuf,
    unsigned short* __restrict__ PQ) {
  __shared__ unsigned short Als[2][256 * 8];   // 64 m x 4 kg elems
  __shared__ unsigned short Bls[2][512 * 8];   // 128 n x 4 kg elems (rows 80..127 pad)
  const int t = threadIdx.x;
  const int wv = t >> 6, lane = t & 63;
  const int qd = lane >> 4, mr = lane & 15;
  const int m0 = blockIdx.x * 64;

  float4v acc[5];
  const float4v zf4 = {0.f, 0.f, 0.f, 0.f};
#pragma unroll
  for (int b = 0; b < 5; ++b) acc[b] = zf4;

  auto stage = [&](int kk, int pb) {
    const int k0 = kk * 32;
    {
      const int q = wv * 64 + lane;              // A sidx (256 total)
      const int m = q >> 2;
      const int kg = (q & 3) ^ ((q >> 3) & 3);
      const int gm = m0 + m;
      const unsigned short* gp = (gm < NN) ? (R1b + (size_t)gm * K2 + k0 + kg * 8) : zbuf;
      gl_lds16(gp, &Als[pb][q * 8]);
    }
#pragma unroll
    for (int i = 0; i < 2; ++i) {
      const int q = (wv * 2 + i) * 64 + lane;    // B sidx (512 total)
      const int n = q >> 2;
      const int kg = (q & 3) ^ ((q >> 3) & 3);
      gl_lds16(WpqT + n * K2 + k0 + kg * 8, &Bls[pb][q * 8]);
    }
  };

  stage(0, 0);
  for (int kk = 0; kk < 8; ++kk) {
    const int cur = kk & 1;
    if (kk + 1 < 8) {
      stage(kk + 1, cur ^ 1);
      asm volatile("s_waitcnt vmcnt(3)" ::: "memory");
    } else {
      asm volatile("s_waitcnt vmcnt(0)" ::: "memory");
    }
    __builtin_amdgcn_s_barrier();

    short8 af;
    {
      const int m = wv * 16 + mr;
      const int sa = m * 4 + (qd ^ ((m >> 1) & 3));
      af = *(const short8*)&Als[cur][sa * 8];
    }
#pragma unroll
    for (int ct = 0; ct < 5; ++ct) {
      const int n = ct * 16 + mr;
      const int sb = n * 4 + (qd ^ ((n >> 1) & 3));
      const short8 bf = *(const short8*)&Bls[cur][sb * 8];
      acc[ct] = __builtin_amdgcn_mfma_f32_16x16x32_bf16(af, bf, acc[ct], 0, 0, 0);
    }
    __builtin_amdgcn_s_barrier();
  }

  const int rb = m0 + wv * 16 + qd * 4;
#pragma unroll
  for (int ct = 0; ct < 5; ++ct) {
    const int col = ct * 16 + mr;
#pragma unroll
    for (int j = 0; j < 4; ++j) {
      const int r = rb + j;
      if (r < NN) PQ[(size_t)r * NPQ + col] = f2bf(acc[ct][j]);
    }
  }
}

// ---------------- gather helpers v4: scalar index batches + pipelined gathers ----------------
__device__ __forceinline__ void ld8(const int2* __restrict__ cw, int base, int e1, bool full,
                                    int2* __restrict__ q) {
  if (full) {
#pragma unroll
    for (int j = 0; j < 8; ++j) q[j] = cw[base + j];
  } else {
    const int e1c = e1 - 1;
#pragma unroll
    for (int j = 0; j < 8; ++j) {
      const int ee = base + j;
      int2 t = cw[(ee < e1) ? ee : e1c];
      t.y = (ee < e1) ? t.y : 0;
      q[j] = t;
    }
  }
}
__device__ __forceinline__ void g8(const int2* __restrict__ q,
    const unsigned* __restrict__ H32, int lane, unsigned* __restrict__ d) {
#pragma unroll
  for (int j = 0; j < 8; ++j) d[j] = H32[(size_t)q[j].x * 64 + lane];
}
__device__ __forceinline__ void f8(const int2* __restrict__ q, const unsigned* __restrict__ d,
                                   float& ax, float& ay) {
#pragma unroll
  for (int j = 0; j < 8; ++j) {
    const float w = __int_as_float(q[j].y);
    ax += w * __uint_as_float(d[j] << 16);
    ay += w * __uint_as_float(d[j] & 0xffff0000u);
  }
}

// ---------------- layer-1 aggregation: one wave per node, BOTH graphs ----------------
__global__ __launch_bounds__(256) void k_agg1(
    const int* __restrict__ rp_s, const int2* __restrict__ colw_s, const float* __restrict__ dinv_s,
    const int* __restrict__ rp_k, const int2* __restrict__ colw_k, const float* __restrict__ dinv_k,
    const unsigned short* __restrict__ H, const float* __restrict__ bias,
    unsigned short* __restrict__ out) {
  const int wv = threadIdx.x >> 6, lane = threadIdx.x & 63;
  const int c = blockIdx.x * 4 + wv;
  if (c >= NN) return;
  const unsigned* H32 = (const unsigned*)H;
  const int e0s = __builtin_amdgcn_readfirstlane(rp_s[c]);
  const int e1s = __builtin_amdgcn_readfirstlane(rp_s[c + 1]);
  const int e0k = __builtin_amdgcn_readfirstlane(rp_k[c]);
  const int e1k = __builtin_amdgcn_readfirstlane(rp_k[c + 1]);
  const int nbS = (e1s - e0s + 7) >> 3;   // may be 0
  const int nbK = (e1k - e0k + 7) >> 3;

  int2 q0[8], q1[8], qk[8];
  unsigned d0[8], d1[8], dk[8];
  // issue phase: self row + structural batches 0,1 + knn batch 0 all in flight
  const unsigned pc = H32[(size_t)c * 64 + lane];
  if (nbS > 0) { ld8(colw_s, e0s, e1s, e0s + 8 <= e1s, q0); g8(q0, H32, lane, d0); }
  if (nbS > 1) { ld8(colw_s, e0s + 8, e1s, e0s + 16 <= e1s, q1); g8(q1, H32, lane, d1); }
  if (nbK > 0) { ld8(colw_k, e0k, e1k, e0k + 8 <= e1k, qk); g8(qk, H32, lane, dk); }

  const float dcs = dinv_s[c], dck = dinv_k[c];
  const float slo = __uint_as_float(pc << 16);
  const float shi = __uint_as_float(pc & 0xffff0000u);
  float ax = dcs * slo, ay = dcs * shi;   // structural self
  float bx = dck * slo, by = dck * shi;   // knn self

  // structural: pairwise ping-pong, always ~16 gathers outstanding
  int b = 0;
  while (b + 2 < nbS) {
    f8(q0, d0, ax, ay);                   // consume batch b
    {
      const int bs = e0s + (b + 2) * 8;   // issue batch b+2
      ld8(colw_s, bs, e1s, bs + 8 <= e1s, q0);
      g8(q0, H32, lane, d0);
    }
    f8(q1, d1, ax, ay);                   // consume batch b+1
    if (b + 3 < nbS) {
      const int bs = e0s + (b + 3) * 8;   // issue batch b+3
      ld8(colw_s, bs, e1s, bs + 8 <= e1s, q1);
      g8(q1, H32, lane, d1);
    }
    b += 2;
  }
  if (b < nbS) f8(q0, d0, ax, ay);
  if (b + 1 < nbS) f8(q1, d1, ax, ay);

  // knn: batch 0 already in flight since the top; extra batches are rare (deg>8)
  if (nbK > 0) f8(qk, dk, bx, by);
  for (int bk = 1; bk < nbK; ++bk) {
    const int bs = e0k + bk * 8;
    ld8(colw_k, bs, e1k, bs + 8 <= e1k, qk);
    g8(qk, H32, lane, dk);
    f8(qk, dk, bx, by);
  }

  const float2 bb = ((const float2*)bias)[lane];
  const float o0 = fmaxf(dcs * ax + bb.x, 0.f);
  const float o1 = fmaxf(dcs * ay + bb.y, 0.f);
  const float o2 = fmaxf(dck * bx + bb.x, 0.f);
  const float o3 = fmaxf(dck * by + bb.y, 0.f);
  unsigned* orow = (unsigned*)(out + (size_t)c * K2);
  orow[lane]      = (unsigned)f2bf(o0) | ((unsigned)f2bf(o1) << 16);
  orow[64 + lane] = (unsigned)f2bf(o2) | ((unsigned)f2bf(o3) << 16);
}

// ---------------- tail v2: logits = agg_s(P) + agg_k(Q) + cb; log_softmax ----------------
__device__ __forceinline__ void ld12(const int2* __restrict__ cw, int base, int e1, bool full,
                                     int2* __restrict__ q) {
  if (full) {
#pragma unroll
    for (int j = 0; j < 12; ++j) q[j] = cw[base + j];
  } else {
    const int e1c = e1 - 1;
#pragma unroll
    for (int j = 0; j < 12; ++j) {
      const int ee = base + j;
      int2 t = cw[(ee < e1) ? ee : e1c];
      t.y = (ee < e1) ? t.y : 0;
      q[j] = t;
    }
  }
}
__device__ __forceinline__ void gt4(const int2* __restrict__ q, const unsigned* __restrict__ PQ32,
                                    int g, int l, int off, float* __restrict__ w,
                                    unsigned* __restrict__ d) {
#pragma unroll
  for (int t = 0; t < 4; ++t) {
    const int2 qa = q[3 * t], qb = q[3 * t + 1], qc = q[3 * t + 2];
    const int xs = (g == 0) ? qa.x : ((g == 1) ? qb.x : qc.x);
    const int wi = (g == 0) ? qa.y : ((g == 1) ? qb.y : qc.y);
    w[t] = __int_as_float(wi);
    d[t] = PQ32[(size_t)xs * 40 + off + l];
  }
}
__device__ __forceinline__ void ct4(const float* __restrict__ w, const unsigned* __restrict__ d,
                                    float& sx, float& sy) {
#pragma unroll
  for (int t = 0; t < 4; ++t) {
    sx += w[t] * __uint_as_float(d[t] << 16);
    sy += w[t] * __uint_as_float(d[t] & 0xffff0000u);
  }
}

__global__ __launch_bounds__(256) void k_aggf(
    const int* __restrict__ rp_s, const int2* __restrict__ colw_s, const float* __restrict__ dinv_s,
    const int* __restrict__ rp_k, const int2* __restrict__ colw_k, const float* __restrict__ dinv_k,
    const unsigned short* __restrict__ PQ, const float* __restrict__ cb,
    float* __restrict__ out) {
  const int wv = threadIdx.x >> 6, lane = threadIdx.x & 63;
  const int c = blockIdx.x * 4 + wv;
  if (c >= NN) return;
  const unsigned* PQ32 = (const unsigned*)PQ;
  const int g = (lane < 60) ? (lane / 20) : 2;   // lanes 60-63 ride with g=2 (results unused)
  const int l = lane - 20 * g;                   // 0..19 active; 20..23 for lanes 60-63 (safe)

  const int e0s = __builtin_amdgcn_readfirstlane(rp_s[c]);
  const int e1s = __builtin_amdgcn_readfirstlane(rp_s[c + 1]);
  const int e0k = __builtin_amdgcn_readfirstlane(rp_k[c]);
  const int e1k = __builtin_amdgcn_readfirstlane(rp_k[c + 1]);
  const int nbS = (e1s - e0s + 11) / 12;
  const int nbK = (e1k - e0k + 11) / 12;

  // self rows issued up-front (consumed at the end)
  unsigned dP = 0, dQ = 0;
  if (lane < 20) {
    dP = PQ32[(size_t)c * 40 + lane];
    dQ = PQ32[(size_t)c * 40 + 20 + lane];
  }

  int2 q0[12], q1[12], qk[12];
  float w0[4], w1[4], wk[4];
  unsigned d0[4], d1[4], dk[4];
  if (nbS > 0) { ld12(colw_s, e0s, e1s, e0s + 12 <= e1s, q0); gt4(q0, PQ32, g, l, 0, w0, d0); }
  if (nbS > 1) { ld12(colw_s, e0s + 12, e1s, e0s + 24 <= e1s, q1); gt4(q1, PQ32, g, l, 0, w1, d1); }
  if (nbK > 0) { ld12(colw_k, e0k, e1k, e0k + 12 <= e1k, qk); gt4(qk, PQ32, g, l, 20, wk, dk); }

  float sx = 0.f, sy = 0.f, kx = 0.f, ky = 0.f;
  int b = 0;
  while (b + 2 < nbS) {
    ct4(w0, d0, sx, sy);
    {
      const int bs = e0s + (b + 2) * 12;
      ld12(colw_s, bs, e1s, bs + 12 <= e1s, q0);
      gt4(q0, PQ32, g, l, 0, w0, d0);
    }
    ct4(w1, d1, sx, sy);
    if (b + 3 < nbS) {
      const int bs = e0s + (b + 3) * 12;
      ld12(colw_s, bs, e1s, bs + 12 <= e1s, q1);
      gt4(q1, PQ32, g, l, 0, w1, d1);
    }
    b += 2;
  }
  if (b < nbS) ct4(w0, d0, sx, sy);
  if (b + 1 < nbS) ct4(w1, d1, sx, sy);

  if (nbK > 0) ct4(wk, dk, kx, ky);
  for (int bk = 1; bk < nbK; ++bk) {
    const int bs = e0k + bk * 12;
    ld12(colw_k, bs, e1k, bs + 12 <= e1k, qk);
    gt4(qk, PQ32, g, l, 20, wk, dk);
    ct4(wk, dk, kx, ky);
  }

  // combine 3 group partials into lanes 0-19
  sx += __shfl(sx, lane + 20) + __shfl(sx, lane + 40);
  sy += __shfl(sy, lane + 20) + __shfl(sy, lane + 40);
  kx += __shfl(kx, lane + 20) + __shfl(kx, lane + 40);
  ky += __shfl(ky, lane + 20) + __shfl(ky, lane + 40);

  float lo = 0.f, hi = 0.f;
  if (lane < 20) {
    const float dcs = dinv_s[c], dck = dinv_k[c];
    const float2 cbb = ((const float2*)cb)[lane];
    lo = dcs * (sx + dcs * __uint_as_float(dP << 16))
       + dck * (kx + dck * __uint_as_float(dQ << 16)) + cbb.x;
    hi = dcs * (sy + dcs * __uint_as_float(dP & 0xffff0000u))
       + dck * (ky + dck * __uint_as_float(dQ & 0xffff0000u)) + cbb.y;
  }
  // log_softmax over 40 (lanes 0-19 hold pairs)
  float m = (lane < 20) ? fmaxf(lo, hi) : -3.4e38f;
#pragma unroll
  for (int off = 1; off < 64; off <<= 1) m = fmaxf(m, __shfl_xor(m, off));
  float s = (lane < 20) ? (expf(lo - m) + expf(hi - m)) : 0.f;
#pragma unroll
  for (int off = 1; off < 64; off <<= 1) s += __shfl_xor(s, off);
  const float lse = m + logf(s);
  if (lane < 20) {
    float2 o; o.x = lo - lse; o.y = hi - lse;
    ((float2*)(out + (size_t)c * CO))[lane] = o;
  }
}

extern "C" void kernel_launch(void* const* d_in, const int* in_sizes, int n_in,
                              void* d_out, int out_size, void* d_ws, size_t ws_size,
                              hipStream_t stream) {
  const float* x  = (const float*)d_in[0];
  const int* ei   = (const int*)d_in[1];   // [2][E]: row0 = src, row1 = tgt
  const int* eik  = (const int*)d_in[2];
  const float* W1 = (const float*)d_in[3];
  const float* b1 = (const float*)d_in[4];
  const float* W2 = (const float*)d_in[5];
  const float* b2 = (const float*)d_in[6];
  const float* Wl = (const float*)d_in[7];
  const float* bl = (const float*)d_in[8];
  float* out = (float*)d_out;
  const int E  = in_sizes[1] / 2;
  const int EK = in_sizes[2] / 2;

  // workspace layout (~125 MB), 256B-aligned slots
  char* p = (char*)d_ws;
  size_t off = 0;
  auto alloc = [&](size_t bytes) -> void* {
    void* r = (void*)(p + off);
    off += (bytes + 255) & ~(size_t)255;
    return r;
  };
  int* gcur_s = (int*)alloc((size_t)NBUCK * 4);
  int* gcur_k = (int*)alloc((size_t)NBUCK * 4);
  void* zbuf = alloc(256);                 // zero redirect target for OOB tiles
  const size_t zero_span = off;            // memset covers gcur_s, gcur_k, zbuf
  int* bscan_s = (int*)alloc((size_t)NBUCK * 4);
  int* bscan_k = (int*)alloc((size_t)NBUCK * 4);
  float* dinv_s = (float*)alloc((size_t)NN * 4);
  float* dinv_k = (float*)alloc((size_t)NN * 4);
  int* rp_s = (int*)alloc((size_t)(NN + 1) * 4);
  int* rp_k = (int*)alloc((size_t)(NN + 1) * 4);
  unsigned short* W1T = (unsigned short*)alloc((size_t)HID * KP1 * 2);
  unsigned short* WpqT = (unsigned short*)alloc((size_t)NPQP * K2 * 2);  // rows 80..127 pad
  float* cbv = (float*)alloc((size_t)CO * 4);
  int* gbin_s = (int*)alloc((size_t)NBUCK * CAPB_S * 4);    // 14.4 MB
  int* gbin_k = (int*)alloc((size_t)NBUCK * CAPB_K * 4);    // 2.4 MB
  int2* colw_s = (int2*)alloc((size_t)E * 8);               // 25.6 MB
  int2* colw_k = (int2*)alloc((size_t)EK * 8);              // 4 MB
  unsigned short* H1b = (unsigned short*)alloc((size_t)NN * HID * 2);   // 25.6 MB
  unsigned short* R1b = (unsigned short*)alloc((size_t)NN * K2 * 2);    // 51.2 MB
  unsigned short* PQ = H1b;   // alias: H1b dead after agg1; PQ = [NN x 80] bf16 (16 MB)

  hipMemsetAsync(d_ws, 0, zero_span, stream);

  // fused: bin || w1t || wpq  (all depend only on inputs)
  const int nb1S = (E + 4095) / 4096;
  const int nb1K = (EK + 4095) / 4096;
  const int nbBin = nb1S + nb1K;
  k_binw<<<nbBin + 256 + NPQ, 256, 0, stream>>>(
      ei, E, nb1S, gcur_s, gbin_s, eik, EK, nbBin, gcur_k, gbin_k,
      W1, W1T, W2, Wl, b2, bl, WpqT, cbv);
  k_bscan<<<2, 512, 0, stream>>>(gcur_s, bscan_s, gcur_k, bscan_k);

  // fused: csr (needs bin+bscan) || gemm1 (needs x, W1T) — independent, co-scheduled
  const int nbG1 = (NN + 63) / 64;
  k_csrg1<<<2 * NBUCK + nbG1, 256, 0, stream>>>(
      gcur_s, gbin_s, bscan_s, rp_s, colw_s, dinv_s,
      gcur_k, gbin_k, bscan_k, rp_k, colw_k, dinv_k,
      x, W1T, (const float*)zbuf, H1b);

  const int nbF = (E + 255) / 256;
  const int nbFk = (EK + 255) / 256;
  k_fuse<<<nbF + nbFk, 256, 0, stream>>>(colw_s, dinv_s, E, nbF, colw_k, dinv_k, EK);

  const int nbAgg = (NN + 3) / 4;
  k_agg1<<<nbAgg, 256, 0, stream>>>(rp_s, colw_s, dinv_s, rp_k, colw_k, dinv_k, H1b, b1, R1b);

  // folded tail: PQ GEMM (BM=64 dbuf, swizzled staging) + fused aggregation/log_softmax
  k_gemm2<<<(NN + 63) / 64, 256, 0, stream>>>(R1b, WpqT, (const unsigned short*)zbuf, PQ);
  k_aggf<<<nbAgg, 256, 0, stream>>>(rp_s, colw_s, dinv_s, rp_k, colw_k, dinv_k, PQ, cbv, out);
}